// Round 9
// baseline (683.343 us; speedup 1.0000x reference)
//
#include <hip/hip_runtime.h>
#include <hip/hip_bf16.h>
#include <math.h>

// Problem constants (B=32, H=W=56, C=256, heads=8, hd=32, ws=7)
#define NTOK 3136            // 56*56
#define C_ 256
#define HEADS_ 8
#define HD 32
#define WS_ 7
#define L_ 49
#define NWIN 2048            // 32 * 8 * 8
#define NWH 16384            // NWIN * HEADS_
#define M_ 100352            // NWIN * 49  == BATCH*NTOK
#define MP 131072            // NWIN * 64  (padded rows, 64 per window)
#define PLANE 33554432       // NWIN * 64 * 256 elems per Q/K/V plane
#define MLPH 512

typedef __bf16 bf16x8 __attribute__((ext_vector_type(8)));
typedef float f32x4 __attribute__((ext_vector_type(4)));

__device__ __forceinline__ unsigned short f2bf(float f) {
    union { float f; unsigned u; } v; v.f = f;
    unsigned r = v.u + 0x7fffu + ((v.u >> 16) & 1u);   // RNE
    return (unsigned short)(r >> 16);
}
__device__ __forceinline__ float bf2f(unsigned short s) {
    union { unsigned u; float f; } v; v.u = ((unsigned)s) << 16;
    return v.f;
}

// windowed token index (49-based) -> natural row index
__device__ __forceinline__ int t2rr(int t) {
    int win = t / L_;
    int l   = t - win * L_;
    int b_  = win >> 6, wh = (win >> 3) & 7, ww = win & 7;
    int ld7 = l / WS_;
    int y   = wh * WS_ + ld7;
    int xc  = ww * WS_ + (l - ld7 * WS_);
    return b_ * NTOK + y * 56 + xc;
}

// XCD-chunked bm-major remap (L2 reuse of the A stripe per XCD)
template <int NBN>
__device__ __forceinline__ void xcd_decode(int nb, int& bm, int& bn) {
    int h = blockIdx.x;
    int fid = (h & 7) * (nb >> 3) + (h >> 3);
    int bmi = fid / NBN;
    bm = bmi * 128;
    bn = (fid - bmi * NBN) * 128;
}

// ---------------------------------------------------------------------------
__global__ __launch_bounds__(256) void cvt_kernel(
    const float* __restrict__ in, unsigned short* __restrict__ out, int n)
{
    int i = blockIdx.x * 256 + threadIdx.x;
    if (i < n) out[i] = f2bf(in[i]);
}

// ---------------------------------------------------------------------------
// LN1 gather: one wave per padded row (win,l). l<49: LN of source token;
// l>=49: zeros. Output [win][64][256] bf16 (linear, coalesced).
// ---------------------------------------------------------------------------
__global__ __launch_bounds__(256) void ln_kernel(
    const float* __restrict__ x, const float* __restrict__ gamma,
    const float* __restrict__ beta, unsigned short* __restrict__ out)
{
    int wave = threadIdx.x >> 6;
    int lane = threadIdx.x & 63;
    int p = blockIdx.x * 4 + wave;        // padded row id, < MP
    int win = p >> 6, l = p & 63;
    if (l >= L_) {
        uint2 z; z.x = 0; z.y = 0;
        *(uint2*)(out + (size_t)p * C_ + lane * 4) = z;
        return;
    }
    int b_ = win >> 6, wh = (win >> 3) & 7, ww = win & 7;
    int ld7 = l / WS_;
    int y   = wh * WS_ + ld7;
    int xc  = ww * WS_ + (l - ld7 * WS_);
    int rr  = b_ * NTOK + y * 56 + xc;
    const float* row = x + (size_t)rr * C_;
    float4 v = *(const float4*)(row + lane * 4);
    float s  = v.x + v.y + v.z + v.w;
    float ss = v.x * v.x + v.y * v.y + v.z * v.z + v.w * v.w;
    #pragma unroll
    for (int m = 1; m < 64; m <<= 1) {
        s  += __shfl_xor(s, m, 64);
        ss += __shfl_xor(ss, m, 64);
    }
    float mean = s * (1.0f / C_);
    float var  = ss * (1.0f / C_) - mean * mean;
    float inv  = rsqrtf(var + 1e-5f);
    float4 gv = *(const float4*)(gamma + lane * 4);
    float4 bv = *(const float4*)(beta + lane * 4);
    unsigned short o[4];
    o[0] = f2bf((v.x - mean) * inv * gv.x + bv.x);
    o[1] = f2bf((v.y - mean) * inv * gv.y + bv.y);
    o[2] = f2bf((v.z - mean) * inv * gv.z + bv.z);
    o[3] = f2bf((v.w - mean) * inv * gv.w + bv.w);
    *(uint2*)(out + (size_t)p * C_ + lane * 4) = *(const uint2*)o;
}

// ---------------------------------------------------------------------------
// QKV GEMM: A (MP x 256 padded windows) @ wqkv^T -> Q,K natural [win][64][256],
// V pre-fragmented [win][kb8][col256][kj8]. 128x128 tile = exactly 2 windows.
// NO-LDS K-loop: each wave loads its A/B fragments straight to VGPRs --
// zero barriers, zero waitcnt pinning; compiler pipelines, waves drift.
// LDS used only for the coalesced transpose epilogue.
// ---------------------------------------------------------------------------
#define TSS 136   // transpose-stage row stride (shorts)

__global__ __launch_bounds__(256) void mgemm_qkv(
    const unsigned short* __restrict__ A, const unsigned short* __restrict__ W,
    const float* __restrict__ bias, unsigned short* __restrict__ Qp,
    unsigned short* __restrict__ Kp, unsigned short* __restrict__ Vp)
{
    __shared__ __align__(16) unsigned short Ts[64 * TSS];   // 17.4 KB

    int tid  = threadIdx.x;
    int w    = tid >> 6;
    int lane = tid & 63;
    int wr = w >> 1, wc = w & 1;
    int bm, bn;
    xcd_decode<6>(gridDim.x, bm, bn);
    int c = lane & 15, hi = lane >> 4;

    const unsigned short* Ab[4];
    const unsigned short* Bb[4];
    #pragma unroll
    for (int mi = 0; mi < 4; ++mi)
        Ab[mi] = A + (size_t)(bm + wr * 64 + mi * 16 + c) * 256 + hi * 8;
    #pragma unroll
    for (int ni = 0; ni < 4; ++ni)
        Bb[ni] = W + (size_t)(bn + wc * 64 + ni * 16 + c) * 256 + hi * 8;

    f32x4 acc[4][4] = {};
    #pragma unroll
    for (int t = 0; t < 8; ++t) {
        bf16x8 af[4], bf[4];
        #pragma unroll
        for (int mi = 0; mi < 4; ++mi) af[mi] = *(const bf16x8*)(Ab[mi] + t * 32);
        #pragma unroll
        for (int ni = 0; ni < 4; ++ni) bf[ni] = *(const bf16x8*)(Bb[ni] + t * 32);
        #pragma unroll
        for (int mi = 0; mi < 4; ++mi)
            #pragma unroll
            for (int ni = 0; ni < 4; ++ni)
                acc[mi][ni] = __builtin_amdgcn_mfma_f32_16x16x32_bf16(
                    af[mi], bf[ni], acc[mi][ni], 0, 0, 0);
    }

    int which  = bn >> 8;                // 0=Q 1=K 2=V (block-uniform)
    int bn_off = bn & 255;
    unsigned short* plane = (which == 0) ? Qp : (which == 1) ? Kp : Vp;

    #pragma unroll
    for (int ch = 0; ch < 2; ++ch) {     // one 64-row chunk = one window
        if (ch) __syncthreads();
        if (wr == ch) {
            #pragma unroll
            for (int mi = 0; mi < 4; ++mi)
                #pragma unroll
                for (int ni = 0; ni < 4; ++ni) {
                    int colb = wc * 64 + ni * 16 + c;
                    float bv = bias[bn + colb];
                    #pragma unroll
                    for (int r = 0; r < 4; ++r)
                        Ts[(mi * 16 + hi * 4 + r) * TSS + colb] =
                            f2bf(acc[mi][ni][r] + bv);
                }
        }
        __syncthreads();
        int win = (bm >> 6) + ch;
        if (which < 2) {
            #pragma unroll
            for (int it = 0; it < 4; ++it) {
                int id = it * 256 + tid;          // 0..1023
                int row = id >> 4, cx = (id & 15) * 8;
                if (row < L_) {                   // skip pad rows (bias-only)
                    uint4 v = *(const uint4*)&Ts[row * TSS + cx];
                    *(uint4*)&plane[(size_t)win * 16384 + (size_t)row * 256 + bn_off + cx] = v;
                }
            }
        } else {
            #pragma unroll
            for (int it = 0; it < 4; ++it) {
                int id = it * 256 + tid;
                int kb = id >> 7, colloc = id & 127;
                union { unsigned short s[8]; uint4 v; } u;
                #pragma unroll
                for (int kj = 0; kj < 8; ++kj)
                    u.s[kj] = Ts[(kb * 8 + kj) * TSS + colloc];
                *(uint4*)&plane[(size_t)win * 16384 +
                                (size_t)(kb * 256 + bn_off + colloc) * 8] = u.v;
            }
        }
    }
}

// ---------------------------------------------------------------------------
// fc1: ln2 (M_ x 256) @ w1^T + b1 -> tanh-GELU -> natural [row][512] bf16.
// No-LDS K-loop; coalesced transpose epilogue.
// ---------------------------------------------------------------------------
__global__ __launch_bounds__(256) void mgemm_g(
    const unsigned short* __restrict__ A, const unsigned short* __restrict__ W,
    const float* __restrict__ bias, unsigned short* __restrict__ outp)
{
    __shared__ __align__(16) unsigned short Ts[64 * TSS];

    int tid  = threadIdx.x;
    int w    = tid >> 6;
    int lane = tid & 63;
    int wr = w >> 1, wc = w & 1;
    int bm, bn;
    xcd_decode<4>(gridDim.x, bm, bn);
    int c = lane & 15, hi = lane >> 4;

    const unsigned short* Ab[4];
    const unsigned short* Bb[4];
    #pragma unroll
    for (int mi = 0; mi < 4; ++mi)
        Ab[mi] = A + (size_t)(bm + wr * 64 + mi * 16 + c) * 256 + hi * 8;
    #pragma unroll
    for (int ni = 0; ni < 4; ++ni)
        Bb[ni] = W + (size_t)(bn + wc * 64 + ni * 16 + c) * 256 + hi * 8;

    f32x4 acc[4][4] = {};
    #pragma unroll
    for (int t = 0; t < 8; ++t) {
        bf16x8 af[4], bf[4];
        #pragma unroll
        for (int mi = 0; mi < 4; ++mi) af[mi] = *(const bf16x8*)(Ab[mi] + t * 32);
        #pragma unroll
        for (int ni = 0; ni < 4; ++ni) bf[ni] = *(const bf16x8*)(Bb[ni] + t * 32);
        #pragma unroll
        for (int mi = 0; mi < 4; ++mi)
            #pragma unroll
            for (int ni = 0; ni < 4; ++ni)
                acc[mi][ni] = __builtin_amdgcn_mfma_f32_16x16x32_bf16(
                    af[mi], bf[ni], acc[mi][ni], 0, 0, 0);
    }

    #pragma unroll
    for (int ch = 0; ch < 2; ++ch) {
        if (ch) __syncthreads();
        if (wr == ch) {
            #pragma unroll
            for (int mi = 0; mi < 4; ++mi)
                #pragma unroll
                for (int ni = 0; ni < 4; ++ni) {
                    int colb = wc * 64 + ni * 16 + c;
                    float bv = bias[bn + colb];
                    #pragma unroll
                    for (int r = 0; r < 4; ++r) {
                        float v = acc[mi][ni][r] + bv;
                        float a = 1.5957691216f * (v + 0.044715f * v * v * v);
                        float g = v / (1.0f + __expf(-a));
                        Ts[(mi * 16 + hi * 4 + r) * TSS + colb] = f2bf(g);
                    }
                }
        }
        __syncthreads();
        #pragma unroll
        for (int it = 0; it < 4; ++it) {
            int id = it * 256 + tid;
            int row = id >> 4, cx = (id & 15) * 8;
            uint4 v = *(const uint4*)&Ts[row * TSS + cx];
            *(uint4*)&outp[(size_t)(bm + ch * 64 + row) * MLPH + bn + cx] = v;
        }
    }
}

// ---------------------------------------------------------------------------
// mgemm_ln: out-proj (o_win @ wout^T + bout) + residual(x gathered) + LN2.
// 512 threads, 128 rows x full 256 cols. No-LDS K-loop.
// Outputs bf16 windowed-sequential: x1 and ln2(x1).
// ---------------------------------------------------------------------------
#define XS 260

__global__ __launch_bounds__(512) void mgemm_ln(
    const unsigned short* __restrict__ A, const unsigned short* __restrict__ W,
    const float* __restrict__ bias, const float* __restrict__ x,
    const float* __restrict__ g2, const float* __restrict__ b2,
    unsigned short* __restrict__ x1_out, unsigned short* __restrict__ ln_out)
{
    __shared__ __align__(16) unsigned short pool[128 * XS];   // 65 KB

    int tid  = threadIdx.x;
    int w    = tid >> 6;          // 0..7
    int lane = tid & 63;
    int wr = w >> 2, wc = w & 3;  // 2 x 4 wave tiles of 64x64
    int bm = blockIdx.x * 128;
    int c = lane & 15, hi = lane >> 4;

    const unsigned short* Ab[4];
    const unsigned short* Bb[4];
    #pragma unroll
    for (int mi = 0; mi < 4; ++mi)
        Ab[mi] = A + (size_t)(bm + wr * 64 + mi * 16 + c) * 256 + hi * 8;
    #pragma unroll
    for (int ni = 0; ni < 4; ++ni)
        Bb[ni] = W + (size_t)(wc * 64 + ni * 16 + c) * 256 + hi * 8;

    f32x4 acc[4][4] = {};
    #pragma unroll
    for (int t = 0; t < 8; ++t) {
        bf16x8 af[4], bf[4];
        #pragma unroll
        for (int mi = 0; mi < 4; ++mi) af[mi] = *(const bf16x8*)(Ab[mi] + t * 32);
        #pragma unroll
        for (int ni = 0; ni < 4; ++ni) bf[ni] = *(const bf16x8*)(Bb[ni] + t * 32);
        #pragma unroll
        for (int mi = 0; mi < 4; ++mi)
            #pragma unroll
            for (int ni = 0; ni < 4; ++ni)
                acc[mi][ni] = __builtin_amdgcn_mfma_f32_16x16x32_bf16(
                    af[mi], bf[ni], acc[mi][ni], 0, 0, 0);
    }

    // stage o (+bias) to LDS bf16
    #pragma unroll
    for (int mi = 0; mi < 4; ++mi) {
        #pragma unroll
        for (int ni = 0; ni < 4; ++ni) {
            int colb = wc * 64 + ni * 16 + c;
            float bv = bias[colb];
            #pragma unroll
            for (int r = 0; r < 4; ++r)
                pool[(wr * 64 + mi * 16 + hi * 4 + r) * XS + colb] =
                    f2bf(acc[mi][ni][r] + bv);
        }
    }
    __syncthreads();

    float4 gv  = *(const float4*)(g2 + lane * 4);
    float4 bv2 = *(const float4*)(b2 + lane * 4);
    #pragma unroll 2
    for (int i = 0; i < 16; ++i) {
        int tl = w * 16 + i;
        int t = bm + tl;
        int rr = t2rr(t);
        float4 xv = *(const float4*)(x + (size_t)rr * C_ + lane * 4);
        uint2 ov = *(const uint2*)&pool[tl * XS + lane * 4];
        float x0 = xv.x + bf2f(ov.x & 0xffff);
        float x1 = xv.y + bf2f(ov.x >> 16);
        float x2 = xv.z + bf2f(ov.y & 0xffff);
        float x3 = xv.w + bf2f(ov.y >> 16);
        float s  = x0 + x1 + x2 + x3;
        float ss = x0 * x0 + x1 * x1 + x2 * x2 + x3 * x3;
        #pragma unroll
        for (int m = 1; m < 64; m <<= 1) {
            s  += __shfl_xor(s, m, 64);
            ss += __shfl_xor(ss, m, 64);
        }
        float mean = s * (1.0f / C_);
        float var  = ss * (1.0f / C_) - mean * mean;
        float inv  = rsqrtf(var + 1e-5f);
        uint2 xw, lw;
        xw.x = (unsigned)f2bf(x0) | ((unsigned)f2bf(x1) << 16);
        xw.y = (unsigned)f2bf(x2) | ((unsigned)f2bf(x3) << 16);
        float l0 = (x0 - mean) * inv * gv.x + bv2.x;
        float l1 = (x1 - mean) * inv * gv.y + bv2.y;
        float l2 = (x2 - mean) * inv * gv.z + bv2.z;
        float l3 = (x3 - mean) * inv * gv.w + bv2.w;
        lw.x = (unsigned)f2bf(l0) | ((unsigned)f2bf(l1) << 16);
        lw.y = (unsigned)f2bf(l2) | ((unsigned)f2bf(l3) << 16);
        *(uint2*)(x1_out + (size_t)t * C_ + lane * 4) = xw;
        *(uint2*)(ln_out + (size_t)t * C_ + lane * 4) = lw;
    }
}

// ---------------------------------------------------------------------------
// fc2: gelu (M_ x 512) @ w2^T + b2 + residual(x1 bf16 windowed) -> natural f32.
// No-LDS K-loop (K=512); LDS-transposed coalesced epilogue. NBN=2.
// ---------------------------------------------------------------------------
__global__ __launch_bounds__(256) void mgemm_out(
    const unsigned short* __restrict__ A, const unsigned short* __restrict__ W,
    const float* __restrict__ bias, const unsigned short* __restrict__ x1,
    float* __restrict__ dout)
{
    __shared__ __align__(16) float stg[32 * 132];   // 16.9 KB

    int tid  = threadIdx.x;
    int w    = tid >> 6;
    int lane = tid & 63;
    int wr = w >> 1, wc = w & 1;
    int bm, bn;
    xcd_decode<2>(gridDim.x, bm, bn);
    int c = lane & 15, hi = lane >> 4;

    const unsigned short* Ab[4];
    const unsigned short* Bb[4];
    #pragma unroll
    for (int mi = 0; mi < 4; ++mi)
        Ab[mi] = A + (size_t)(bm + wr * 64 + mi * 16 + c) * 512 + hi * 8;
    #pragma unroll
    for (int ni = 0; ni < 4; ++ni)
        Bb[ni] = W + (size_t)(bn + wc * 64 + ni * 16 + c) * 512 + hi * 8;

    f32x4 acc[4][4] = {};
    #pragma unroll
    for (int t = 0; t < 16; ++t) {
        bf16x8 af[4], bf[4];
        #pragma unroll
        for (int mi = 0; mi < 4; ++mi) af[mi] = *(const bf16x8*)(Ab[mi] + t * 32);
        #pragma unroll
        for (int ni = 0; ni < 4; ++ni) bf[ni] = *(const bf16x8*)(Bb[ni] + t * 32);
        #pragma unroll
        for (int mi = 0; mi < 4; ++mi)
            #pragma unroll
            for (int ni = 0; ni < 4; ++ni)
                acc[mi][ni] = __builtin_amdgcn_mfma_f32_16x16x32_bf16(
                    af[mi], bf[ni], acc[mi][ni], 0, 0, 0);
    }

    #pragma unroll
    for (int c2 = 0; c2 < 4; ++c2) {
        if (c2) __syncthreads();
        if (wr == (c2 >> 1)) {
            int mi0 = (c2 & 1) * 2;
            #pragma unroll
            for (int mm = 0; mm < 2; ++mm) {
                #pragma unroll
                for (int ni = 0; ni < 4; ++ni) {
                    int colb = wc * 64 + ni * 16 + c;
                    float bv = bias[bn + colb];
                    #pragma unroll
                    for (int r = 0; r < 4; ++r)
                        stg[(mm * 16 + hi * 4 + r) * 132 + colb] =
                            acc[mi0 + mm][ni][r] + bv;
                }
            }
        }
        __syncthreads();
        #pragma unroll
        for (int i = 0; i < 4; ++i) {
            int lr = i * 8 + (tid >> 5);         // 0..31
            int t = bm + c2 * 32 + lr;
            int rr = t2rr(t);
            int col4 = (tid & 31) * 4;
            float4 v = *(const float4*)&stg[lr * 132 + col4];
            uint2 rv = *(const uint2*)&x1[(size_t)t * C_ + bn + col4];
            v.x += bf2f(rv.x & 0xffff);
            v.y += bf2f(rv.x >> 16);
            v.z += bf2f(rv.y & 0xffff);
            v.w += bf2f(rv.y >> 16);
            *(float4*)&dout[(size_t)rr * C_ + bn + col4] = v;
        }
    }
}

// ---------------------------------------------------------------------------
// MFMA window attention: reads Q,K natural [win][64][256], V fragmented.
// ---------------------------------------------------------------------------
__global__ __launch_bounds__(256) void mattn(
    const unsigned short* __restrict__ Qp, const unsigned short* __restrict__ Kp,
    const unsigned short* __restrict__ Vp, unsigned short* __restrict__ o_win)
{
    __shared__ __align__(16) unsigned short P_lds[4][64][72];
    int wave = threadIdx.x >> 6, lane = threadIdx.x & 63;
    int c = lane & 15, hi = lane >> 4;
    int wh = blockIdx.x * 4 + wave;
    int win = wh >> 3, head = wh & 7;
    const unsigned short* qb = Qp + (size_t)win * 16384 + head * HD;
    const unsigned short* kb = Kp + (size_t)win * 16384 + head * HD;
    const unsigned short* vb = Vp + (size_t)win * 16384 + head * HD * 8;

    bf16x8 af[4], bk[4];
    #pragma unroll
    for (int mi = 0; mi < 4; ++mi)
        af[mi] = *(const bf16x8*)(qb + (size_t)(mi * 16 + c) * 256 + hi * 8);
    #pragma unroll
    for (int ni = 0; ni < 4; ++ni)
        bk[ni] = *(const bf16x8*)(kb + (size_t)(ni * 16 + c) * 256 + hi * 8);

    f32x4 sacc[4][4] = {};
    #pragma unroll
    for (int mi = 0; mi < 4; ++mi)
        #pragma unroll
        for (int ni = 0; ni < 4; ++ni)
            sacc[mi][ni] = __builtin_amdgcn_mfma_f32_16x16x32_bf16(
                af[mi], bk[ni], sacc[mi][ni], 0, 0, 0);

    const float scale = 0.17677669529663687f;
    float inv_[4][4];
    #pragma unroll
    for (int mi = 0; mi < 4; ++mi) {
        #pragma unroll
        for (int r = 0; r < 4; ++r) {
            float sv[4];
            float m = -1e30f;
            #pragma unroll
            for (int ni = 0; ni < 4; ++ni) {
                float v = sacc[mi][ni][r] * scale;
                v = (ni * 16 + c < L_) ? v : -1e30f;
                sv[ni] = v;
                m = fmaxf(m, v);
            }
            #pragma unroll
            for (int msk = 1; msk < 16; msk <<= 1)
                m = fmaxf(m, __shfl_xor(m, msk, 64));
            float sum = 0.f;
            unsigned short pb[4];
            #pragma unroll
            for (int ni = 0; ni < 4; ++ni) {
                float p = __expf(sv[ni] - m);
                sum += p;
                pb[ni] = f2bf(p);
            }
            #pragma unroll
            for (int msk = 1; msk < 16; msk <<= 1)
                sum += __shfl_xor(sum, msk, 64);
            inv_[mi][r] = 1.0f / sum;
            int q = mi * 16 + hi * 4 + r;
            #pragma unroll
            for (int ni = 0; ni < 4; ++ni)
                P_lds[wave][q][ni * 16 + c] = pb[ni];
        }
    }

    f32x4 oacc[4][2] = {};
    #pragma unroll
    for (int ks = 0; ks < 2; ++ks) {
        bf16x8 pa[4], bv[2];
        #pragma unroll
        for (int mi = 0; mi < 4; ++mi)
            pa[mi] = *(const bf16x8*)&P_lds[wave][mi * 16 + c][ks * 32 + hi * 8];
        #pragma unroll
        for (int ni = 0; ni < 2; ++ni)
            bv[ni] = *(const bf16x8*)(vb + (size_t)((ks * 4 + hi) * 256 + ni * 16 + c) * 8);
        #pragma unroll
        for (int mi = 0; mi < 4; ++mi)
            #pragma unroll
            for (int ni = 0; ni < 2; ++ni)
                oacc[mi][ni] = __builtin_amdgcn_mfma_f32_16x16x32_bf16(
                    pa[mi], bv[ni], oacc[mi][ni], 0, 0, 0);
    }

    #pragma unroll
    for (int mi = 0; mi < 4; ++mi) {
        #pragma unroll
        for (int r = 0; r < 4; ++r) {
            int q = mi * 16 + hi * 4 + r;
            if (q < L_) {
                size_t rowoff = ((size_t)(win * L_ + q)) * C_ + head * HD;
                float iv = inv_[mi][r];
                #pragma unroll
                for (int ni = 0; ni < 2; ++ni)
                    o_win[rowoff + ni * 16 + c] = f2bf(oacc[mi][ni][r] * iv);
            }
        }
    }
}

// ---------------------------------------------------------------------------
extern "C" void kernel_launch(void* const* d_in, const int* in_sizes, int n_in,
                              void* d_out, int out_size, void* d_ws, size_t ws_size,
                              hipStream_t stream)
{
    (void)in_sizes; (void)n_in; (void)out_size; (void)ws_size;
    const float* x    = (const float*)d_in[0];
    const float* n1g  = (const float*)d_in[3];
    const float* n1b  = (const float*)d_in[4];
    const float* wqkv = (const float*)d_in[5];
    const float* bqkv = (const float*)d_in[6];
    const float* wout = (const float*)d_in[7];
    const float* bout = (const float*)d_in[8];
    const float* n2g  = (const float*)d_in[9];
    const float* n2b  = (const float*)d_in[10];
    const float* w1   = (const float*)d_in[11];
    const float* b1   = (const float*)d_in[12];
    const float* w2   = (const float*)d_in[13];
    const float* b2   = (const float*)d_in[14];
    float* out = (float*)d_out;

    // workspace layout (bf16 shorts), ~322 MB with aliasing
    unsigned short* lnq   = (unsigned short*)d_ws;        // MP*256 (later: x1_bf)
    unsigned short* Qp    = lnq + (size_t)MP * C_;        // PLANE  (later: gelu)
    unsigned short* Kp    = Qp + (size_t)PLANE;           // PLANE  (gelu cont.)
    unsigned short* Vp    = Kp + (size_t)PLANE;           // PLANE  (later: ln2_bf)
    unsigned short* o_win = Vp + (size_t)PLANE;           // M_*256
    unsigned short* wqkv_bf = o_win + (size_t)M_ * C_;
    unsigned short* wout_bf = wqkv_bf + 768 * 256;
    unsigned short* w1_bf   = wout_bf + 256 * 256;
    unsigned short* w2_bf   = w1_bf + 512 * 256;
    unsigned short* x1_bf  = lnq;      // alias (lnq dead after QKV GEMM)
    unsigned short* ln2_bf = Vp;       // alias (Vp dead after mattn)
    unsigned short* gelu   = Qp;       // alias (Qp/Kp dead after mattn)

    // 0) weights -> bf16
    cvt_kernel<<<(768 * 256 + 255) / 256, 256, 0, stream>>>(wqkv, wqkv_bf, 768 * 256);
    cvt_kernel<<<(256 * 256 + 255) / 256, 256, 0, stream>>>(wout, wout_bf, 256 * 256);
    cvt_kernel<<<(512 * 256 + 255) / 256, 256, 0, stream>>>(w1, w1_bf, 512 * 256);
    cvt_kernel<<<(256 * 512 + 255) / 256, 256, 0, stream>>>(w2, w2_bf, 256 * 512);

    // 1) LN1 gather -> padded [win][64][256] (zeros in pad rows)
    ln_kernel<<<MP / 4, 256, 0, stream>>>(x, n1g, n1b, lnq);

    // 2) QKV GEMM -> Q,K natural + V fragmented (coalesced epilogue)
    mgemm_qkv<<<(MP / 128) * 6, 256, 0, stream>>>(
        lnq, wqkv_bf, bqkv, Qp, Kp, Vp);

    // 3) MFMA window attention -> o_win (49-based rows x 256)
    mattn<<<NWH / 4, 256, 0, stream>>>(Qp, Kp, Vp, o_win);

    // 4) out-proj + residual + LN2 fused -> x1_bf, ln2_bf
    mgemm_ln<<<M_ / 128, 512, 0, stream>>>(
        o_win, wout_bf, bout, x, n2g, n2b, x1_bf, ln2_bf);

    // 5) MLP fc1 + tanh-GELU -> gelu [M_ x 512] natural
    mgemm_g<<<(M_ / 128) * 4, 256, 0, stream>>>(ln2_bf, w1_bf, b1, gelu);

    // 6) MLP fc2 + residual(x1) -> d_out natural f32
    mgemm_out<<<(M_ / 128) * 2, 256, 0, stream>>>(gelu, w2_bf, b2, x1_bf, out);
}

// Round 10
// 448.053 us; speedup vs baseline: 1.5251x; 1.5251x over previous
//
#include <hip/hip_runtime.h>
#include <hip/hip_bf16.h>
#include <math.h>

// Problem constants (B=32, H=W=56, C=256, heads=8, hd=32, ws=7)
#define NTOK 3136            // 56*56
#define C_ 256
#define HEADS_ 8
#define HD 32
#define WS_ 7
#define L_ 49
#define NWIN 2048            // 32 * 8 * 8
#define M_ 100352            // NWIN * 49  == BATCH*NTOK
#define MP 131072            // NWIN * 64  (padded rows, 64 per window)
#define MLPH 512

typedef __bf16 bf16x8 __attribute__((ext_vector_type(8)));
typedef float f32x4 __attribute__((ext_vector_type(4)));

#define VMWAIT(n) asm volatile("s_waitcnt vmcnt(" #n ")" ::: "memory")
#define LGKWAIT   asm volatile("s_waitcnt lgkmcnt(0)" ::: "memory")
#define SBAR      __builtin_amdgcn_s_barrier()

__device__ __forceinline__ unsigned short f2bf(float f) {
    union { float f; unsigned u; } v; v.f = f;
    unsigned r = v.u + 0x7fffu + ((v.u >> 16) & 1u);   // RNE
    return (unsigned short)(r >> 16);
}
__device__ __forceinline__ float bf2f(unsigned short s) {
    union { unsigned u; float f; } v; v.u = ((unsigned)s) << 16;
    return v.f;
}

// windowed token index (49-based) -> natural row index
__device__ __forceinline__ int t2rr(int t) {
    int win = t / L_;
    int l   = t - win * L_;
    int b_  = win >> 6, wh = (win >> 3) & 7, ww = win & 7;
    int ld7 = l / WS_;
    int y   = wh * WS_ + ld7;
    int xc  = ww * WS_ + (l - ld7 * WS_);
    return b_ * NTOK + y * 56 + xc;
}

// XCD-chunked bm-major remap (L2 reuse of the A stripe per XCD)
template <int NBN>
__device__ __forceinline__ void xcd_decode(int nb, int& bm, int& bn) {
    int h = blockIdx.x;
    int fid = (h & 7) * (nb >> 3) + (h >> 3);
    int bmi = fid / NBN;
    bm = bmi * 128;
    bn = (fid - bmi * NBN) * 128;
}

// ---------------------------------------------------------------------------
__global__ __launch_bounds__(256) void cvt_kernel(
    const float* __restrict__ in, unsigned short* __restrict__ out, int n)
{
    int i = blockIdx.x * 256 + threadIdx.x;
    if (i < n) out[i] = f2bf(in[i]);
}

// ---------------------------------------------------------------------------
// LN1 gather: one wave per padded row (win,l). l<49: LN of source token;
// l>=49: zeros. Output [win][64][256] bf16 (linear, coalesced).
// ---------------------------------------------------------------------------
__global__ __launch_bounds__(256) void ln_kernel(
    const float* __restrict__ x, const float* __restrict__ gamma,
    const float* __restrict__ beta, unsigned short* __restrict__ out)
{
    int wave = threadIdx.x >> 6;
    int lane = threadIdx.x & 63;
    int p = blockIdx.x * 4 + wave;        // padded row id, < MP
    int win = p >> 6, l = p & 63;
    if (l >= L_) {
        uint2 z; z.x = 0; z.y = 0;
        *(uint2*)(out + (size_t)p * C_ + lane * 4) = z;
        return;
    }
    int b_ = win >> 6, wh = (win >> 3) & 7, ww = win & 7;
    int ld7 = l / WS_;
    int y   = wh * WS_ + ld7;
    int xc  = ww * WS_ + (l - ld7 * WS_);
    int rr  = b_ * NTOK + y * 56 + xc;
    const float* row = x + (size_t)rr * C_;
    float4 v = *(const float4*)(row + lane * 4);
    float s  = v.x + v.y + v.z + v.w;
    float ss = v.x * v.x + v.y * v.y + v.z * v.z + v.w * v.w;
    #pragma unroll
    for (int m = 1; m < 64; m <<= 1) {
        s  += __shfl_xor(s, m, 64);
        ss += __shfl_xor(ss, m, 64);
    }
    float mean = s * (1.0f / C_);
    float var  = ss * (1.0f / C_) - mean * mean;
    float inv  = rsqrtf(var + 1e-5f);
    float4 gv = *(const float4*)(gamma + lane * 4);
    float4 bv = *(const float4*)(beta + lane * 4);
    unsigned short o[4];
    o[0] = f2bf((v.x - mean) * inv * gv.x + bv.x);
    o[1] = f2bf((v.y - mean) * inv * gv.y + bv.y);
    o[2] = f2bf((v.z - mean) * inv * gv.z + bv.z);
    o[3] = f2bf((v.w - mean) * inv * gv.w + bv.w);
    *(uint2*)(out + (size_t)p * C_ + lane * 4) = *(const uint2*)o;
}

// ---------------------------------------------------------------------------
#define GBK 32

__device__ __forceinline__ void gload_lds16(const void* g, void* l) {
    __builtin_amdgcn_global_load_lds(
        (const __attribute__((address_space(1))) unsigned*)g,
        (__attribute__((address_space(3))) unsigned*)l, 16, 0, 0);
}

// ---------------------------------------------------------------------------
// FUSED QKV GEMM + window attention. One block (512 thr, 8 waves) per window.
// Phase 1: QKV = A(64x256, LDS) @ wqkv^T (streamed from L2, counted-vmcnt
//   dbuf). Wave w computes 64 x 96 (frags fn = 6w..6w+5), acc in regs.
// Phase 2: write Q,K (XOR-swizzled natural 64x256) + V' (fragmented) to LDS.
// Phase 3: wave h does head h attention entirely from LDS; P aliases Q/K
//   region after a barrier. O written to global (49 rows).
// LDS map (shorts): GEMM: A[0,16384) B0[16384,40960) B1[40960,65536)
//   attn: Q[0,16384) K[16384,32768) V[32768,49152) P = h*4096 in [0,32768)
// ---------------------------------------------------------------------------
__global__ __launch_bounds__(512, 2) void qkattn(
    const unsigned short* __restrict__ A, const unsigned short* __restrict__ W,
    const float* __restrict__ bias, unsigned short* __restrict__ o_win)
{
    __shared__ __align__(16) unsigned short pool[65536];   // 128 KB

    int tid  = threadIdx.x;
    int w    = tid >> 6;
    int lane = tid & 63;
    int c = lane & 15, hi = lane >> 4;
    int win = blockIdx.x;
    const unsigned short* Ag = A + (size_t)win * 16384;

    // ---- stage A once (64x256), chunk-swizzled: pos p holds chunk p^(row&7)
    #pragma unroll
    for (int it = 0; it < 4; ++it) {
        int idx = it * 512 + tid;
        int row = idx >> 5, p = idx & 31;
        gload_lds16(Ag + row * 256 + ((p ^ (row & 7)) << 3),
                    &pool[(it * 512 + w * 64) * 8]);
    }

    int srow = lane >> 2;
    int scol = ((lane & 3) ^ ((lane >> 3) & 3)) * 8;
    auto stageB = [&](int buf, int k0) {
        #pragma unroll
        for (int it = 0; it < 6; ++it) {
            int row = it * 128 + w * 16 + srow;
            gload_lds16(W + (size_t)row * 256 + k0 + scol,
                        &pool[buf + (it * 512 + w * 64) * 8]);
        }
    };

    f32x4 acc[4][6] = {};
    stageB(16384, 0);
    stageB(40960, 32);
    VMWAIT(6); SBAR;                    // A + B0 landed; B1 in flight
    #pragma unroll
    for (int t = 0; t < 8; ++t) {
        int buf = (t & 1) ? 40960 : 16384;
        bf16x8 af[4], bf[6];
        #pragma unroll
        for (int mi = 0; mi < 4; ++mi) {
            int row = mi * 16 + c;
            af[mi] = *(const bf16x8*)&pool[row * 256 + (((t * 4 + hi) ^ (c & 7)) << 3)];
        }
        int hs = (hi ^ ((c >> 1) & 3)) << 3;
        #pragma unroll
        for (int ni = 0; ni < 6; ++ni)
            bf[ni] = *(const bf16x8*)&pool[buf + ((w * 6 + ni) * 16 + c) * GBK + hs];
        LGKWAIT; SBAR;
        if (t + 2 < 8) stageB(buf, (t + 2) * GBK);
        #pragma unroll
        for (int mi = 0; mi < 4; ++mi)
            #pragma unroll
            for (int ni = 0; ni < 6; ++ni)
                acc[mi][ni] = __builtin_amdgcn_mfma_f32_16x16x32_bf16(
                    af[mi], bf[ni], acc[mi][ni], 0, 0, 0);
        if (t < 7) {
            if (t + 2 < 8) { VMWAIT(6); } else { VMWAIT(0); }
            SBAR;
        }
    }
    __syncthreads();

    // ---- phase 2: QKV -> LDS (Q,K swizzled natural; V' fragmented)
    #pragma unroll
    for (int ni = 0; ni < 6; ++ni) {
        int fn = w * 6 + ni;
        int which = fn >> 4;
        int colp = ((fn & 15) << 4) + c;
        float bv = bias[(fn << 4) + c];
        #pragma unroll
        for (int mi = 0; mi < 4; ++mi) {
            #pragma unroll
            for (int r = 0; r < 4; ++r) {
                int row = mi * 16 + hi * 4 + r;
                unsigned short val = f2bf(acc[mi][ni][r] + bv);
                if (which < 2) {
                    int pos = (colp >> 3) ^ (row & 7);
                    pool[which * 16384 + row * 256 + pos * 8 + (colp & 7)] = val;
                } else {
                    pool[32768 + (((row >> 3) << 8) + colp) * 8 + (row & 7)] = val;
                }
            }
        }
    }
    __syncthreads();

    // ---- phase 3: attention, wave h = w
    int h = w;
    bf16x8 aq[4], bk[4];
    #pragma unroll
    for (int mi = 0; mi < 4; ++mi) {
        int row = mi * 16 + c;
        int pos8 = ((h * 4 + hi) ^ (c & 7)) << 3;
        aq[mi] = *(const bf16x8*)&pool[row * 256 + pos8];
        bk[mi] = *(const bf16x8*)&pool[16384 + row * 256 + pos8];
    }
    __syncthreads();                    // all waves read Q,K before P overwrite

    f32x4 sacc[4][4] = {};
    #pragma unroll
    for (int mi = 0; mi < 4; ++mi)
        #pragma unroll
        for (int ni = 0; ni < 4; ++ni)
            sacc[mi][ni] = __builtin_amdgcn_mfma_f32_16x16x32_bf16(
                aq[mi], bk[ni], sacc[mi][ni], 0, 0, 0);

    const float scale = 0.17677669529663687f;
    float inv_[4][4];
    unsigned short* Pb = &pool[h * 4096];    // 64 rows x 64 shorts, swizzled
    #pragma unroll
    for (int mi = 0; mi < 4; ++mi) {
        #pragma unroll
        for (int r = 0; r < 4; ++r) {
            float sv[4];
            float m = -1e30f;
            #pragma unroll
            for (int ni = 0; ni < 4; ++ni) {
                float v = sacc[mi][ni][r] * scale;
                v = (ni * 16 + c < L_) ? v : -1e30f;
                sv[ni] = v;
                m = fmaxf(m, v);
            }
            #pragma unroll
            for (int msk = 1; msk < 16; msk <<= 1)
                m = fmaxf(m, __shfl_xor(m, msk, 64));
            float sum = 0.f;
            unsigned short pb[4];
            #pragma unroll
            for (int ni = 0; ni < 4; ++ni) {
                float p = __expf(sv[ni] - m);
                sum += p;
                pb[ni] = f2bf(p);
            }
            #pragma unroll
            for (int msk = 1; msk < 16; msk <<= 1)
                sum += __shfl_xor(sum, msk, 64);
            inv_[mi][r] = 1.0f / sum;
            int q = mi * 16 + hi * 4 + r;
            int qs = q & 7;
            #pragma unroll
            for (int ni = 0; ni < 4; ++ni) {
                int k = ni * 16 + c;
                int pos = ((k >> 3) ^ qs);
                Pb[q * 64 + pos * 8 + (k & 7)] = pb[ni];
            }
        }
    }

    f32x4 oacc[4][2] = {};
    #pragma unroll
    for (int ks = 0; ks < 2; ++ks) {
        bf16x8 pa[4], bv[2];
        #pragma unroll
        for (int mi = 0; mi < 4; ++mi) {
            int row = mi * 16 + c;
            pa[mi] = *(const bf16x8*)&Pb[row * 64 + (((ks * 4 + hi) ^ (c & 7)) << 3)];
        }
        #pragma unroll
        for (int ni = 0; ni < 2; ++ni)
            bv[ni] = *(const bf16x8*)&pool[32768 +
                ((ks * 4 + hi) * 256 + h * HD + ni * 16 + c) * 8];
        #pragma unroll
        for (int mi = 0; mi < 4; ++mi)
            #pragma unroll
            for (int ni = 0; ni < 2; ++ni)
                oacc[mi][ni] = __builtin_amdgcn_mfma_f32_16x16x32_bf16(
                    pa[mi], bv[ni], oacc[mi][ni], 0, 0, 0);
    }

    #pragma unroll
    for (int mi = 0; mi < 4; ++mi) {
        #pragma unroll
        for (int r = 0; r < 4; ++r) {
            int q = mi * 16 + hi * 4 + r;
            if (q < L_) {
                size_t rowoff = ((size_t)(win * L_ + q)) * C_ + h * HD;
                float iv = inv_[mi][r];
                #pragma unroll
                for (int ni = 0; ni < 2; ++ni)
                    o_win[rowoff + ni * 16 + c] = f2bf(oacc[mi][ni][r] * iv);
            }
        }
    }
}

// ---------------------------------------------------------------------------
// mgemm_ln: out-proj (o_win @ wout^T + bout) + residual(x gathered) + LN2.
// 512 threads, 128 rows x full 256 cols. Counted-vmcnt dbuf (3 loads/wave).
// Outputs bf16 windowed-sequential: x1 and ln2(x1).
// ---------------------------------------------------------------------------
#define XS 260

__global__ __launch_bounds__(512) void mgemm_ln(
    const unsigned short* __restrict__ A, const unsigned short* __restrict__ W,
    const float* __restrict__ bias, const float* __restrict__ x,
    const float* __restrict__ g2, const float* __restrict__ b2,
    unsigned short* __restrict__ x1_out, unsigned short* __restrict__ ln_out)
{
    __shared__ __align__(16) unsigned short pool[128 * XS];   // 65 KB
    unsigned short* As0 = pool;
    unsigned short* As1 = pool + 4096;
    unsigned short* Bs0 = pool + 8192;
    unsigned short* Bs1 = pool + 16384;

    int tid  = threadIdx.x;
    int w    = tid >> 6;
    int lane = tid & 63;
    int wr = w >> 2, wc = w & 3;
    int bm = blockIdx.x * 128;
    int srow = lane >> 2;
    int scol = ((lane & 3) ^ ((lane >> 3) & 3)) * 8;
    int c = lane & 15, hi = lane >> 4;
    int hs = (hi ^ ((c >> 1) & 3)) * 8;

    f32x4 acc[4][4] = {};

    auto stage = [&](unsigned short* asd, unsigned short* bsd, int k0) {
        gload_lds16(A + (size_t)(bm + w * 16 + srow) * 256 + k0 + scol,
                    asd + (w * 16) * GBK);
        #pragma unroll
        for (int i = 0; i < 2; ++i) {
            int ra = w * 32 + i * 16;
            gload_lds16(W + (size_t)(ra + srow) * 256 + k0 + scol, bsd + ra * GBK);
        }
    };

    stage(As0, Bs0, 0);
    stage(As1, Bs1, GBK);
    VMWAIT(3); SBAR;
    #pragma unroll
    for (int t = 0; t < 8; ++t) {
        unsigned short* as = (t & 1) ? As1 : As0;
        unsigned short* bs = (t & 1) ? Bs1 : Bs0;
        bf16x8 af[4], bf[4];
        #pragma unroll
        for (int mi = 0; mi < 4; ++mi)
            af[mi] = *(const bf16x8*)&as[(wr * 64 + mi * 16 + c) * GBK + hs];
        #pragma unroll
        for (int ni = 0; ni < 4; ++ni)
            bf[ni] = *(const bf16x8*)&bs[(wc * 64 + ni * 16 + c) * GBK + hs];
        LGKWAIT; SBAR;
        if (t + 2 < 8) stage(as, bs, (t + 2) * GBK);
        #pragma unroll
        for (int mi = 0; mi < 4; ++mi)
            #pragma unroll
            for (int ni = 0; ni < 4; ++ni)
                acc[mi][ni] = __builtin_amdgcn_mfma_f32_16x16x32_bf16(
                    af[mi], bf[ni], acc[mi][ni], 0, 0, 0);
        if (t < 7) {
            if (t + 2 < 8) { VMWAIT(3); } else { VMWAIT(0); }
            SBAR;
        }
    }
    __syncthreads();

    #pragma unroll
    for (int mi = 0; mi < 4; ++mi) {
        #pragma unroll
        for (int ni = 0; ni < 4; ++ni) {
            int colb = wc * 64 + ni * 16 + c;
            float bv = bias[colb];
            #pragma unroll
            for (int r = 0; r < 4; ++r)
                pool[(wr * 64 + mi * 16 + hi * 4 + r) * XS + colb] =
                    f2bf(acc[mi][ni][r] + bv);
        }
    }
    __syncthreads();

    float4 gv  = *(const float4*)(g2 + lane * 4);
    float4 bv2 = *(const float4*)(b2 + lane * 4);
    #pragma unroll 2
    for (int i = 0; i < 16; ++i) {
        int tl = w * 16 + i;
        int t = bm + tl;
        int rr = t2rr(t);
        float4 xv = *(const float4*)(x + (size_t)rr * C_ + lane * 4);
        uint2 ov = *(const uint2*)&pool[tl * XS + lane * 4];
        float x0 = xv.x + bf2f(ov.x & 0xffff);
        float x1 = xv.y + bf2f(ov.x >> 16);
        float x2 = xv.z + bf2f(ov.y & 0xffff);
        float x3 = xv.w + bf2f(ov.y >> 16);
        float s  = x0 + x1 + x2 + x3;
        float ss = x0 * x0 + x1 * x1 + x2 * x2 + x3 * x3;
        #pragma unroll
        for (int m = 1; m < 64; m <<= 1) {
            s  += __shfl_xor(s, m, 64);
            ss += __shfl_xor(ss, m, 64);
        }
        float mean = s * (1.0f / C_);
        float var  = ss * (1.0f / C_) - mean * mean;
        float inv  = rsqrtf(var + 1e-5f);
        uint2 xw, lw;
        xw.x = (unsigned)f2bf(x0) | ((unsigned)f2bf(x1) << 16);
        xw.y = (unsigned)f2bf(x2) | ((unsigned)f2bf(x3) << 16);
        float l0 = (x0 - mean) * inv * gv.x + bv2.x;
        float l1 = (x1 - mean) * inv * gv.y + bv2.y;
        float l2 = (x2 - mean) * inv * gv.z + bv2.z;
        float l3 = (x3 - mean) * inv * gv.w + bv2.w;
        lw.x = (unsigned)f2bf(l0) | ((unsigned)f2bf(l1) << 16);
        lw.y = (unsigned)f2bf(l2) | ((unsigned)f2bf(l3) << 16);
        *(uint2*)(x1_out + (size_t)t * C_ + lane * 4) = xw;
        *(uint2*)(ln_out + (size_t)t * C_ + lane * 4) = lw;
    }
}

// ---------------------------------------------------------------------------
// fc1: ln2 (M_ x 256) @ w1^T + b1 -> tanh-GELU -> natural [row][512] bf16.
// Counted-vmcnt dbuf K-loop + T2 swizzle; coalesced transpose epilogue.
// ---------------------------------------------------------------------------
#define TSS 136

__global__ __launch_bounds__(256) void mgemm_g(
    const unsigned short* __restrict__ A, const unsigned short* __restrict__ W,
    const float* __restrict__ bias, unsigned short* __restrict__ outp)
{
    __shared__ __align__(16) unsigned short pool[16384];
    unsigned short* As0 = pool;
    unsigned short* As1 = pool + 4096;
    unsigned short* Bs0 = pool + 8192;
    unsigned short* Bs1 = pool + 12288;
    unsigned short* Ts  = pool;

    int tid  = threadIdx.x;
    int w    = tid >> 6;
    int lane = tid & 63;
    int wr = w >> 1, wc = w & 1;
    int bm, bn;
    xcd_decode<4>(gridDim.x, bm, bn);
    int srow = lane >> 2;
    int scol = ((lane & 3) ^ ((lane >> 3) & 3)) * 8;
    int c = lane & 15, hi = lane >> 4;
    int hs = (hi ^ ((c >> 1) & 3)) * 8;

    f32x4 acc[4][4] = {};

    auto stage = [&](unsigned short* asd, unsigned short* bsd, int k0) {
        #pragma unroll
        for (int i = 0; i < 2; ++i) {
            int ra = w * 32 + i * 16;
            gload_lds16(A + (size_t)(bm + ra + srow) * 256 + k0 + scol, asd + ra * GBK);
            gload_lds16(W + (size_t)(bn + ra + srow) * 256 + k0 + scol, bsd + ra * GBK);
        }
    };

    stage(As0, Bs0, 0);
    stage(As1, Bs1, GBK);
    VMWAIT(4); SBAR;
    #pragma unroll
    for (int t = 0; t < 8; ++t) {
        unsigned short* as = (t & 1) ? As1 : As0;
        unsigned short* bs = (t & 1) ? Bs1 : Bs0;
        bf16x8 af[4], bf[4];
        #pragma unroll
        for (int mi = 0; mi < 4; ++mi)
            af[mi] = *(const bf16x8*)&as[(wr * 64 + mi * 16 + c) * GBK + hs];
        #pragma unroll
        for (int ni = 0; ni < 4; ++ni)
            bf[ni] = *(const bf16x8*)&bs[(wc * 64 + ni * 16 + c) * GBK + hs];
        LGKWAIT; SBAR;
        if (t + 2 < 8) stage(as, bs, (t + 2) * GBK);
        #pragma unroll
        for (int mi = 0; mi < 4; ++mi)
            #pragma unroll
            for (int ni = 0; ni < 4; ++ni)
                acc[mi][ni] = __builtin_amdgcn_mfma_f32_16x16x32_bf16(
                    af[mi], bf[ni], acc[mi][ni], 0, 0, 0);
        if (t < 7) {
            if (t + 2 < 8) { VMWAIT(4); } else { VMWAIT(0); }
            SBAR;
        }
    }
    __syncthreads();

    #pragma unroll
    for (int ch = 0; ch < 2; ++ch) {
        if (wr == ch) {
            #pragma unroll
            for (int mi = 0; mi < 4; ++mi)
                #pragma unroll
                for (int ni = 0; ni < 4; ++ni) {
                    int colb = wc * 64 + ni * 16 + c;
                    float bv = bias[bn + colb];
                    #pragma unroll
                    for (int r = 0; r < 4; ++r) {
                        float v = acc[mi][ni][r] + bv;
                        float a = 1.5957691216f * (v + 0.044715f * v * v * v);
                        float g = v / (1.0f + __expf(-a));
                        Ts[(mi * 16 + hi * 4 + r) * TSS + colb] = f2bf(g);
                    }
                }
        }
        __syncthreads();
        #pragma unroll
        for (int it = 0; it < 4; ++it) {
            int id = it * 256 + tid;
            int row = id >> 4, cx = (id & 15) * 8;
            uint4 v = *(const uint4*)&Ts[row * TSS + cx];
            *(uint4*)&outp[(size_t)(bm + ch * 64 + row) * MLPH + bn + cx] = v;
        }
        __syncthreads();
    }
}

// ---------------------------------------------------------------------------
// fc2: gelu (M_ x 512) @ w2^T + b2 + residual(x1 bf16 windowed) -> natural f32.
// Counted-vmcnt dbuf (NT=16) + swizzle; LDS-transposed coalesced epilogue.
// ---------------------------------------------------------------------------
__global__ __launch_bounds__(256) void mgemm_out(
    const unsigned short* __restrict__ A, const unsigned short* __restrict__ W,
    const float* __restrict__ bias, const unsigned short* __restrict__ x1,
    float* __restrict__ dout)
{
    __shared__ __align__(16) unsigned short pool[16896];
    unsigned short* As0 = pool;
    unsigned short* As1 = pool + 4096;
    unsigned short* Bs0 = pool + 8192;
    unsigned short* Bs1 = pool + 12288;
    float* stg = (float*)pool;

    int tid  = threadIdx.x;
    int w    = tid >> 6;
    int lane = tid & 63;
    int wr = w >> 1, wc = w & 1;
    int bm, bn;
    xcd_decode<2>(gridDim.x, bm, bn);
    int srow = lane >> 2;
    int scol = ((lane & 3) ^ ((lane >> 3) & 3)) * 8;
    int c = lane & 15, hi = lane >> 4;
    int hs = (hi ^ ((c >> 1) & 3)) * 8;

    f32x4 acc[4][4] = {};

    auto stage = [&](unsigned short* asd, unsigned short* bsd, int k0) {
        #pragma unroll
        for (int i = 0; i < 2; ++i) {
            int ra = w * 32 + i * 16;
            gload_lds16(A + (size_t)(bm + ra + srow) * 512 + k0 + scol, asd + ra * GBK);
            gload_lds16(W + (size_t)(bn + ra + srow) * 512 + k0 + scol, bsd + ra * GBK);
        }
    };

    stage(As0, Bs0, 0);
    stage(As1, Bs1, GBK);
    VMWAIT(4); SBAR;
    #pragma unroll
    for (int t = 0; t < 16; ++t) {
        unsigned short* as = (t & 1) ? As1 : As0;
        unsigned short* bs = (t & 1) ? Bs1 : Bs0;
        bf16x8 af[4], bf[4];
        #pragma unroll
        for (int mi = 0; mi < 4; ++mi)
            af[mi] = *(const bf16x8*)&as[(wr * 64 + mi * 16 + c) * GBK + hs];
        #pragma unroll
        for (int ni = 0; ni < 4; ++ni)
            bf[ni] = *(const bf16x8*)&bs[(wc * 64 + ni * 16 + c) * GBK + hs];
        LGKWAIT; SBAR;
        if (t + 2 < 16) stage(as, bs, (t + 2) * GBK);
        #pragma unroll
        for (int mi = 0; mi < 4; ++mi)
            #pragma unroll
            for (int ni = 0; ni < 4; ++ni)
                acc[mi][ni] = __builtin_amdgcn_mfma_f32_16x16x32_bf16(
                    af[mi], bf[ni], acc[mi][ni], 0, 0, 0);
        if (t < 15) {
            if (t + 2 < 16) { VMWAIT(4); } else { VMWAIT(0); }
            SBAR;
        }
    }
    __syncthreads();

    #pragma unroll
    for (int c2 = 0; c2 < 4; ++c2) {
        if (wr == (c2 >> 1)) {
            int mi0 = (c2 & 1) * 2;
            #pragma unroll
            for (int mm = 0; mm < 2; ++mm) {
                #pragma unroll
                for (int ni = 0; ni < 4; ++ni) {
                    int colb = wc * 64 + ni * 16 + c;
                    float bv = bias[bn + colb];
                    #pragma unroll
                    for (int r = 0; r < 4; ++r)
                        stg[(mm * 16 + hi * 4 + r) * 132 + colb] =
                            acc[mi0 + mm][ni][r] + bv;
                }
            }
        }
        __syncthreads();
        #pragma unroll
        for (int i = 0; i < 4; ++i) {
            int lr = i * 8 + (tid >> 5);
            int t = bm + c2 * 32 + lr;
            int rr = t2rr(t);
            int col4 = (tid & 31) * 4;
            float4 v = *(const float4*)&stg[lr * 132 + col4];
            uint2 rv = *(const uint2*)&x1[(size_t)t * C_ + bn + col4];
            v.x += bf2f(rv.x & 0xffff);
            v.y += bf2f(rv.x >> 16);
            v.z += bf2f(rv.y & 0xffff);
            v.w += bf2f(rv.y >> 16);
            *(float4*)&dout[(size_t)rr * C_ + bn + col4] = v;
        }
        __syncthreads();
    }
}

// ---------------------------------------------------------------------------
extern "C" void kernel_launch(void* const* d_in, const int* in_sizes, int n_in,
                              void* d_out, int out_size, void* d_ws, size_t ws_size,
                              hipStream_t stream)
{
    (void)in_sizes; (void)n_in; (void)out_size; (void)ws_size;
    const float* x    = (const float*)d_in[0];
    const float* n1g  = (const float*)d_in[3];
    const float* n1b  = (const float*)d_in[4];
    const float* wqkv = (const float*)d_in[5];
    const float* bqkv = (const float*)d_in[6];
    const float* wout = (const float*)d_in[7];
    const float* bout = (const float*)d_in[8];
    const float* n2g  = (const float*)d_in[9];
    const float* n2b  = (const float*)d_in[10];
    const float* w1   = (const float*)d_in[11];
    const float* b1   = (const float*)d_in[12];
    const float* w2   = (const float*)d_in[13];
    const float* b2   = (const float*)d_in[14];
    float* out = (float*)d_out;

    // workspace layout (bf16 shorts), ~326 MB
    unsigned short* lnq    = (unsigned short*)d_ws;            // MP*256
    unsigned short* o_win  = lnq + (size_t)MP * C_;            // M_*256
    unsigned short* x1_bf  = o_win + (size_t)M_ * C_;          // M_*256
    unsigned short* ln2_bf = x1_bf + (size_t)M_ * C_;          // M_*256
    unsigned short* gelu   = ln2_bf + (size_t)M_ * C_;         // M_*512
    unsigned short* wqkv_bf = gelu + (size_t)M_ * MLPH;
    unsigned short* wout_bf = wqkv_bf + 768 * 256;
    unsigned short* w1_bf   = wout_bf + 256 * 256;
    unsigned short* w2_bf   = w1_bf + 512 * 256;

    // 0) weights -> bf16
    cvt_kernel<<<(768 * 256 + 255) / 256, 256, 0, stream>>>(wqkv, wqkv_bf, 768 * 256);
    cvt_kernel<<<(256 * 256 + 255) / 256, 256, 0, stream>>>(wout, wout_bf, 256 * 256);
    cvt_kernel<<<(512 * 256 + 255) / 256, 256, 0, stream>>>(w1, w1_bf, 512 * 256);
    cvt_kernel<<<(256 * 512 + 255) / 256, 256, 0, stream>>>(w2, w2_bf, 256 * 512);

    // 1) LN1 gather -> padded [win][64][256] (zeros in pad rows)
    ln_kernel<<<MP / 4, 256, 0, stream>>>(x, n1g, n1b, lnq);

    // 2) FUSED QKV + window attention -> o_win (49-based rows x 256)
    qkattn<<<NWIN, 512, 0, stream>>>(lnq, wqkv_bf, bqkv, o_win);

    // 3) out-proj + residual + LN2 fused -> x1_bf, ln2_bf
    mgemm_ln<<<M_ / 128, 512, 0, stream>>>(
        o_win, wout_bf, bout, x, n2g, n2b, x1_bf, ln2_bf);

    // 4) MLP fc1 + tanh-GELU -> gelu [M_ x 512] natural
    mgemm_g<<<(M_ / 128) * 4, 256, 0, stream>>>(ln2_bf, w1_bf, b1, gelu);

    // 5) MLP fc2 + residual(x1) -> d_out natural f32
    mgemm_out<<<(M_ / 128) * 2, 256, 0, stream>>>(gelu, w2_bf, b2, x1_bf, out);
}

// Round 11
// 421.021 us; speedup vs baseline: 1.6231x; 1.0642x over previous
//
#include <hip/hip_runtime.h>
#include <hip/hip_bf16.h>
#include <math.h>

// Problem constants (B=32, H=W=56, C=256, heads=8, hd=32, ws=7)
#define NTOK 3136            // 56*56
#define C_ 256
#define HEADS_ 8
#define HD 32
#define WS_ 7
#define L_ 49
#define NWIN 2048            // 32 * 8 * 8
#define NWH 16384            // NWIN * HEADS_
#define M_ 100352            // NWIN * 49  == BATCH*NTOK
#define MLPH 512
#define WHSZ 2048            // 64 (padded L) * 32 (hd) elems per (win,head) plane

typedef __bf16 bf16x8 __attribute__((ext_vector_type(8)));
typedef float f32x4 __attribute__((ext_vector_type(4)));

__device__ __forceinline__ unsigned short f2bf(float f) {
    union { float f; unsigned u; } v; v.f = f;
    unsigned r = v.u + 0x7fffu + ((v.u >> 16) & 1u);   // RNE
    return (unsigned short)(r >> 16);
}
__device__ __forceinline__ float bf2f(unsigned short s) {
    union { unsigned u; float f; } v; v.u = ((unsigned)s) << 16;
    return v.f;
}

// windowed token index (49-based) -> natural row index
__device__ __forceinline__ int t2rr(int t) {
    int win = t / L_;
    int l   = t - win * L_;
    int b_  = win >> 6, wh = (win >> 3) & 7, ww = win & 7;
    int ld7 = l / WS_;
    int y   = wh * WS_ + ld7;
    int xc  = ww * WS_ + (l - ld7 * WS_);
    return b_ * NTOK + y * 56 + xc;
}

// XCD-chunked bm-major remap (L2 reuse of the A stripe per XCD)
template <int NBN>
__device__ __forceinline__ void xcd_decode(int nb, int& bm, int& bn) {
    int h = blockIdx.x;
    int fid = (h & 7) * (nb >> 3) + (h >> 3);
    int bmi = fid / NBN;
    bm = bmi * 128;
    bn = (fid - bmi * NBN) * 128;
}

// ---------------------------------------------------------------------------
__global__ __launch_bounds__(256) void cvt_kernel(
    const float* __restrict__ in, unsigned short* __restrict__ out, int n)
{
    int i = blockIdx.x * 256 + threadIdx.x;
    if (i < n) out[i] = f2bf(in[i]);
}

// ---------------------------------------------------------------------------
// LN1: one wave per token; bf16 output in windowed row order (M_ rows).
// ---------------------------------------------------------------------------
__global__ __launch_bounds__(256) void ln_kernel(
    const float* __restrict__ x, const float* __restrict__ gamma,
    const float* __restrict__ beta, unsigned short* __restrict__ out)
{
    int wave = threadIdx.x >> 6;
    int lane = threadIdx.x & 63;
    int p = blockIdx.x * 4 + wave;
    const float* row = x + (size_t)p * C_;
    float4 v = *(const float4*)(row + lane * 4);
    float s  = v.x + v.y + v.z + v.w;
    float ss = v.x * v.x + v.y * v.y + v.z * v.z + v.w * v.w;
    #pragma unroll
    for (int m = 1; m < 64; m <<= 1) {
        s  += __shfl_xor(s, m, 64);
        ss += __shfl_xor(ss, m, 64);
    }
    float mean = s * (1.0f / C_);
    float var  = ss * (1.0f / C_) - mean * mean;
    float inv  = rsqrtf(var + 1e-5f);
    float4 gv = *(const float4*)(gamma + lane * 4);
    float4 bv = *(const float4*)(beta + lane * 4);
    int b_ = p / NTOK, n = p - b_ * NTOK;
    int y = n / 56, xc = n - y * 56;
    int win = (b_ * 8 + y / WS_) * 8 + xc / WS_;
    int l   = (y % WS_) * WS_ + (xc % WS_);
    size_t orow = (size_t)(win * L_ + l) * C_;
    unsigned short o[4];
    o[0] = f2bf((v.x - mean) * inv * gv.x + bv.x);
    o[1] = f2bf((v.y - mean) * inv * gv.y + bv.y);
    o[2] = f2bf((v.z - mean) * inv * gv.z + bv.z);
    o[3] = f2bf((v.w - mean) * inv * gv.w + bv.w);
    *(uint2*)(out + orow + lane * 4) = *(const uint2*)o;
}

// ---------------------------------------------------------------------------
#define GBK 32

__device__ __forceinline__ void gload_lds16(const void* g, void* l) {
    __builtin_amdgcn_global_load_lds(
        (const __attribute__((address_space(1))) unsigned*)g,
        (__attribute__((address_space(3))) unsigned*)l, 16, 0, 0);
}

// ---------------------------------------------------------------------------
// QKV GEMM (R5 structure): A (M_ x 256 windowed) @ wqkv^T -> scatter to
// per-(win,head) planes: Q,K [wh][l*32+d], V pre-fragmented [wh][kb][d][kj].
// Single-buffer 2-barrier K-loop + T2 swizzle (conflict-free, 16 KB LDS).
// Grid (M_/128)*6, XCD-chunked.
// ---------------------------------------------------------------------------
__global__ __launch_bounds__(256) void mgemm_qkv(
    const unsigned short* __restrict__ A, const unsigned short* __restrict__ W,
    const float* __restrict__ bias, unsigned short* __restrict__ qkv)
{
    __shared__ __align__(16) unsigned short As[4096];   // 128x32
    __shared__ __align__(16) unsigned short Bs[4096];   // 128x32

    int tid  = threadIdx.x;
    int w    = tid >> 6;
    int lane = tid & 63;
    int wr = w >> 1, wc = w & 1;
    int bm, bn;
    xcd_decode<6>(gridDim.x, bm, bn);
    int srow = lane >> 2;
    int scol = ((lane & 3) ^ ((lane >> 3) & 3)) * 8;  // T2 inverse-swizzled src
    int c = lane & 15, hi = lane >> 4;
    int hs = (hi ^ ((c >> 1) & 3)) * 8;               // T2 swizzled read chunk

    f32x4 acc[4][4] = {};

    for (int k0 = 0; k0 < 256; k0 += GBK) {
        #pragma unroll
        for (int i = 0; i < 2; ++i) {
            int ra = w * 32 + i * 16;
            gload_lds16(A + (size_t)(bm + ra + srow) * 256 + k0 + scol, As + ra * GBK);
            gload_lds16(W + (size_t)(bn + ra + srow) * 256 + k0 + scol, Bs + ra * GBK);
        }
        __syncthreads();
        bf16x8 af[4], bf[4];
        #pragma unroll
        for (int mi = 0; mi < 4; ++mi)
            af[mi] = *(const bf16x8*)&As[(wr * 64 + mi * 16 + c) * GBK + hs];
        #pragma unroll
        for (int ni = 0; ni < 4; ++ni)
            bf[ni] = *(const bf16x8*)&Bs[(wc * 64 + ni * 16 + c) * GBK + hs];
        #pragma unroll
        for (int mi = 0; mi < 4; ++mi)
            #pragma unroll
            for (int ni = 0; ni < 4; ++ni)
                acc[mi][ni] = __builtin_amdgcn_mfma_f32_16x16x32_bf16(
                    af[mi], bf[ni], acc[mi][ni], 0, 0, 0);
        __syncthreads();
    }

    // scatter epilogue: planes (compact per-head; mattn reads contiguously)
    #pragma unroll
    for (int mi = 0; mi < 4; ++mi) {
        #pragma unroll
        for (int r = 0; r < 4; ++r) {
            int row = bm + wr * 64 + mi * 16 + hi * 4 + r;
            int win = row / L_, l = row - win * L_;
            #pragma unroll
            for (int ni = 0; ni < 4; ++ni) {
                int col = bn + wc * 64 + ni * 16 + c;
                float val = acc[mi][ni][r] + bias[col];
                int which = col >> 8;
                int head  = (col >> 5) & 7;
                int d     = col & 31;
                int wh = win * HEADS_ + head;
                size_t base = (size_t)which * ((size_t)NWH * WHSZ) + (size_t)wh * WHSZ;
                size_t off;
                if (which == 2)
                    off = base + (size_t)(((l >> 3) * HD + d) << 3) + (l & 7);
                else
                    off = base + (size_t)l * HD + d;
                qkv[off] = f2bf(val);
            }
        }
    }
}

// ---------------------------------------------------------------------------
// MFMA window attention (R5): 4 waves/block, wave = one (win,head).
// Reads compact planes (fully coalesced per wave). P via LDS (72-stride).
// ---------------------------------------------------------------------------
__global__ __launch_bounds__(256) void mattn(
    const unsigned short* __restrict__ qkv, unsigned short* __restrict__ o_win)
{
    __shared__ __align__(16) unsigned short P_lds[4][64][72];
    int wave = threadIdx.x >> 6, lane = threadIdx.x & 63;
    int c = lane & 15, hi = lane >> 4;
    int wh = blockIdx.x * 4 + wave;
    int win = wh >> 3, head = wh & 7;
    const unsigned short* qb = qkv + (size_t)wh * WHSZ;
    const unsigned short* kb = qb + (size_t)NWH * WHSZ;
    const unsigned short* vb = kb + (size_t)NWH * WHSZ;

    bf16x8 af[4], bk[4];
    #pragma unroll
    for (int mi = 0; mi < 4; ++mi)
        af[mi] = *(const bf16x8*)(qb + (mi * 16 + c) * HD + hi * 8);
    #pragma unroll
    for (int ni = 0; ni < 4; ++ni)
        bk[ni] = *(const bf16x8*)(kb + (ni * 16 + c) * HD + hi * 8);

    f32x4 sacc[4][4] = {};
    #pragma unroll
    for (int mi = 0; mi < 4; ++mi)
        #pragma unroll
        for (int ni = 0; ni < 4; ++ni)
            sacc[mi][ni] = __builtin_amdgcn_mfma_f32_16x16x32_bf16(
                af[mi], bk[ni], sacc[mi][ni], 0, 0, 0);

    const float scale = 0.17677669529663687f;
    float inv_[4][4];
    #pragma unroll
    for (int mi = 0; mi < 4; ++mi) {
        #pragma unroll
        for (int r = 0; r < 4; ++r) {
            float sv[4];
            float m = -1e30f;
            #pragma unroll
            for (int ni = 0; ni < 4; ++ni) {
                float v = sacc[mi][ni][r] * scale;
                v = (ni * 16 + c < L_) ? v : -1e30f;
                sv[ni] = v;
                m = fmaxf(m, v);
            }
            #pragma unroll
            for (int msk = 1; msk < 16; msk <<= 1)
                m = fmaxf(m, __shfl_xor(m, msk, 64));
            float sum = 0.f;
            unsigned short pb[4];
            #pragma unroll
            for (int ni = 0; ni < 4; ++ni) {
                float p = __expf(sv[ni] - m);
                sum += p;
                pb[ni] = f2bf(p);
            }
            #pragma unroll
            for (int msk = 1; msk < 16; msk <<= 1)
                sum += __shfl_xor(sum, msk, 64);
            inv_[mi][r] = 1.0f / sum;
            int q = mi * 16 + hi * 4 + r;
            #pragma unroll
            for (int ni = 0; ni < 4; ++ni)
                P_lds[wave][q][ni * 16 + c] = pb[ni];
        }
    }

    f32x4 oacc[4][2] = {};
    #pragma unroll
    for (int ks = 0; ks < 2; ++ks) {
        bf16x8 pa[4], bv[2];
        #pragma unroll
        for (int mi = 0; mi < 4; ++mi)
            pa[mi] = *(const bf16x8*)&P_lds[wave][mi * 16 + c][ks * 32 + hi * 8];
        #pragma unroll
        for (int ni = 0; ni < 2; ++ni)
            bv[ni] = *(const bf16x8*)(vb + ((ks * 4 + hi) * HD + ni * 16 + c) * 8);
        #pragma unroll
        for (int mi = 0; mi < 4; ++mi)
            #pragma unroll
            for (int ni = 0; ni < 2; ++ni)
                oacc[mi][ni] = __builtin_amdgcn_mfma_f32_16x16x32_bf16(
                    pa[mi], bv[ni], oacc[mi][ni], 0, 0, 0);
    }

    #pragma unroll
    for (int mi = 0; mi < 4; ++mi) {
        #pragma unroll
        for (int r = 0; r < 4; ++r) {
            int q = mi * 16 + hi * 4 + r;
            if (q < L_) {
                size_t rowoff = ((size_t)(win * L_ + q)) * C_ + head * HD;
                float iv = inv_[mi][r];
                #pragma unroll
                for (int ni = 0; ni < 2; ++ni)
                    o_win[rowoff + ni * 16 + c] = f2bf(oacc[mi][ni][r] * iv);
            }
        }
    }
}

// ---------------------------------------------------------------------------
// mgemm_ln: out-proj (o_win @ wout^T + bout) + residual(x gathered f32) + LN2.
// 512 threads, 128 rows x full 256 cols. Single-buffer + T2 swizzle.
// Outputs bf16 windowed-sequential: x1 and ln2(x1).
// ---------------------------------------------------------------------------
#define XS 260

__global__ __launch_bounds__(512) void mgemm_ln(
    const unsigned short* __restrict__ A, const unsigned short* __restrict__ W,
    const float* __restrict__ bias, const float* __restrict__ x,
    const float* __restrict__ g2, const float* __restrict__ b2,
    unsigned short* __restrict__ x1_out, unsigned short* __restrict__ ln_out)
{
    __shared__ __align__(16) unsigned short pool[128 * XS];   // 65 KB
    unsigned short* As = pool;            // 4096 shorts
    unsigned short* Bs = pool + 4096;     // 8192 shorts

    int tid  = threadIdx.x;
    int w    = tid >> 6;          // 0..7
    int lane = tid & 63;
    int wr = w >> 2, wc = w & 3;  // 2 x 4 wave tiles of 64x64
    int bm = blockIdx.x * 128;
    int srow = lane >> 2;
    int scol = ((lane & 3) ^ ((lane >> 3) & 3)) * 8;
    int c = lane & 15, hi = lane >> 4;
    int hs = (hi ^ ((c >> 1) & 3)) * 8;

    f32x4 acc[4][4] = {};

    for (int k0 = 0; k0 < 256; k0 += GBK) {
        gload_lds16(A + (size_t)(bm + w * 16 + srow) * 256 + k0 + scol,
                    As + (w * 16) * GBK);
        #pragma unroll
        for (int i = 0; i < 2; ++i) {
            int ra = w * 32 + i * 16;
            gload_lds16(W + (size_t)(ra + srow) * 256 + k0 + scol, Bs + ra * GBK);
        }
        __syncthreads();
        bf16x8 af[4], bf[4];
        #pragma unroll
        for (int mi = 0; mi < 4; ++mi)
            af[mi] = *(const bf16x8*)&As[(wr * 64 + mi * 16 + c) * GBK + hs];
        #pragma unroll
        for (int ni = 0; ni < 4; ++ni)
            bf[ni] = *(const bf16x8*)&Bs[(wc * 64 + ni * 16 + c) * GBK + hs];
        #pragma unroll
        for (int mi = 0; mi < 4; ++mi)
            #pragma unroll
            for (int ni = 0; ni < 4; ++ni)
                acc[mi][ni] = __builtin_amdgcn_mfma_f32_16x16x32_bf16(
                    af[mi], bf[ni], acc[mi][ni], 0, 0, 0);
        __syncthreads();
    }

    // stage o (+bias) to LDS bf16
    #pragma unroll
    for (int mi = 0; mi < 4; ++mi) {
        #pragma unroll
        for (int ni = 0; ni < 4; ++ni) {
            int colb = wc * 64 + ni * 16 + c;
            float bv = bias[colb];
            #pragma unroll
            for (int r = 0; r < 4; ++r)
                pool[(wr * 64 + mi * 16 + hi * 4 + r) * XS + colb] =
                    f2bf(acc[mi][ni][r] + bv);
        }
    }
    __syncthreads();

    float4 gv  = *(const float4*)(g2 + lane * 4);
    float4 bv2 = *(const float4*)(b2 + lane * 4);
    #pragma unroll 2
    for (int i = 0; i < 16; ++i) {
        int tl = w * 16 + i;
        int t = bm + tl;
        int rr = t2rr(t);
        float4 xv = *(const float4*)(x + (size_t)rr * C_ + lane * 4);
        uint2 ov = *(const uint2*)&pool[tl * XS + lane * 4];
        float x0 = xv.x + bf2f(ov.x & 0xffff);
        float x1 = xv.y + bf2f(ov.x >> 16);
        float x2 = xv.z + bf2f(ov.y & 0xffff);
        float x3 = xv.w + bf2f(ov.y >> 16);
        float s  = x0 + x1 + x2 + x3;
        float ss = x0 * x0 + x1 * x1 + x2 * x2 + x3 * x3;
        #pragma unroll
        for (int m = 1; m < 64; m <<= 1) {
            s  += __shfl_xor(s, m, 64);
            ss += __shfl_xor(ss, m, 64);
        }
        float mean = s * (1.0f / C_);
        float var  = ss * (1.0f / C_) - mean * mean;
        float inv  = rsqrtf(var + 1e-5f);
        uint2 xw, lw;
        xw.x = (unsigned)f2bf(x0) | ((unsigned)f2bf(x1) << 16);
        xw.y = (unsigned)f2bf(x2) | ((unsigned)f2bf(x3) << 16);
        float l0 = (x0 - mean) * inv * gv.x + bv2.x;
        float l1 = (x1 - mean) * inv * gv.y + bv2.y;
        float l2 = (x2 - mean) * inv * gv.z + bv2.z;
        float l3 = (x3 - mean) * inv * gv.w + bv2.w;
        lw.x = (unsigned)f2bf(l0) | ((unsigned)f2bf(l1) << 16);
        lw.y = (unsigned)f2bf(l2) | ((unsigned)f2bf(l3) << 16);
        *(uint2*)(x1_out + (size_t)t * C_ + lane * 4) = xw;
        *(uint2*)(ln_out + (size_t)t * C_ + lane * 4) = lw;
    }
}

// ---------------------------------------------------------------------------
// fc1: ln2 (M_ x 256) @ w1^T + b1 -> tanh-GELU -> natural [row][512] bf16.
// Single-buffer + swizzle; coalesced Ts-transpose epilogue (uint4 stores).
// ---------------------------------------------------------------------------
#define TSS 136

__global__ __launch_bounds__(256) void mgemm_g(
    const unsigned short* __restrict__ A, const unsigned short* __restrict__ W,
    const float* __restrict__ bias, unsigned short* __restrict__ outp)
{
    __shared__ __align__(16) unsigned short pool[64 * TSS];   // 17.4 KB
    unsigned short* As = pool;
    unsigned short* Bs = pool + 4096;
    unsigned short* Ts = pool;

    int tid  = threadIdx.x;
    int w    = tid >> 6;
    int lane = tid & 63;
    int wr = w >> 1, wc = w & 1;
    int bm, bn;
    xcd_decode<4>(gridDim.x, bm, bn);
    int srow = lane >> 2;
    int scol = ((lane & 3) ^ ((lane >> 3) & 3)) * 8;
    int c = lane & 15, hi = lane >> 4;
    int hs = (hi ^ ((c >> 1) & 3)) * 8;

    f32x4 acc[4][4] = {};

    for (int k0 = 0; k0 < 256; k0 += GBK) {
        #pragma unroll
        for (int i = 0; i < 2; ++i) {
            int ra = w * 32 + i * 16;
            gload_lds16(A + (size_t)(bm + ra + srow) * 256 + k0 + scol, As + ra * GBK);
            gload_lds16(W + (size_t)(bn + ra + srow) * 256 + k0 + scol, Bs + ra * GBK);
        }
        __syncthreads();
        bf16x8 af[4], bf[4];
        #pragma unroll
        for (int mi = 0; mi < 4; ++mi)
            af[mi] = *(const bf16x8*)&As[(wr * 64 + mi * 16 + c) * GBK + hs];
        #pragma unroll
        for (int ni = 0; ni < 4; ++ni)
            bf[ni] = *(const bf16x8*)&Bs[(wc * 64 + ni * 16 + c) * GBK + hs];
        #pragma unroll
        for (int mi = 0; mi < 4; ++mi)
            #pragma unroll
            for (int ni = 0; ni < 4; ++ni)
                acc[mi][ni] = __builtin_amdgcn_mfma_f32_16x16x32_bf16(
                    af[mi], bf[ni], acc[mi][ni], 0, 0, 0);
        __syncthreads();
    }

    #pragma unroll
    for (int ch = 0; ch < 2; ++ch) {
        if (wr == ch) {
            #pragma unroll
            for (int mi = 0; mi < 4; ++mi)
                #pragma unroll
                for (int ni = 0; ni < 4; ++ni) {
                    int colb = wc * 64 + ni * 16 + c;
                    float bv = bias[bn + colb];
                    #pragma unroll
                    for (int r = 0; r < 4; ++r) {
                        float v = acc[mi][ni][r] + bv;
                        float a = 1.5957691216f * (v + 0.044715f * v * v * v);
                        float g = v / (1.0f + __expf(-a));
                        Ts[(mi * 16 + hi * 4 + r) * TSS + colb] = f2bf(g);
                    }
                }
        }
        __syncthreads();
        #pragma unroll
        for (int it = 0; it < 4; ++it) {
            int id = it * 256 + tid;
            int row = id >> 4, cx = (id & 15) * 8;
            uint4 v = *(const uint4*)&Ts[row * TSS + cx];
            *(uint4*)&outp[(size_t)(bm + ch * 64 + row) * MLPH + bn + cx] = v;
        }
        __syncthreads();
    }
}

// ---------------------------------------------------------------------------
// fc2: gelu (M_ x 512) @ w2^T + b2 + residual(x1 bf16 windowed) -> natural f32.
// Single-buffer + swizzle; LDS-transposed coalesced epilogue. NBN=2.
// ---------------------------------------------------------------------------
__global__ __launch_bounds__(256) void mgemm_out(
    const unsigned short* __restrict__ A, const unsigned short* __restrict__ W,
    const float* __restrict__ bias, const unsigned short* __restrict__ x1,
    float* __restrict__ dout)
{
    __shared__ __align__(16) unsigned short pool[8704];   // 17 KB
    unsigned short* As = pool;
    unsigned short* Bs = pool + 4096;
    float* stg = (float*)pool;                            // 32 x 132 f32

    int tid  = threadIdx.x;
    int w    = tid >> 6;
    int lane = tid & 63;
    int wr = w >> 1, wc = w & 1;
    int bm, bn;
    xcd_decode<2>(gridDim.x, bm, bn);
    int srow = lane >> 2;
    int scol = ((lane & 3) ^ ((lane >> 3) & 3)) * 8;
    int c = lane & 15, hi = lane >> 4;
    int hs = (hi ^ ((c >> 1) & 3)) * 8;

    f32x4 acc[4][4] = {};

    for (int k0 = 0; k0 < 512; k0 += GBK) {
        #pragma unroll
        for (int i = 0; i < 2; ++i) {
            int ra = w * 32 + i * 16;
            gload_lds16(A + (size_t)(bm + ra + srow) * 512 + k0 + scol, As + ra * GBK);
            gload_lds16(W + (size_t)(bn + ra + srow) * 512 + k0 + scol, Bs + ra * GBK);
        }
        __syncthreads();
        bf16x8 af[4], bf[4];
        #pragma unroll
        for (int mi = 0; mi < 4; ++mi)
            af[mi] = *(const bf16x8*)&As[(wr * 64 + mi * 16 + c) * GBK + hs];
        #pragma unroll
        for (int ni = 0; ni < 4; ++ni)
            bf[ni] = *(const bf16x8*)&Bs[(wc * 64 + ni * 16 + c) * GBK + hs];
        #pragma unroll
        for (int mi = 0; mi < 4; ++mi)
            #pragma unroll
            for (int ni = 0; ni < 4; ++ni)
                acc[mi][ni] = __builtin_amdgcn_mfma_f32_16x16x32_bf16(
                    af[mi], bf[ni], acc[mi][ni], 0, 0, 0);
        __syncthreads();
    }

    #pragma unroll
    for (int c2 = 0; c2 < 4; ++c2) {
        if (wr == (c2 >> 1)) {
            int mi0 = (c2 & 1) * 2;
            #pragma unroll
            for (int mm = 0; mm < 2; ++mm) {
                #pragma unroll
                for (int ni = 0; ni < 4; ++ni) {
                    int colb = wc * 64 + ni * 16 + c;
                    float bv = bias[bn + colb];
                    #pragma unroll
                    for (int r = 0; r < 4; ++r)
                        stg[(mm * 16 + hi * 4 + r) * 132 + colb] =
                            acc[mi0 + mm][ni][r] + bv;
                }
            }
        }
        __syncthreads();
        #pragma unroll
        for (int i = 0; i < 4; ++i) {
            int lr = i * 8 + (tid >> 5);         // 0..31
            int t = bm + c2 * 32 + lr;
            int rr = t2rr(t);
            int col4 = (tid & 31) * 4;
            float4 v = *(const float4*)&stg[lr * 132 + col4];
            uint2 rv = *(const uint2*)&x1[(size_t)t * C_ + bn + col4];
            v.x += bf2f(rv.x & 0xffff);
            v.y += bf2f(rv.x >> 16);
            v.z += bf2f(rv.y & 0xffff);
            v.w += bf2f(rv.y >> 16);
            *(float4*)&dout[(size_t)rr * C_ + bn + col4] = v;
        }
        __syncthreads();
    }
}

// ---------------------------------------------------------------------------
extern "C" void kernel_launch(void* const* d_in, const int* in_sizes, int n_in,
                              void* d_out, int out_size, void* d_ws, size_t ws_size,
                              hipStream_t stream)
{
    (void)in_sizes; (void)n_in; (void)out_size; (void)ws_size;
    const float* x    = (const float*)d_in[0];
    const float* n1g  = (const float*)d_in[3];
    const float* n1b  = (const float*)d_in[4];
    const float* wqkv = (const float*)d_in[5];
    const float* bqkv = (const float*)d_in[6];
    const float* wout = (const float*)d_in[7];
    const float* bout = (const float*)d_in[8];
    const float* n2g  = (const float*)d_in[9];
    const float* n2b  = (const float*)d_in[10];
    const float* w1   = (const float*)d_in[11];
    const float* b1   = (const float*)d_in[12];
    const float* w2   = (const float*)d_in[13];
    const float* b2   = (const float*)d_in[14];
    float* out = (float*)d_out;

    // workspace layout (bf16 shorts)
    unsigned short* bufA_bf = (unsigned short*)d_ws;                 // M*256 (LN1 out, then o_win)
    unsigned short* qkv_bf  = bufA_bf + (size_t)M_ * C_;             // 3*NWH*2048 (Q,K,V'; later gelu M*512)
    unsigned short* x1_bf   = qkv_bf + (size_t)3 * NWH * WHSZ;       // M*256
    unsigned short* ln2_bf  = x1_bf + (size_t)M_ * C_;               // M*256
    unsigned short* wqkv_bf = ln2_bf + (size_t)M_ * C_;
    unsigned short* wout_bf = wqkv_bf + 768 * 256;
    unsigned short* w1_bf   = wout_bf + 256 * 256;
    unsigned short* w2_bf   = w1_bf + 512 * 256;
    unsigned short* gelu    = qkv_bf;   // alias (qkv dead after mattn)

    // 0) weights -> bf16
    cvt_kernel<<<(768 * 256 + 255) / 256, 256, 0, stream>>>(wqkv, wqkv_bf, 768 * 256);
    cvt_kernel<<<(256 * 256 + 255) / 256, 256, 0, stream>>>(wout, wout_bf, 256 * 256);
    cvt_kernel<<<(512 * 256 + 255) / 256, 256, 0, stream>>>(w1, w1_bf, 512 * 256);
    cvt_kernel<<<(256 * 512 + 255) / 256, 256, 0, stream>>>(w2, w2_bf, 256 * 512);

    // 1) LN1 + window partition -> bufA_bf
    ln_kernel<<<M_ / 4, 256, 0, stream>>>(x, n1g, n1b, bufA_bf);

    // 2) QKV GEMM -> Q/K/V' planes (XCD-chunked)
    mgemm_qkv<<<(M_ / 128) * 6, 256, 0, stream>>>(
        bufA_bf, wqkv_bf, bqkv, qkv_bf);

    // 3) MFMA window attention -> o_win (bufA_bf)
    mattn<<<NWH / 4, 256, 0, stream>>>(qkv_bf, bufA_bf);

    // 4) out-proj + residual + LN2 fused -> x1_bf, ln2_bf
    mgemm_ln<<<M_ / 128, 512, 0, stream>>>(
        bufA_bf, wout_bf, bout, x, n2g, n2b, x1_bf, ln2_bf);

    // 5) MLP fc1 + tanh-GELU -> gelu (M_ x 512, natural)
    mgemm_g<<<(M_ / 128) * 4, 256, 0, stream>>>(ln2_bf, w1_bf, b1, gelu);

    // 6) MLP fc2 + residual(x1) -> d_out natural f32
    mgemm_out<<<(M_ / 128) * 2, 256, 0, stream>>>(gelu, w2_bf, b2, x1_bf, out);
}

// Round 12
// 401.493 us; speedup vs baseline: 1.7020x; 1.0486x over previous
//
#include <hip/hip_runtime.h>
#include <hip/hip_bf16.h>
#include <math.h>

// Problem constants (B=32, H=W=56, C=256, heads=8, hd=32, ws=7)
#define NTOK 3136            // 56*56
#define C_ 256
#define HEADS_ 8
#define HD 32
#define WS_ 7
#define L_ 49
#define NWIN 2048            // 32 * 8 * 8
#define NWH 16384            // NWIN * HEADS_
#define M_ 100352            // NWIN * 49  == BATCH*NTOK
#define MLPH 512
#define WHSZ 2048            // per (win,head) plane elems

typedef __bf16 bf16x8 __attribute__((ext_vector_type(8)));
typedef float f32x4 __attribute__((ext_vector_type(4)));

__device__ __forceinline__ unsigned short f2bf(float f) {
    union { float f; unsigned u; } v; v.f = f;
    unsigned r = v.u + 0x7fffu + ((v.u >> 16) & 1u);   // RNE
    return (unsigned short)(r >> 16);
}
__device__ __forceinline__ float bf2f(unsigned short s) {
    union { unsigned u; float f; } v; v.u = ((unsigned)s) << 16;
    return v.f;
}

// windowed token index (49-based) -> natural row index
__device__ __forceinline__ int t2rr(int t) {
    int win = t / L_;
    int l   = t - win * L_;
    int b_  = win >> 6, wh = (win >> 3) & 7, ww = win & 7;
    int ld7 = l / WS_;
    int y   = wh * WS_ + ld7;
    int xc  = ww * WS_ + (l - ld7 * WS_);
    return b_ * NTOK + y * 56 + xc;
}

// XCD-chunked bm-major remap (L2 reuse of the A stripe per XCD)
template <int NBN>
__device__ __forceinline__ void xcd_decode(int nb, int& bm, int& bn) {
    int h = blockIdx.x;
    int fid = (h & 7) * (nb >> 3) + (h >> 3);
    int bmi = fid / NBN;
    bm = bmi * 128;
    bn = (fid - bmi * NBN) * 128;
}

// ---------------------------------------------------------------------------
// merged weight conversion: the 4 bf16 weight regions are contiguous in ws.
// seg sizes: 196608 (wqkv) / 65536 (wout) / 131072 (w1) / 131072 (w2)
// ---------------------------------------------------------------------------
__global__ __launch_bounds__(256) void cvt4_kernel(
    const float* __restrict__ a, const float* __restrict__ b,
    const float* __restrict__ c2, const float* __restrict__ d,
    unsigned short* __restrict__ out)
{
    int i = (blockIdx.x * 256 + threadIdx.x) * 4;
    const float* src; int off;
    if (i < 196608)      { src = a;  off = i; }
    else if (i < 262144) { src = b;  off = i - 196608; }
    else if (i < 393216) { src = c2; off = i - 262144; }
    else                 { src = d;  off = i - 393216; }
    float4 v = *(const float4*)(src + off);
    unsigned short o[4];
    o[0] = f2bf(v.x); o[1] = f2bf(v.y); o[2] = f2bf(v.z); o[3] = f2bf(v.w);
    *(uint2*)(out + i) = *(const uint2*)o;
}

// ---------------------------------------------------------------------------
// LN1: one wave per token; bf16 output in windowed row order (M_ rows).
// ---------------------------------------------------------------------------
__global__ __launch_bounds__(256) void ln_kernel(
    const float* __restrict__ x, const float* __restrict__ gamma,
    const float* __restrict__ beta, unsigned short* __restrict__ out)
{
    int wave = threadIdx.x >> 6;
    int lane = threadIdx.x & 63;
    int p = blockIdx.x * 4 + wave;
    const float* row = x + (size_t)p * C_;
    float4 v = *(const float4*)(row + lane * 4);
    float s  = v.x + v.y + v.z + v.w;
    float ss = v.x * v.x + v.y * v.y + v.z * v.z + v.w * v.w;
    #pragma unroll
    for (int m = 1; m < 64; m <<= 1) {
        s  += __shfl_xor(s, m, 64);
        ss += __shfl_xor(ss, m, 64);
    }
    float mean = s * (1.0f / C_);
    float var  = ss * (1.0f / C_) - mean * mean;
    float inv  = rsqrtf(var + 1e-5f);
    float4 gv = *(const float4*)(gamma + lane * 4);
    float4 bv = *(const float4*)(beta + lane * 4);
    int b_ = p / NTOK, n = p - b_ * NTOK;
    int y = n / 56, xc = n - y * 56;
    int win = (b_ * 8 + y / WS_) * 8 + xc / WS_;
    int l   = (y % WS_) * WS_ + (xc % WS_);
    size_t orow = (size_t)(win * L_ + l) * C_;
    unsigned short o[4];
    o[0] = f2bf((v.x - mean) * inv * gv.x + bv.x);
    o[1] = f2bf((v.y - mean) * inv * gv.y + bv.y);
    o[2] = f2bf((v.z - mean) * inv * gv.z + bv.z);
    o[3] = f2bf((v.w - mean) * inv * gv.w + bv.w);
    *(uint2*)(out + orow + lane * 4) = *(const uint2*)o;
}

// ---------------------------------------------------------------------------
#define GBK 64

__device__ __forceinline__ void gload_lds16(const void* g, void* l) {
    __builtin_amdgcn_global_load_lds(
        (const __attribute__((address_space(1))) unsigned*)g,
        (__attribute__((address_space(3))) unsigned*)l, 16, 0, 0);
}

// ---------------------------------------------------------------------------
// QKV GEMM: A (M_ x 256 windowed) @ wqkv^T -> scatter to per-(win,head)
// planes. BK=64 single-buffer (4 K-iters, 32 MFMA/wave/barrier) + swizzle.
// Grid (M_/128)*6, XCD-chunked.
// ---------------------------------------------------------------------------
__global__ __launch_bounds__(256) void mgemm_qkv(
    const unsigned short* __restrict__ A, const unsigned short* __restrict__ W,
    const float* __restrict__ bias, unsigned short* __restrict__ qkv)
{
    __shared__ __align__(16) unsigned short As[8192];   // 128x64
    __shared__ __align__(16) unsigned short Bs[8192];   // 128x64

    int tid  = threadIdx.x;
    int w    = tid >> 6;
    int lane = tid & 63;
    int wr = w >> 1, wc = w & 1;
    int bm, bn;
    xcd_decode<6>(gridDim.x, bm, bn);
    int srow8 = lane >> 3;                       // 0..7
    int scol  = ((lane & 7) ^ srow8) * 8;        // inverse-swizzled source col
    int c = lane & 15, hi = lane >> 4;

    f32x4 acc[4][4] = {};

    for (int k0 = 0; k0 < 256; k0 += GBK) {
        #pragma unroll
        for (int it = 0; it < 4; ++it) {
            int rb = it * 32 + w * 8;
            gload_lds16(A + (size_t)(bm + rb + srow8) * 256 + k0 + scol, As + rb * 64);
            gload_lds16(W + (size_t)(bn + rb + srow8) * 256 + k0 + scol, Bs + rb * 64);
        }
        __syncthreads();
        #pragma unroll
        for (int kk = 0; kk < 2; ++kk) {
            bf16x8 af[4], bf[4];
            int hs = ((kk * 4 + hi) ^ (c & 7)) * 8;
            #pragma unroll
            for (int mi = 0; mi < 4; ++mi)
                af[mi] = *(const bf16x8*)&As[(wr * 64 + mi * 16 + c) * 64 + hs];
            #pragma unroll
            for (int ni = 0; ni < 4; ++ni)
                bf[ni] = *(const bf16x8*)&Bs[(wc * 64 + ni * 16 + c) * 64 + hs];
            #pragma unroll
            for (int mi = 0; mi < 4; ++mi)
                #pragma unroll
                for (int ni = 0; ni < 4; ++ni)
                    acc[mi][ni] = __builtin_amdgcn_mfma_f32_16x16x32_bf16(
                        af[mi], bf[ni], acc[mi][ni], 0, 0, 0);
        }
        __syncthreads();
    }

    // scatter epilogue to compact per-head planes
    #pragma unroll
    for (int mi = 0; mi < 4; ++mi) {
        #pragma unroll
        for (int r = 0; r < 4; ++r) {
            int row = bm + wr * 64 + mi * 16 + hi * 4 + r;
            int win = row / L_, l = row - win * L_;
            #pragma unroll
            for (int ni = 0; ni < 4; ++ni) {
                int col = bn + wc * 64 + ni * 16 + c;
                float val = acc[mi][ni][r] + bias[col];
                int which = col >> 8;
                int head  = (col >> 5) & 7;
                int d     = col & 31;
                int wh = win * HEADS_ + head;
                size_t base = (size_t)which * ((size_t)NWH * WHSZ) + (size_t)wh * WHSZ;
                size_t off;
                if (which == 2)
                    off = base + (size_t)(((l >> 3) * HD + d) << 3) + (l & 7);
                else
                    off = base + (size_t)l * HD + d;
                qkv[off] = f2bf(val);
            }
        }
    }
}

// ---------------------------------------------------------------------------
// MFMA window attention: 4 waves/block, wave = one (win,head).
// ---------------------------------------------------------------------------
__global__ __launch_bounds__(256) void mattn(
    const unsigned short* __restrict__ qkv, unsigned short* __restrict__ o_win)
{
    __shared__ __align__(16) unsigned short P_lds[4][64][72];
    int wave = threadIdx.x >> 6, lane = threadIdx.x & 63;
    int c = lane & 15, hi = lane >> 4;
    int wh = blockIdx.x * 4 + wave;
    int win = wh >> 3, head = wh & 7;
    const unsigned short* qb = qkv + (size_t)wh * WHSZ;
    const unsigned short* kb = qb + (size_t)NWH * WHSZ;
    const unsigned short* vb = kb + (size_t)NWH * WHSZ;

    bf16x8 af[4], bk[4];
    #pragma unroll
    for (int mi = 0; mi < 4; ++mi)
        af[mi] = *(const bf16x8*)(qb + (mi * 16 + c) * HD + hi * 8);
    #pragma unroll
    for (int ni = 0; ni < 4; ++ni)
        bk[ni] = *(const bf16x8*)(kb + (ni * 16 + c) * HD + hi * 8);

    f32x4 sacc[4][4] = {};
    #pragma unroll
    for (int mi = 0; mi < 4; ++mi)
        #pragma unroll
        for (int ni = 0; ni < 4; ++ni)
            sacc[mi][ni] = __builtin_amdgcn_mfma_f32_16x16x32_bf16(
                af[mi], bk[ni], sacc[mi][ni], 0, 0, 0);

    const float scale = 0.17677669529663687f;
    float inv_[4][4];
    #pragma unroll
    for (int mi = 0; mi < 4; ++mi) {
        #pragma unroll
        for (int r = 0; r < 4; ++r) {
            float sv[4];
            float m = -1e30f;
            #pragma unroll
            for (int ni = 0; ni < 4; ++ni) {
                float v = sacc[mi][ni][r] * scale;
                v = (ni * 16 + c < L_) ? v : -1e30f;
                sv[ni] = v;
                m = fmaxf(m, v);
            }
            #pragma unroll
            for (int msk = 1; msk < 16; msk <<= 1)
                m = fmaxf(m, __shfl_xor(m, msk, 64));
            float sum = 0.f;
            unsigned short pb[4];
            #pragma unroll
            for (int ni = 0; ni < 4; ++ni) {
                float p = __expf(sv[ni] - m);
                sum += p;
                pb[ni] = f2bf(p);
            }
            #pragma unroll
            for (int msk = 1; msk < 16; msk <<= 1)
                sum += __shfl_xor(sum, msk, 64);
            inv_[mi][r] = 1.0f / sum;
            int q = mi * 16 + hi * 4 + r;
            #pragma unroll
            for (int ni = 0; ni < 4; ++ni)
                P_lds[wave][q][ni * 16 + c] = pb[ni];
        }
    }

    f32x4 oacc[4][2] = {};
    #pragma unroll
    for (int ks = 0; ks < 2; ++ks) {
        bf16x8 pa[4], bv[2];
        #pragma unroll
        for (int mi = 0; mi < 4; ++mi)
            pa[mi] = *(const bf16x8*)&P_lds[wave][mi * 16 + c][ks * 32 + hi * 8];
        #pragma unroll
        for (int ni = 0; ni < 2; ++ni)
            bv[ni] = *(const bf16x8*)(vb + ((ks * 4 + hi) * HD + ni * 16 + c) * 8);
        #pragma unroll
        for (int mi = 0; mi < 4; ++mi)
            #pragma unroll
            for (int ni = 0; ni < 2; ++ni)
                oacc[mi][ni] = __builtin_amdgcn_mfma_f32_16x16x32_bf16(
                    pa[mi], bv[ni], oacc[mi][ni], 0, 0, 0);
    }

    #pragma unroll
    for (int mi = 0; mi < 4; ++mi) {
        #pragma unroll
        for (int r = 0; r < 4; ++r) {
            int q = mi * 16 + hi * 4 + r;
            if (q < L_) {
                size_t rowoff = ((size_t)(win * L_ + q)) * C_ + head * HD;
                float iv = inv_[mi][r];
                #pragma unroll
                for (int ni = 0; ni < 2; ++ni)
                    o_win[rowoff + ni * 16 + c] = f2bf(oacc[mi][ni][r] * iv);
            }
        }
    }
}

// ---------------------------------------------------------------------------
// mgemm_ln: out-proj + residual(x gathered f32) + LN2. 512 threads,
// 128 rows x full 256 cols. BK=64 single-buffer + swizzle.
// ---------------------------------------------------------------------------
#define XS 260

__global__ __launch_bounds__(512) void mgemm_ln(
    const unsigned short* __restrict__ A, const unsigned short* __restrict__ W,
    const float* __restrict__ bias, const float* __restrict__ x,
    const float* __restrict__ g2, const float* __restrict__ b2,
    unsigned short* __restrict__ x1_out, unsigned short* __restrict__ ln_out)
{
    __shared__ __align__(16) unsigned short pool[128 * XS];   // 65 KB
    unsigned short* As = pool;            // 8192 shorts (128x64)
    unsigned short* Bs = pool + 8192;     // 16384 shorts (256x64)

    int tid  = threadIdx.x;
    int w    = tid >> 6;          // 0..7
    int lane = tid & 63;
    int wr = w >> 2, wc = w & 3;  // 2 x 4 wave tiles of 64x64
    int bm = blockIdx.x * 128;
    int srow8 = lane >> 3;
    int scol  = ((lane & 7) ^ srow8) * 8;
    int c = lane & 15, hi = lane >> 4;

    f32x4 acc[4][4] = {};

    for (int k0 = 0; k0 < 256; k0 += GBK) {
        #pragma unroll
        for (int it = 0; it < 2; ++it) {
            int rb = it * 64 + w * 8;
            gload_lds16(A + (size_t)(bm + rb + srow8) * 256 + k0 + scol, As + rb * 64);
        }
        #pragma unroll
        for (int it = 0; it < 4; ++it) {
            int rb = it * 64 + w * 8;
            gload_lds16(W + (size_t)(rb + srow8) * 256 + k0 + scol, Bs + rb * 64);
        }
        __syncthreads();
        #pragma unroll
        for (int kk = 0; kk < 2; ++kk) {
            bf16x8 af[4], bf[4];
            int hs = ((kk * 4 + hi) ^ (c & 7)) * 8;
            #pragma unroll
            for (int mi = 0; mi < 4; ++mi)
                af[mi] = *(const bf16x8*)&As[(wr * 64 + mi * 16 + c) * 64 + hs];
            #pragma unroll
            for (int ni = 0; ni < 4; ++ni)
                bf[ni] = *(const bf16x8*)&Bs[(wc * 64 + ni * 16 + c) * 64 + hs];
            #pragma unroll
            for (int mi = 0; mi < 4; ++mi)
                #pragma unroll
                for (int ni = 0; ni < 4; ++ni)
                    acc[mi][ni] = __builtin_amdgcn_mfma_f32_16x16x32_bf16(
                        af[mi], bf[ni], acc[mi][ni], 0, 0, 0);
        }
        __syncthreads();
    }

    // stage o (+bias) to LDS bf16
    #pragma unroll
    for (int mi = 0; mi < 4; ++mi) {
        #pragma unroll
        for (int ni = 0; ni < 4; ++ni) {
            int colb = wc * 64 + ni * 16 + c;
            float bv = bias[colb];
            #pragma unroll
            for (int r = 0; r < 4; ++r)
                pool[(wr * 64 + mi * 16 + hi * 4 + r) * XS + colb] =
                    f2bf(acc[mi][ni][r] + bv);
        }
    }
    __syncthreads();

    float4 gv  = *(const float4*)(g2 + lane * 4);
    float4 bv2 = *(const float4*)(b2 + lane * 4);
    #pragma unroll 2
    for (int i = 0; i < 16; ++i) {
        int tl = w * 16 + i;
        int t = bm + tl;
        int rr = t2rr(t);
        float4 xv = *(const float4*)(x + (size_t)rr * C_ + lane * 4);
        uint2 ov = *(const uint2*)&pool[tl * XS + lane * 4];
        float x0 = xv.x + bf2f(ov.x & 0xffff);
        float x1 = xv.y + bf2f(ov.x >> 16);
        float x2 = xv.z + bf2f(ov.y & 0xffff);
        float x3 = xv.w + bf2f(ov.y >> 16);
        float s  = x0 + x1 + x2 + x3;
        float ss = x0 * x0 + x1 * x1 + x2 * x2 + x3 * x3;
        #pragma unroll
        for (int m = 1; m < 64; m <<= 1) {
            s  += __shfl_xor(s, m, 64);
            ss += __shfl_xor(ss, m, 64);
        }
        float mean = s * (1.0f / C_);
        float var  = ss * (1.0f / C_) - mean * mean;
        float inv  = rsqrtf(var + 1e-5f);
        uint2 xw, lw;
        xw.x = (unsigned)f2bf(x0) | ((unsigned)f2bf(x1) << 16);
        xw.y = (unsigned)f2bf(x2) | ((unsigned)f2bf(x3) << 16);
        float l0 = (x0 - mean) * inv * gv.x + bv2.x;
        float l1 = (x1 - mean) * inv * gv.y + bv2.y;
        float l2 = (x2 - mean) * inv * gv.z + bv2.z;
        float l3 = (x3 - mean) * inv * gv.w + bv2.w;
        lw.x = (unsigned)f2bf(l0) | ((unsigned)f2bf(l1) << 16);
        lw.y = (unsigned)f2bf(l2) | ((unsigned)f2bf(l3) << 16);
        *(uint2*)(x1_out + (size_t)t * C_ + lane * 4) = xw;
        *(uint2*)(ln_out + (size_t)t * C_ + lane * 4) = lw;
    }
}

// ---------------------------------------------------------------------------
// fc1: ln2 (M_ x 256) @ w1^T + b1 -> tanh-GELU -> natural [row][512] bf16.
// BK=64 single-buffer + swizzle; coalesced Ts-transpose epilogue.
// ---------------------------------------------------------------------------
#define TSS 136

__global__ __launch_bounds__(256) void mgemm_g(
    const unsigned short* __restrict__ A, const unsigned short* __restrict__ W,
    const float* __restrict__ bias, unsigned short* __restrict__ outp)
{
    __shared__ __align__(16) unsigned short pool[16384];   // 32 KB
    unsigned short* As = pool;
    unsigned short* Bs = pool + 8192;
    unsigned short* Ts = pool;            // 64 x TSS alias after K-loop

    int tid  = threadIdx.x;
    int w    = tid >> 6;
    int lane = tid & 63;
    int wr = w >> 1, wc = w & 1;
    int bm, bn;
    xcd_decode<4>(gridDim.x, bm, bn);
    int srow8 = lane >> 3;
    int scol  = ((lane & 7) ^ srow8) * 8;
    int c = lane & 15, hi = lane >> 4;

    f32x4 acc[4][4] = {};

    for (int k0 = 0; k0 < 256; k0 += GBK) {
        #pragma unroll
        for (int it = 0; it < 4; ++it) {
            int rb = it * 32 + w * 8;
            gload_lds16(A + (size_t)(bm + rb + srow8) * 256 + k0 + scol, As + rb * 64);
            gload_lds16(W + (size_t)(bn + rb + srow8) * 256 + k0 + scol, Bs + rb * 64);
        }
        __syncthreads();
        #pragma unroll
        for (int kk = 0; kk < 2; ++kk) {
            bf16x8 af[4], bf[4];
            int hs = ((kk * 4 + hi) ^ (c & 7)) * 8;
            #pragma unroll
            for (int mi = 0; mi < 4; ++mi)
                af[mi] = *(const bf16x8*)&As[(wr * 64 + mi * 16 + c) * 64 + hs];
            #pragma unroll
            for (int ni = 0; ni < 4; ++ni)
                bf[ni] = *(const bf16x8*)&Bs[(wc * 64 + ni * 16 + c) * 64 + hs];
            #pragma unroll
            for (int mi = 0; mi < 4; ++mi)
                #pragma unroll
                for (int ni = 0; ni < 4; ++ni)
                    acc[mi][ni] = __builtin_amdgcn_mfma_f32_16x16x32_bf16(
                        af[mi], bf[ni], acc[mi][ni], 0, 0, 0);
        }
        __syncthreads();
    }

    #pragma unroll
    for (int ch = 0; ch < 2; ++ch) {
        if (wr == ch) {
            #pragma unroll
            for (int mi = 0; mi < 4; ++mi)
                #pragma unroll
                for (int ni = 0; ni < 4; ++ni) {
                    int colb = wc * 64 + ni * 16 + c;
                    float bv = bias[bn + colb];
                    #pragma unroll
                    for (int r = 0; r < 4; ++r) {
                        float v = acc[mi][ni][r] + bv;
                        float a = 1.5957691216f * (v + 0.044715f * v * v * v);
                        float g = v / (1.0f + __expf(-a));
                        Ts[(mi * 16 + hi * 4 + r) * TSS + colb] = f2bf(g);
                    }
                }
        }
        __syncthreads();
        #pragma unroll
        for (int it = 0; it < 4; ++it) {
            int id = it * 256 + tid;
            int row = id >> 4, cx = (id & 15) * 8;
            uint4 v = *(const uint4*)&Ts[row * TSS + cx];
            *(uint4*)&outp[(size_t)(bm + ch * 64 + row) * MLPH + bn + cx] = v;
        }
        __syncthreads();
    }
}

// ---------------------------------------------------------------------------
// fc2: gelu (M_ x 512) @ w2^T + b2 + residual(x1 bf16 windowed) -> natural f32.
// BK=64 single-buffer (8 iters) + swizzle; LDS-transposed coalesced epilogue.
// ---------------------------------------------------------------------------
__global__ __launch_bounds__(256) void mgemm_out(
    const unsigned short* __restrict__ A, const unsigned short* __restrict__ W,
    const float* __restrict__ bias, const unsigned short* __restrict__ x1,
    float* __restrict__ dout)
{
    __shared__ __align__(16) unsigned short pool[16384];   // 32 KB
    unsigned short* As = pool;
    unsigned short* Bs = pool + 8192;
    float* stg = (float*)pool;                             // 32 x 132 f32 alias

    int tid  = threadIdx.x;
    int w    = tid >> 6;
    int lane = tid & 63;
    int wr = w >> 1, wc = w & 1;
    int bm, bn;
    xcd_decode<2>(gridDim.x, bm, bn);
    int srow8 = lane >> 3;
    int scol  = ((lane & 7) ^ srow8) * 8;
    int c = lane & 15, hi = lane >> 4;

    f32x4 acc[4][4] = {};

    for (int k0 = 0; k0 < 512; k0 += GBK) {
        #pragma unroll
        for (int it = 0; it < 4; ++it) {
            int rb = it * 32 + w * 8;
            gload_lds16(A + (size_t)(bm + rb + srow8) * 512 + k0 + scol, As + rb * 64);
            gload_lds16(W + (size_t)(bn + rb + srow8) * 512 + k0 + scol, Bs + rb * 64);
        }
        __syncthreads();
        #pragma unroll
        for (int kk = 0; kk < 2; ++kk) {
            bf16x8 af[4], bf[4];
            int hs = ((kk * 4 + hi) ^ (c & 7)) * 8;
            #pragma unroll
            for (int mi = 0; mi < 4; ++mi)
                af[mi] = *(const bf16x8*)&As[(wr * 64 + mi * 16 + c) * 64 + hs];
            #pragma unroll
            for (int ni = 0; ni < 4; ++ni)
                bf[ni] = *(const bf16x8*)&Bs[(wc * 64 + ni * 16 + c) * 64 + hs];
            #pragma unroll
            for (int mi = 0; mi < 4; ++mi)
                #pragma unroll
                for (int ni = 0; ni < 4; ++ni)
                    acc[mi][ni] = __builtin_amdgcn_mfma_f32_16x16x32_bf16(
                        af[mi], bf[ni], acc[mi][ni], 0, 0, 0);
        }
        __syncthreads();
    }

    #pragma unroll
    for (int c2 = 0; c2 < 4; ++c2) {
        if (wr == (c2 >> 1)) {
            int mi0 = (c2 & 1) * 2;
            #pragma unroll
            for (int mm = 0; mm < 2; ++mm) {
                #pragma unroll
                for (int ni = 0; ni < 4; ++ni) {
                    int colb = wc * 64 + ni * 16 + c;
                    float bv = bias[bn + colb];
                    #pragma unroll
                    for (int r = 0; r < 4; ++r)
                        stg[(mm * 16 + hi * 4 + r) * 132 + colb] =
                            acc[mi0 + mm][ni][r] + bv;
                }
            }
        }
        __syncthreads();
        #pragma unroll
        for (int i = 0; i < 4; ++i) {
            int lr = i * 8 + (tid >> 5);         // 0..31
            int t = bm + c2 * 32 + lr;
            int rr = t2rr(t);
            int col4 = (tid & 31) * 4;
            float4 v = *(const float4*)&stg[lr * 132 + col4];
            uint2 rv = *(const uint2*)&x1[(size_t)t * C_ + bn + col4];
            v.x += bf2f(rv.x & 0xffff);
            v.y += bf2f(rv.x >> 16);
            v.z += bf2f(rv.y & 0xffff);
            v.w += bf2f(rv.y >> 16);
            *(float4*)&dout[(size_t)rr * C_ + bn + col4] = v;
        }
        __syncthreads();
    }
}

// ---------------------------------------------------------------------------
extern "C" void kernel_launch(void* const* d_in, const int* in_sizes, int n_in,
                              void* d_out, int out_size, void* d_ws, size_t ws_size,
                              hipStream_t stream)
{
    (void)in_sizes; (void)n_in; (void)out_size; (void)ws_size;
    const float* x    = (const float*)d_in[0];
    const float* n1g  = (const float*)d_in[3];
    const float* n1b  = (const float*)d_in[4];
    const float* wqkv = (const float*)d_in[5];
    const float* bqkv = (const float*)d_in[6];
    const float* wout = (const float*)d_in[7];
    const float* bout = (const float*)d_in[8];
    const float* n2g  = (const float*)d_in[9];
    const float* n2b  = (const float*)d_in[10];
    const float* w1   = (const float*)d_in[11];
    const float* b1   = (const float*)d_in[12];
    const float* w2   = (const float*)d_in[13];
    const float* b2   = (const float*)d_in[14];
    float* out = (float*)d_out;

    // workspace layout (bf16 shorts)
    unsigned short* bufA_bf = (unsigned short*)d_ws;                 // M*256 (LN1 out, then o_win)
    unsigned short* qkv_bf  = bufA_bf + (size_t)M_ * C_;             // 3*NWH*2048 (later gelu M*512)
    unsigned short* x1_bf   = qkv_bf + (size_t)3 * NWH * WHSZ;       // M*256
    unsigned short* ln2_bf  = x1_bf + (size_t)M_ * C_;               // M*256
    unsigned short* wqkv_bf = ln2_bf + (size_t)M_ * C_;              // contiguous weights:
    unsigned short* wout_bf = wqkv_bf + 768 * 256;
    unsigned short* w1_bf   = wout_bf + 256 * 256;
    unsigned short* w2_bf   = w1_bf + 512 * 256;
    unsigned short* gelu    = qkv_bf;   // alias (qkv dead after mattn)

    // 0) weights -> bf16 (single merged launch; regions contiguous)
    cvt4_kernel<<<512, 256, 0, stream>>>(wqkv, wout, w1, w2, wqkv_bf);

    // 1) LN1 + window partition -> bufA_bf
    ln_kernel<<<M_ / 4, 256, 0, stream>>>(x, n1g, n1b, bufA_bf);

    // 2) QKV GEMM -> Q/K/V' planes (XCD-chunked)
    mgemm_qkv<<<(M_ / 128) * 6, 256, 0, stream>>>(
        bufA_bf, wqkv_bf, bqkv, qkv_bf);

    // 3) MFMA window attention -> o_win (bufA_bf)
    mattn<<<NWH / 4, 256, 0, stream>>>(qkv_bf, bufA_bf);

    // 4) out-proj + residual + LN2 fused -> x1_bf, ln2_bf
    mgemm_ln<<<M_ / 128, 512, 0, stream>>>(
        bufA_bf, wout_bf, bout, x, n2g, n2b, x1_bf, ln2_bf);

    // 5) MLP fc1 + tanh-GELU -> gelu (M_ x 512, natural)
    mgemm_g<<<(M_ / 128) * 4, 256, 0, stream>>>(ln2_bf, w1_bf, b1, gelu);

    // 6) MLP fc2 + residual(x1) -> d_out natural f32
    mgemm_out<<<(M_ / 128) * 2, 256, 0, stream>>>(gelu, w2_bf, b2, x1_bf, out);
}

// Round 13
// 381.985 us; speedup vs baseline: 1.7889x; 1.0511x over previous
//
#include <hip/hip_runtime.h>
#include <hip/hip_bf16.h>
#include <math.h>

// Problem constants (B=32, H=W=56, C=256, heads=8, hd=32, ws=7)
#define NTOK 3136            // 56*56
#define C_ 256
#define HEADS_ 8
#define HD 32
#define WS_ 7
#define L_ 49
#define NWIN 2048            // 32 * 8 * 8
#define NWH 16384            // NWIN * HEADS_
#define M_ 100352            // NWIN * 49  == BATCH*NTOK
#define MLPH 512
#define WHSZ 2048            // per (win,head) plane elems

typedef __bf16 bf16x8 __attribute__((ext_vector_type(8)));
typedef float f32x4 __attribute__((ext_vector_type(4)));

__device__ __forceinline__ unsigned short f2bf(float f) {
    union { float f; unsigned u; } v; v.f = f;
    unsigned r = v.u + 0x7fffu + ((v.u >> 16) & 1u);   // RNE
    return (unsigned short)(r >> 16);
}
__device__ __forceinline__ float bf2f(unsigned short s) {
    union { unsigned u; float f; } v; v.u = ((unsigned)s) << 16;
    return v.f;
}

// windowed token index (49-based) -> natural row index
__device__ __forceinline__ int t2rr(int t) {
    int win = t / L_;
    int l   = t - win * L_;
    int b_  = win >> 6, wh = (win >> 3) & 7, ww = win & 7;
    int ld7 = l / WS_;
    int y   = wh * WS_ + ld7;
    int xc  = ww * WS_ + (l - ld7 * WS_);
    return b_ * NTOK + y * 56 + xc;
}

// XCD-chunked bm-major remap (L2 reuse of the A stripe per XCD)
template <int NBN>
__device__ __forceinline__ void xcd_decode(int nb, int& bm, int& bn) {
    int h = blockIdx.x;
    int fid = (h & 7) * (nb >> 3) + (h >> 3);
    int bmi = fid / NBN;
    bm = bmi * 128;
    bn = (fid - bmi * NBN) * 128;
}

// ---------------------------------------------------------------------------
// merged weight conversion: the 4 bf16 weight regions are contiguous in ws.
// seg sizes: 196608 (wqkv) / 65536 (wout) / 131072 (w1) / 131072 (w2)
// ---------------------------------------------------------------------------
__global__ __launch_bounds__(256) void cvt4_kernel(
    const float* __restrict__ a, const float* __restrict__ b,
    const float* __restrict__ c2, const float* __restrict__ d,
    unsigned short* __restrict__ out)
{
    int i = (blockIdx.x * 256 + threadIdx.x) * 4;
    const float* src; int off;
    if (i < 196608)      { src = a;  off = i; }
    else if (i < 262144) { src = b;  off = i - 196608; }
    else if (i < 393216) { src = c2; off = i - 262144; }
    else                 { src = d;  off = i - 393216; }
    float4 v = *(const float4*)(src + off);
    unsigned short o[4];
    o[0] = f2bf(v.x); o[1] = f2bf(v.y); o[2] = f2bf(v.z); o[3] = f2bf(v.w);
    *(uint2*)(out + i) = *(const uint2*)o;
}

// ---------------------------------------------------------------------------
// LN1: one wave per token; bf16 output in windowed row order (M_ rows).
// ---------------------------------------------------------------------------
__global__ __launch_bounds__(256) void ln_kernel(
    const float* __restrict__ x, const float* __restrict__ gamma,
    const float* __restrict__ beta, unsigned short* __restrict__ out)
{
    int wave = threadIdx.x >> 6;
    int lane = threadIdx.x & 63;
    int p = blockIdx.x * 4 + wave;
    const float* row = x + (size_t)p * C_;
    float4 v = *(const float4*)(row + lane * 4);
    float s  = v.x + v.y + v.z + v.w;
    float ss = v.x * v.x + v.y * v.y + v.z * v.z + v.w * v.w;
    #pragma unroll
    for (int m = 1; m < 64; m <<= 1) {
        s  += __shfl_xor(s, m, 64);
        ss += __shfl_xor(ss, m, 64);
    }
    float mean = s * (1.0f / C_);
    float var  = ss * (1.0f / C_) - mean * mean;
    float inv  = rsqrtf(var + 1e-5f);
    float4 gv = *(const float4*)(gamma + lane * 4);
    float4 bv = *(const float4*)(beta + lane * 4);
    int b_ = p / NTOK, n = p - b_ * NTOK;
    int y = n / 56, xc = n - y * 56;
    int win = (b_ * 8 + y / WS_) * 8 + xc / WS_;
    int l   = (y % WS_) * WS_ + (xc % WS_);
    size_t orow = (size_t)(win * L_ + l) * C_;
    unsigned short o[4];
    o[0] = f2bf((v.x - mean) * inv * gv.x + bv.x);
    o[1] = f2bf((v.y - mean) * inv * gv.y + bv.y);
    o[2] = f2bf((v.z - mean) * inv * gv.z + bv.z);
    o[3] = f2bf((v.w - mean) * inv * gv.w + bv.w);
    *(uint2*)(out + orow + lane * 4) = *(const uint2*)o;
}

// ---------------------------------------------------------------------------
#define GBK 64

__device__ __forceinline__ void gload_lds16(const void* g, void* l) {
    __builtin_amdgcn_global_load_lds(
        (const __attribute__((address_space(1))) unsigned*)g,
        (__attribute__((address_space(3))) unsigned*)l, 16, 0, 0);
}

// ---------------------------------------------------------------------------
// QKV GEMM: A (M_ x 256 windowed) @ wqkv^T -> scatter to per-(win,head)
// planes. BK=64 single-buffer (32 MFMA/wave/barrier) + swizzle.
// Grid (M_/128)*6, XCD-chunked.
// ---------------------------------------------------------------------------
__global__ __launch_bounds__(256) void mgemm_qkv(
    const unsigned short* __restrict__ A, const unsigned short* __restrict__ W,
    const float* __restrict__ bias, unsigned short* __restrict__ qkv)
{
    __shared__ __align__(16) unsigned short As[8192];   // 128x64
    __shared__ __align__(16) unsigned short Bs[8192];   // 128x64

    int tid  = threadIdx.x;
    int w    = tid >> 6;
    int lane = tid & 63;
    int wr = w >> 1, wc = w & 1;
    int bm, bn;
    xcd_decode<6>(gridDim.x, bm, bn);
    int srow8 = lane >> 3;                       // 0..7
    int scol  = ((lane & 7) ^ srow8) * 8;        // inverse-swizzled source col
    int c = lane & 15, hi = lane >> 4;

    f32x4 acc[4][4] = {};

    for (int k0 = 0; k0 < 256; k0 += GBK) {
        #pragma unroll
        for (int it = 0; it < 4; ++it) {
            int rb = it * 32 + w * 8;
            gload_lds16(A + (size_t)(bm + rb + srow8) * 256 + k0 + scol, As + rb * 64);
            gload_lds16(W + (size_t)(bn + rb + srow8) * 256 + k0 + scol, Bs + rb * 64);
        }
        __syncthreads();
        #pragma unroll
        for (int kk = 0; kk < 2; ++kk) {
            bf16x8 af[4], bf[4];
            int hs = ((kk * 4 + hi) ^ (c & 7)) * 8;
            #pragma unroll
            for (int mi = 0; mi < 4; ++mi)
                af[mi] = *(const bf16x8*)&As[(wr * 64 + mi * 16 + c) * 64 + hs];
            #pragma unroll
            for (int ni = 0; ni < 4; ++ni)
                bf[ni] = *(const bf16x8*)&Bs[(wc * 64 + ni * 16 + c) * 64 + hs];
            #pragma unroll
            for (int mi = 0; mi < 4; ++mi)
                #pragma unroll
                for (int ni = 0; ni < 4; ++ni)
                    acc[mi][ni] = __builtin_amdgcn_mfma_f32_16x16x32_bf16(
                        af[mi], bf[ni], acc[mi][ni], 0, 0, 0);
        }
        __syncthreads();
    }

    // scatter epilogue to compact per-head planes
    #pragma unroll
    for (int mi = 0; mi < 4; ++mi) {
        #pragma unroll
        for (int r = 0; r < 4; ++r) {
            int row = bm + wr * 64 + mi * 16 + hi * 4 + r;
            int win = row / L_, l = row - win * L_;
            #pragma unroll
            for (int ni = 0; ni < 4; ++ni) {
                int col = bn + wc * 64 + ni * 16 + c;
                float val = acc[mi][ni][r] + bias[col];
                int which = col >> 8;
                int head  = (col >> 5) & 7;
                int d     = col & 31;
                int wh = win * HEADS_ + head;
                size_t base = (size_t)which * ((size_t)NWH * WHSZ) + (size_t)wh * WHSZ;
                size_t off;
                if (which == 2)
                    off = base + (size_t)(((l >> 3) * HD + d) << 3) + (l & 7);
                else
                    off = base + (size_t)l * HD + d;
                qkv[off] = f2bf(val);
            }
        }
    }
}

// ---------------------------------------------------------------------------
// MFMA window attention: 4 waves/block, wave = one (win,head).
// ---------------------------------------------------------------------------
__global__ __launch_bounds__(256) void mattn(
    const unsigned short* __restrict__ qkv, unsigned short* __restrict__ o_win)
{
    __shared__ __align__(16) unsigned short P_lds[4][64][72];
    int wave = threadIdx.x >> 6, lane = threadIdx.x & 63;
    int c = lane & 15, hi = lane >> 4;
    int wh = blockIdx.x * 4 + wave;
    int win = wh >> 3, head = wh & 7;
    const unsigned short* qb = qkv + (size_t)wh * WHSZ;
    const unsigned short* kb = qb + (size_t)NWH * WHSZ;
    const unsigned short* vb = kb + (size_t)NWH * WHSZ;

    bf16x8 af[4], bk[4];
    #pragma unroll
    for (int mi = 0; mi < 4; ++mi)
        af[mi] = *(const bf16x8*)(qb + (mi * 16 + c) * HD + hi * 8);
    #pragma unroll
    for (int ni = 0; ni < 4; ++ni)
        bk[ni] = *(const bf16x8*)(kb + (ni * 16 + c) * HD + hi * 8);

    f32x4 sacc[4][4] = {};
    #pragma unroll
    for (int mi = 0; mi < 4; ++mi)
        #pragma unroll
        for (int ni = 0; ni < 4; ++ni)
            sacc[mi][ni] = __builtin_amdgcn_mfma_f32_16x16x32_bf16(
                af[mi], bk[ni], sacc[mi][ni], 0, 0, 0);

    const float scale = 0.17677669529663687f;
    float inv_[4][4];
    #pragma unroll
    for (int mi = 0; mi < 4; ++mi) {
        #pragma unroll
        for (int r = 0; r < 4; ++r) {
            float sv[4];
            float m = -1e30f;
            #pragma unroll
            for (int ni = 0; ni < 4; ++ni) {
                float v = sacc[mi][ni][r] * scale;
                v = (ni * 16 + c < L_) ? v : -1e30f;
                sv[ni] = v;
                m = fmaxf(m, v);
            }
            #pragma unroll
            for (int msk = 1; msk < 16; msk <<= 1)
                m = fmaxf(m, __shfl_xor(m, msk, 64));
            float sum = 0.f;
            unsigned short pb[4];
            #pragma unroll
            for (int ni = 0; ni < 4; ++ni) {
                float p = __expf(sv[ni] - m);
                sum += p;
                pb[ni] = f2bf(p);
            }
            #pragma unroll
            for (int msk = 1; msk < 16; msk <<= 1)
                sum += __shfl_xor(sum, msk, 64);
            inv_[mi][r] = 1.0f / sum;
            int q = mi * 16 + hi * 4 + r;
            #pragma unroll
            for (int ni = 0; ni < 4; ++ni)
                P_lds[wave][q][ni * 16 + c] = pb[ni];
        }
    }

    f32x4 oacc[4][2] = {};
    #pragma unroll
    for (int ks = 0; ks < 2; ++ks) {
        bf16x8 pa[4], bv[2];
        #pragma unroll
        for (int mi = 0; mi < 4; ++mi)
            pa[mi] = *(const bf16x8*)&P_lds[wave][mi * 16 + c][ks * 32 + hi * 8];
        #pragma unroll
        for (int ni = 0; ni < 2; ++ni)
            bv[ni] = *(const bf16x8*)(vb + ((ks * 4 + hi) * HD + ni * 16 + c) * 8);
        #pragma unroll
        for (int mi = 0; mi < 4; ++mi)
            #pragma unroll
            for (int ni = 0; ni < 2; ++ni)
                oacc[mi][ni] = __builtin_amdgcn_mfma_f32_16x16x32_bf16(
                    pa[mi], bv[ni], oacc[mi][ni], 0, 0, 0);
    }

    #pragma unroll
    for (int mi = 0; mi < 4; ++mi) {
        #pragma unroll
        for (int r = 0; r < 4; ++r) {
            int q = mi * 16 + hi * 4 + r;
            if (q < L_) {
                size_t rowoff = ((size_t)(win * L_ + q)) * C_ + head * HD;
                float iv = inv_[mi][r];
                #pragma unroll
                for (int ni = 0; ni < 2; ++ni)
                    o_win[rowoff + ni * 16 + c] = f2bf(oacc[mi][ni][r] * iv);
            }
        }
    }
}

// ---------------------------------------------------------------------------
// mgemm_ln: out-proj + residual(x gathered f32) + LN2. 512 threads,
// 128 rows x full 256 cols. BK=64 single-buffer + swizzle.
// ---------------------------------------------------------------------------
#define XS 260

__global__ __launch_bounds__(512) void mgemm_ln(
    const unsigned short* __restrict__ A, const unsigned short* __restrict__ W,
    const float* __restrict__ bias, const float* __restrict__ x,
    const float* __restrict__ g2, const float* __restrict__ b2,
    unsigned short* __restrict__ x1_out, unsigned short* __restrict__ ln_out)
{
    __shared__ __align__(16) unsigned short pool[128 * XS];   // 65 KB
    unsigned short* As = pool;            // 8192 shorts (128x64)
    unsigned short* Bs = pool + 8192;     // 16384 shorts (256x64)

    int tid  = threadIdx.x;
    int w    = tid >> 6;          // 0..7
    int lane = tid & 63;
    int wr = w >> 2, wc = w & 3;  // 2 x 4 wave tiles of 64x64
    int bm = blockIdx.x * 128;
    int srow8 = lane >> 3;
    int scol  = ((lane & 7) ^ srow8) * 8;
    int c = lane & 15, hi = lane >> 4;

    f32x4 acc[4][4] = {};

    for (int k0 = 0; k0 < 256; k0 += GBK) {
        #pragma unroll
        for (int it = 0; it < 2; ++it) {
            int rb = it * 64 + w * 8;
            gload_lds16(A + (size_t)(bm + rb + srow8) * 256 + k0 + scol, As + rb * 64);
        }
        #pragma unroll
        for (int it = 0; it < 4; ++it) {
            int rb = it * 64 + w * 8;
            gload_lds16(W + (size_t)(rb + srow8) * 256 + k0 + scol, Bs + rb * 64);
        }
        __syncthreads();
        #pragma unroll
        for (int kk = 0; kk < 2; ++kk) {
            bf16x8 af[4], bf[4];
            int hs = ((kk * 4 + hi) ^ (c & 7)) * 8;
            #pragma unroll
            for (int mi = 0; mi < 4; ++mi)
                af[mi] = *(const bf16x8*)&As[(wr * 64 + mi * 16 + c) * 64 + hs];
            #pragma unroll
            for (int ni = 0; ni < 4; ++ni)
                bf[ni] = *(const bf16x8*)&Bs[(wc * 64 + ni * 16 + c) * 64 + hs];
            #pragma unroll
            for (int mi = 0; mi < 4; ++mi)
                #pragma unroll
                for (int ni = 0; ni < 4; ++ni)
                    acc[mi][ni] = __builtin_amdgcn_mfma_f32_16x16x32_bf16(
                        af[mi], bf[ni], acc[mi][ni], 0, 0, 0);
        }
        __syncthreads();
    }

    // stage o (+bias) to LDS bf16
    #pragma unroll
    for (int mi = 0; mi < 4; ++mi) {
        #pragma unroll
        for (int ni = 0; ni < 4; ++ni) {
            int colb = wc * 64 + ni * 16 + c;
            float bv = bias[colb];
            #pragma unroll
            for (int r = 0; r < 4; ++r)
                pool[(wr * 64 + mi * 16 + hi * 4 + r) * XS + colb] =
                    f2bf(acc[mi][ni][r] + bv);
        }
    }
    __syncthreads();

    float4 gv  = *(const float4*)(g2 + lane * 4);
    float4 bv2 = *(const float4*)(b2 + lane * 4);
    #pragma unroll 2
    for (int i = 0; i < 16; ++i) {
        int tl = w * 16 + i;
        int t = bm + tl;
        int rr = t2rr(t);
        float4 xv = *(const float4*)(x + (size_t)rr * C_ + lane * 4);
        uint2 ov = *(const uint2*)&pool[tl * XS + lane * 4];
        float x0 = xv.x + bf2f(ov.x & 0xffff);
        float x1 = xv.y + bf2f(ov.x >> 16);
        float x2 = xv.z + bf2f(ov.y & 0xffff);
        float x3 = xv.w + bf2f(ov.y >> 16);
        float s  = x0 + x1 + x2 + x3;
        float ss = x0 * x0 + x1 * x1 + x2 * x2 + x3 * x3;
        #pragma unroll
        for (int m = 1; m < 64; m <<= 1) {
            s  += __shfl_xor(s, m, 64);
            ss += __shfl_xor(ss, m, 64);
        }
        float mean = s * (1.0f / C_);
        float var  = ss * (1.0f / C_) - mean * mean;
        float inv  = rsqrtf(var + 1e-5f);
        uint2 xw, lw;
        xw.x = (unsigned)f2bf(x0) | ((unsigned)f2bf(x1) << 16);
        xw.y = (unsigned)f2bf(x2) | ((unsigned)f2bf(x3) << 16);
        float l0 = (x0 - mean) * inv * gv.x + bv2.x;
        float l1 = (x1 - mean) * inv * gv.y + bv2.y;
        float l2 = (x2 - mean) * inv * gv.z + bv2.z;
        float l3 = (x3 - mean) * inv * gv.w + bv2.w;
        lw.x = (unsigned)f2bf(l0) | ((unsigned)f2bf(l1) << 16);
        lw.y = (unsigned)f2bf(l2) | ((unsigned)f2bf(l3) << 16);
        *(uint2*)(x1_out + (size_t)t * C_ + lane * 4) = xw;
        *(uint2*)(ln_out + (size_t)t * C_ + lane * 4) = lw;
    }
}

// ---------------------------------------------------------------------------
// fc1: ln2 (M_ x 256) @ w1^T + b1 -> tanh-GELU -> natural [row][512] bf16.
// BK=64 single-buffer + swizzle; FULL-WIDTH single-phase Ts epilogue:
// all threads GELU+stage concurrently (128x136 Ts aliases pool), one barrier,
// one coalesced 16B store sweep.
// ---------------------------------------------------------------------------
#define TSS 136

__global__ __launch_bounds__(256) void mgemm_g(
    const unsigned short* __restrict__ A, const unsigned short* __restrict__ W,
    const float* __restrict__ bias, unsigned short* __restrict__ outp)
{
    __shared__ __align__(16) unsigned short pool[128 * TSS];   // 34.8 KB
    unsigned short* As = pool;            // 8192 shorts
    unsigned short* Bs = pool + 8192;     // 8192 shorts
    unsigned short* Ts = pool;            // 128 x TSS (alias after K-loop)

    int tid  = threadIdx.x;
    int w    = tid >> 6;
    int lane = tid & 63;
    int wr = w >> 1, wc = w & 1;
    int bm, bn;
    xcd_decode<4>(gridDim.x, bm, bn);
    int srow8 = lane >> 3;
    int scol  = ((lane & 7) ^ srow8) * 8;
    int c = lane & 15, hi = lane >> 4;

    f32x4 acc[4][4] = {};

    for (int k0 = 0; k0 < 256; k0 += GBK) {
        #pragma unroll
        for (int it = 0; it < 4; ++it) {
            int rb = it * 32 + w * 8;
            gload_lds16(A + (size_t)(bm + rb + srow8) * 256 + k0 + scol, As + rb * 64);
            gload_lds16(W + (size_t)(bn + rb + srow8) * 256 + k0 + scol, Bs + rb * 64);
        }
        __syncthreads();
        #pragma unroll
        for (int kk = 0; kk < 2; ++kk) {
            bf16x8 af[4], bf[4];
            int hs = ((kk * 4 + hi) ^ (c & 7)) * 8;
            #pragma unroll
            for (int mi = 0; mi < 4; ++mi)
                af[mi] = *(const bf16x8*)&As[(wr * 64 + mi * 16 + c) * 64 + hs];
            #pragma unroll
            for (int ni = 0; ni < 4; ++ni)
                bf[ni] = *(const bf16x8*)&Bs[(wc * 64 + ni * 16 + c) * 64 + hs];
            #pragma unroll
            for (int mi = 0; mi < 4; ++mi)
                #pragma unroll
                for (int ni = 0; ni < 4; ++ni)
                    acc[mi][ni] = __builtin_amdgcn_mfma_f32_16x16x32_bf16(
                        af[mi], bf[ni], acc[mi][ni], 0, 0, 0);
        }
        __syncthreads();
    }

    // full-width GELU + stage (all 256 threads concurrently)
    #pragma unroll
    for (int mi = 0; mi < 4; ++mi) {
        #pragma unroll
        for (int ni = 0; ni < 4; ++ni) {
            int colb = wc * 64 + ni * 16 + c;
            float bv = bias[bn + colb];
            #pragma unroll
            for (int r = 0; r < 4; ++r) {
                float v = acc[mi][ni][r] + bv;
                float a = 1.5957691216f * (v + 0.044715f * v * v * v);
                float g = v / (1.0f + __expf(-a));
                Ts[(wr * 64 + mi * 16 + hi * 4 + r) * TSS + colb] = f2bf(g);
            }
        }
    }
    __syncthreads();

    // one coalesced store sweep: 128 rows x 128 cols, 16B per thread-iter
    #pragma unroll
    for (int it = 0; it < 8; ++it) {
        int id = it * 256 + tid;          // 0..2047
        int row = id >> 4, cx = (id & 15) * 8;
        uint4 v = *(const uint4*)&Ts[row * TSS + cx];
        *(uint4*)&outp[(size_t)(bm + row) * MLPH + bn + cx] = v;
    }
}

// ---------------------------------------------------------------------------
// fc2: gelu (M_ x 512) @ w2^T + b2 + residual(x1 bf16 windowed) -> natural f32.
// BK=64 single-buffer + swizzle; 2-phase LDS-transposed epilogue (64-row stg).
// ---------------------------------------------------------------------------
__global__ __launch_bounds__(256) void mgemm_out(
    const unsigned short* __restrict__ A, const unsigned short* __restrict__ W,
    const float* __restrict__ bias, const unsigned short* __restrict__ x1,
    float* __restrict__ dout)
{
    __shared__ __align__(16) unsigned short pool[16896];   // 33.8 KB
    unsigned short* As = pool;
    unsigned short* Bs = pool + 8192;
    float* stg = (float*)pool;                             // 64 x 132 f32 alias

    int tid  = threadIdx.x;
    int w    = tid >> 6;
    int lane = tid & 63;
    int wr = w >> 1, wc = w & 1;
    int bm, bn;
    xcd_decode<2>(gridDim.x, bm, bn);
    int srow8 = lane >> 3;
    int scol  = ((lane & 7) ^ srow8) * 8;
    int c = lane & 15, hi = lane >> 4;

    f32x4 acc[4][4] = {};

    for (int k0 = 0; k0 < 512; k0 += GBK) {
        #pragma unroll
        for (int it = 0; it < 4; ++it) {
            int rb = it * 32 + w * 8;
            gload_lds16(A + (size_t)(bm + rb + srow8) * 512 + k0 + scol, As + rb * 64);
            gload_lds16(W + (size_t)(bn + rb + srow8) * 512 + k0 + scol, Bs + rb * 64);
        }
        __syncthreads();
        #pragma unroll
        for (int kk = 0; kk < 2; ++kk) {
            bf16x8 af[4], bf[4];
            int hs = ((kk * 4 + hi) ^ (c & 7)) * 8;
            #pragma unroll
            for (int mi = 0; mi < 4; ++mi)
                af[mi] = *(const bf16x8*)&As[(wr * 64 + mi * 16 + c) * 64 + hs];
            #pragma unroll
            for (int ni = 0; ni < 4; ++ni)
                bf[ni] = *(const bf16x8*)&Bs[(wc * 64 + ni * 16 + c) * 64 + hs];
            #pragma unroll
            for (int mi = 0; mi < 4; ++mi)
                #pragma unroll
                for (int ni = 0; ni < 4; ++ni)
                    acc[mi][ni] = __builtin_amdgcn_mfma_f32_16x16x32_bf16(
                        af[mi], bf[ni], acc[mi][ni], 0, 0, 0);
        }
        __syncthreads();
    }

    // 2 phases of 64 rows: stage f32 -> coalesced readback + residual + store
    #pragma unroll
    for (int p = 0; p < 2; ++p) {
        if (wr == p) {
            #pragma unroll
            for (int mi = 0; mi < 4; ++mi)
                #pragma unroll
                for (int ni = 0; ni < 4; ++ni) {
                    int colb = wc * 64 + ni * 16 + c;
                    float bv = bias[bn + colb];
                    #pragma unroll
                    for (int r = 0; r < 4; ++r)
                        stg[(mi * 16 + hi * 4 + r) * 132 + colb] =
                            acc[mi][ni][r] + bv;
                }
        }
        __syncthreads();
        #pragma unroll
        for (int i = 0; i < 8; ++i) {
            int lr = i * 8 + (tid >> 5);         // 0..63
            int t = bm + p * 64 + lr;
            int rr = t2rr(t);
            int col4 = (tid & 31) * 4;
            float4 v = *(const float4*)&stg[lr * 132 + col4];
            uint2 rv = *(const uint2*)&x1[(size_t)t * C_ + bn + col4];
            v.x += bf2f(rv.x & 0xffff);
            v.y += bf2f(rv.x >> 16);
            v.z += bf2f(rv.y & 0xffff);
            v.w += bf2f(rv.y >> 16);
            *(float4*)&dout[(size_t)rr * C_ + bn + col4] = v;
        }
        __syncthreads();
    }
}

// ---------------------------------------------------------------------------
extern "C" void kernel_launch(void* const* d_in, const int* in_sizes, int n_in,
                              void* d_out, int out_size, void* d_ws, size_t ws_size,
                              hipStream_t stream)
{
    (void)in_sizes; (void)n_in; (void)out_size; (void)ws_size;
    const float* x    = (const float*)d_in[0];
    const float* n1g  = (const float*)d_in[3];
    const float* n1b  = (const float*)d_in[4];
    const float* wqkv = (const float*)d_in[5];
    const float* bqkv = (const float*)d_in[6];
    const float* wout = (const float*)d_in[7];
    const float* bout = (const float*)d_in[8];
    const float* n2g  = (const float*)d_in[9];
    const float* n2b  = (const float*)d_in[10];
    const float* w1   = (const float*)d_in[11];
    const float* b1   = (const float*)d_in[12];
    const float* w2   = (const float*)d_in[13];
    const float* b2   = (const float*)d_in[14];
    float* out = (float*)d_out;

    // workspace layout (bf16 shorts)
    unsigned short* bufA_bf = (unsigned short*)d_ws;                 // M*256 (LN1 out, then o_win)
    unsigned short* qkv_bf  = bufA_bf + (size_t)M_ * C_;             // 3*NWH*2048 (later gelu M*512)
    unsigned short* x1_bf   = qkv_bf + (size_t)3 * NWH * WHSZ;       // M*256
    unsigned short* ln2_bf  = x1_bf + (size_t)M_ * C_;               // M*256
    unsigned short* wqkv_bf = ln2_bf + (size_t)M_ * C_;              // contiguous weights
    unsigned short* wout_bf = wqkv_bf + 768 * 256;
    unsigned short* w1_bf   = wout_bf + 256 * 256;
    unsigned short* w2_bf   = w1_bf + 512 * 256;
    unsigned short* gelu    = qkv_bf;   // alias (qkv dead after mattn)

    // 0) weights -> bf16 (single merged launch; regions contiguous)
    cvt4_kernel<<<512, 256, 0, stream>>>(wqkv, wout, w1, w2, wqkv_bf);

    // 1) LN1 + window partition -> bufA_bf
    ln_kernel<<<M_ / 4, 256, 0, stream>>>(x, n1g, n1b, bufA_bf);

    // 2) QKV GEMM -> Q/K/V' planes (XCD-chunked)
    mgemm_qkv<<<(M_ / 128) * 6, 256, 0, stream>>>(
        bufA_bf, wqkv_bf, bqkv, qkv_bf);

    // 3) MFMA window attention -> o_win (bufA_bf)
    mattn<<<NWH / 4, 256, 0, stream>>>(qkv_bf, bufA_bf);

    // 4) out-proj + residual + LN2 fused -> x1_bf, ln2_bf
    mgemm_ln<<<M_ / 128, 512, 0, stream>>>(
        bufA_bf, wout_bf, bout, x, n2g, n2b, x1_bf, ln2_bf);

    // 5) MLP fc1 + tanh-GELU -> gelu (M_ x 512, natural)
    mgemm_g<<<(M_ / 128) * 4, 256, 0, stream>>>(ln2_bf, w1_bf, b1, gelu);

    // 6) MLP fc2 + residual(x1) -> d_out natural f32
    mgemm_out<<<(M_ / 128) * 2, 256, 0, stream>>>(gelu, w2_bf, b2, x1_bf, out);
}

// Round 14
// 370.859 us; speedup vs baseline: 1.8426x; 1.0300x over previous
//
#include <hip/hip_runtime.h>
#include <hip/hip_bf16.h>
#include <math.h>

// Problem constants (B=32, H=W=56, C=256, heads=8, hd=32, ws=7)
#define NTOK 3136            // 56*56
#define C_ 256
#define HEADS_ 8
#define HD 32
#define WS_ 7
#define L_ 49
#define NWIN 2048            // 32 * 8 * 8
#define NWH 16384            // NWIN * HEADS_
#define M_ 100352            // NWIN * 49  == BATCH*NTOK
#define MLPH 512
#define WHSZ 2048            // per (win,head) plane stride (elems)

typedef __bf16 bf16x8 __attribute__((ext_vector_type(8)));
typedef float f32x4 __attribute__((ext_vector_type(4)));

__device__ __forceinline__ unsigned short f2bf(float f) {
    union { float f; unsigned u; } v; v.f = f;
    unsigned r = v.u + 0x7fffu + ((v.u >> 16) & 1u);   // RNE
    return (unsigned short)(r >> 16);
}
__device__ __forceinline__ float bf2f(unsigned short s) {
    union { unsigned u; float f; } v; v.u = ((unsigned)s) << 16;
    return v.f;
}

// windowed token index (49-based) -> natural row index
__device__ __forceinline__ int t2rr(int t) {
    int win = t / L_;
    int l   = t - win * L_;
    int b_  = win >> 6, wh = (win >> 3) & 7, ww = win & 7;
    int ld7 = l / WS_;
    int y   = wh * WS_ + ld7;
    int xc  = ww * WS_ + (l - ld7 * WS_);
    return b_ * NTOK + y * 56 + xc;
}

// XCD-chunked bm-major remap (L2 reuse of the A stripe per XCD)
template <int NBN>
__device__ __forceinline__ void xcd_decode(int nb, int& bm, int& bn) {
    int h = blockIdx.x;
    int fid = (h & 7) * (nb >> 3) + (h >> 3);
    int bmi = fid / NBN;
    bm = bmi * 128;
    bn = (fid - bmi * NBN) * 128;
}

// ---------------------------------------------------------------------------
// merged weight conversion: the 4 bf16 weight regions are contiguous in ws.
// ---------------------------------------------------------------------------
__global__ __launch_bounds__(256) void cvt4_kernel(
    const float* __restrict__ a, const float* __restrict__ b,
    const float* __restrict__ c2, const float* __restrict__ d,
    unsigned short* __restrict__ out)
{
    int i = (blockIdx.x * 256 + threadIdx.x) * 4;
    const float* src; int off;
    if (i < 196608)      { src = a;  off = i; }
    else if (i < 262144) { src = b;  off = i - 196608; }
    else if (i < 393216) { src = c2; off = i - 262144; }
    else                 { src = d;  off = i - 393216; }
    float4 v = *(const float4*)(src + off);
    unsigned short o[4];
    o[0] = f2bf(v.x); o[1] = f2bf(v.y); o[2] = f2bf(v.z); o[3] = f2bf(v.w);
    *(uint2*)(out + i) = *(const uint2*)o;
}

// ---------------------------------------------------------------------------
// LN1: one wave per token; bf16 output in windowed row order (M_ rows).
// ---------------------------------------------------------------------------
__global__ __launch_bounds__(256) void ln_kernel(
    const float* __restrict__ x, const float* __restrict__ gamma,
    const float* __restrict__ beta, unsigned short* __restrict__ out)
{
    int wave = threadIdx.x >> 6;
    int lane = threadIdx.x & 63;
    int p = blockIdx.x * 4 + wave;
    const float* row = x + (size_t)p * C_;
    float4 v = *(const float4*)(row + lane * 4);
    float s  = v.x + v.y + v.z + v.w;
    float ss = v.x * v.x + v.y * v.y + v.z * v.z + v.w * v.w;
    #pragma unroll
    for (int m = 1; m < 64; m <<= 1) {
        s  += __shfl_xor(s, m, 64);
        ss += __shfl_xor(ss, m, 64);
    }
    float mean = s * (1.0f / C_);
    float var  = ss * (1.0f / C_) - mean * mean;
    float inv  = rsqrtf(var + 1e-5f);
    float4 gv = *(const float4*)(gamma + lane * 4);
    float4 bv = *(const float4*)(beta + lane * 4);
    int b_ = p / NTOK, n = p - b_ * NTOK;
    int y = n / 56, xc = n - y * 56;
    int win = (b_ * 8 + y / WS_) * 8 + xc / WS_;
    int l   = (y % WS_) * WS_ + (xc % WS_);
    size_t orow = (size_t)(win * L_ + l) * C_;
    unsigned short o[4];
    o[0] = f2bf((v.x - mean) * inv * gv.x + bv.x);
    o[1] = f2bf((v.y - mean) * inv * gv.y + bv.y);
    o[2] = f2bf((v.z - mean) * inv * gv.z + bv.z);
    o[3] = f2bf((v.w - mean) * inv * gv.w + bv.w);
    *(uint2*)(out + orow + lane * 4) = *(const uint2*)o;
}

// ---------------------------------------------------------------------------
#define GBK 64

__device__ __forceinline__ void gload_lds16(const void* g, void* l) {
    __builtin_amdgcn_global_load_lds(
        (const __attribute__((address_space(1))) unsigned*)g,
        (__attribute__((address_space(3))) unsigned*)l, 16, 0, 0);
}

// ---------------------------------------------------------------------------
// QKV GEMM: A (M_ x 256 windowed) @ wqkv^T -> Q,K,V ALL natural per-(win,head)
// planes [wh][l*32+d]. BK=64 single-buffer + swizzle. Full-width Ts epilogue:
// all 256 threads stage concurrently, then 8 x uint4 coalesced stores each.
// Grid (M_/128)*6, XCD-chunked.
// ---------------------------------------------------------------------------
#define TSS 136

__global__ __launch_bounds__(256) void mgemm_qkv(
    const unsigned short* __restrict__ A, const unsigned short* __restrict__ W,
    const float* __restrict__ bias, unsigned short* __restrict__ qkv)
{
    __shared__ __align__(16) unsigned short pool[128 * TSS];   // 34.8 KB
    unsigned short* As = pool;            // 8192 shorts (128x64)
    unsigned short* Bs = pool + 8192;     // 8192 shorts (128x64)
    unsigned short* Ts = pool;            // 128 x TSS (alias after K-loop)

    int tid  = threadIdx.x;
    int w    = tid >> 6;
    int lane = tid & 63;
    int wr = w >> 1, wc = w & 1;
    int bm, bn;
    xcd_decode<6>(gridDim.x, bm, bn);
    int srow8 = lane >> 3;
    int scol  = ((lane & 7) ^ srow8) * 8;
    int c = lane & 15, hi = lane >> 4;

    f32x4 acc[4][4] = {};

    for (int k0 = 0; k0 < 256; k0 += GBK) {
        #pragma unroll
        for (int it = 0; it < 4; ++it) {
            int rb = it * 32 + w * 8;
            gload_lds16(A + (size_t)(bm + rb + srow8) * 256 + k0 + scol, As + rb * 64);
            gload_lds16(W + (size_t)(bn + rb + srow8) * 256 + k0 + scol, Bs + rb * 64);
        }
        __syncthreads();
        #pragma unroll
        for (int kk = 0; kk < 2; ++kk) {
            bf16x8 af[4], bf[4];
            int hs = ((kk * 4 + hi) ^ (c & 7)) * 8;
            #pragma unroll
            for (int mi = 0; mi < 4; ++mi)
                af[mi] = *(const bf16x8*)&As[(wr * 64 + mi * 16 + c) * 64 + hs];
            #pragma unroll
            for (int ni = 0; ni < 4; ++ni)
                bf[ni] = *(const bf16x8*)&Bs[(wc * 64 + ni * 16 + c) * 64 + hs];
            #pragma unroll
            for (int mi = 0; mi < 4; ++mi)
                #pragma unroll
                for (int ni = 0; ni < 4; ++ni)
                    acc[mi][ni] = __builtin_amdgcn_mfma_f32_16x16x32_bf16(
                        af[mi], bf[ni], acc[mi][ni], 0, 0, 0);
        }
        __syncthreads();
    }

    // full-width stage (+bias) to Ts
    #pragma unroll
    for (int mi = 0; mi < 4; ++mi) {
        #pragma unroll
        for (int ni = 0; ni < 4; ++ni) {
            int colb = wc * 64 + ni * 16 + c;
            float bv = bias[bn + colb];
            #pragma unroll
            for (int r = 0; r < 4; ++r)
                Ts[(wr * 64 + mi * 16 + hi * 4 + r) * TSS + colb] =
                    f2bf(acc[mi][ni][r] + bv);
        }
    }
    __syncthreads();

    // coalesced sweep: 128 rows x 128 cols, 16B per thread-iter
    int which  = bn >> 8;                // block-uniform (128 | 256)
    int bn_off = bn & 255;
    unsigned short* plane = qkv + (size_t)which * ((size_t)NWH * WHSZ);
    #pragma unroll
    for (int it = 0; it < 8; ++it) {
        int id = it * 256 + tid;          // 0..2047
        int row = id >> 4, cx = (id & 15) * 8;
        int grow = bm + row;
        int win = grow / L_, l = grow - win * L_;
        int col = bn_off + cx;
        int head = col >> 5, d0 = col & 31;
        uint4 v = *(const uint4*)&Ts[row * TSS + cx];
        *(uint4*)&plane[(size_t)(win * HEADS_ + head) * WHSZ + l * HD + d0] = v;
    }
}

// ---------------------------------------------------------------------------
// MFMA window attention: 4 waves/block, wave = one (win,head).
// Q,K,V all natural [l][d]. V staged wave-locally into the P_lds slice,
// B-fragments gathered to registers, THEN softmax overwrites slice with P.
// ---------------------------------------------------------------------------
__global__ __launch_bounds__(256) void mattn(
    const unsigned short* __restrict__ qkv, unsigned short* __restrict__ o_win)
{
    __shared__ __align__(16) unsigned short P_lds[4][64][72];
    int wave = threadIdx.x >> 6, lane = threadIdx.x & 63;
    int c = lane & 15, hi = lane >> 4;
    int wh = blockIdx.x * 4 + wave;
    int win = wh >> 3, head = wh & 7;
    const unsigned short* qb = qkv + (size_t)wh * WHSZ;
    const unsigned short* kb = qb + (size_t)NWH * WHSZ;
    const unsigned short* vb = kb + (size_t)NWH * WHSZ;

    // stage natural V (64x32, 4KB) into this wave's P_lds slice
    unsigned short* Vs = &P_lds[wave][0][0];
    #pragma unroll
    for (int i = 0; i < 4; ++i) {
        int idx = i * 64 + lane;              // 0..255 chunks of 8 shorts
        *(uint4*)&Vs[idx * 8] = *(const uint4*)(vb + idx * 8);
    }

    bf16x8 af[4], bk[4];
    #pragma unroll
    for (int mi = 0; mi < 4; ++mi)
        af[mi] = *(const bf16x8*)(qb + (mi * 16 + c) * HD + hi * 8);
    #pragma unroll
    for (int ni = 0; ni < 4; ++ni)
        bk[ni] = *(const bf16x8*)(kb + (ni * 16 + c) * HD + hi * 8);

    // gather PV B-fragments to registers (before P overwrites Vs)
    bf16x8 vf[2][2];
    #pragma unroll
    for (int ks = 0; ks < 2; ++ks)
        #pragma unroll
        for (int ni = 0; ni < 2; ++ni) {
            union { unsigned short s[8]; bf16x8 v; } uu;
            #pragma unroll
            for (int j = 0; j < 8; ++j)
                uu.s[j] = Vs[(ks * 32 + hi * 8 + j) * HD + ni * 16 + c];
            vf[ks][ni] = uu.v;
        }

    f32x4 sacc[4][4] = {};
    #pragma unroll
    for (int mi = 0; mi < 4; ++mi)
        #pragma unroll
        for (int ni = 0; ni < 4; ++ni)
            sacc[mi][ni] = __builtin_amdgcn_mfma_f32_16x16x32_bf16(
                af[mi], bk[ni], sacc[mi][ni], 0, 0, 0);

    const float scale = 0.17677669529663687f;
    float inv_[4][4];
    #pragma unroll
    for (int mi = 0; mi < 4; ++mi) {
        #pragma unroll
        for (int r = 0; r < 4; ++r) {
            float sv[4];
            float m = -1e30f;
            #pragma unroll
            for (int ni = 0; ni < 4; ++ni) {
                float v = sacc[mi][ni][r] * scale;
                v = (ni * 16 + c < L_) ? v : -1e30f;
                sv[ni] = v;
                m = fmaxf(m, v);
            }
            #pragma unroll
            for (int msk = 1; msk < 16; msk <<= 1)
                m = fmaxf(m, __shfl_xor(m, msk, 64));
            float sum = 0.f;
            unsigned short pb[4];
            #pragma unroll
            for (int ni = 0; ni < 4; ++ni) {
                float p = __expf(sv[ni] - m);
                sum += p;
                pb[ni] = f2bf(p);
            }
            #pragma unroll
            for (int msk = 1; msk < 16; msk <<= 1)
                sum += __shfl_xor(sum, msk, 64);
            inv_[mi][r] = 1.0f / sum;
            int q = mi * 16 + hi * 4 + r;
            #pragma unroll
            for (int ni = 0; ni < 4; ++ni)
                P_lds[wave][q][ni * 16 + c] = pb[ni];
        }
    }

    f32x4 oacc[4][2] = {};
    #pragma unroll
    for (int ks = 0; ks < 2; ++ks) {
        bf16x8 pa[4];
        #pragma unroll
        for (int mi = 0; mi < 4; ++mi)
            pa[mi] = *(const bf16x8*)&P_lds[wave][mi * 16 + c][ks * 32 + hi * 8];
        #pragma unroll
        for (int mi = 0; mi < 4; ++mi)
            #pragma unroll
            for (int ni = 0; ni < 2; ++ni)
                oacc[mi][ni] = __builtin_amdgcn_mfma_f32_16x16x32_bf16(
                    pa[mi], vf[ks][ni], oacc[mi][ni], 0, 0, 0);
    }

    #pragma unroll
    for (int mi = 0; mi < 4; ++mi) {
        #pragma unroll
        for (int r = 0; r < 4; ++r) {
            int q = mi * 16 + hi * 4 + r;
            if (q < L_) {
                size_t rowoff = ((size_t)(win * L_ + q)) * C_ + head * HD;
                float iv = inv_[mi][r];
                #pragma unroll
                for (int ni = 0; ni < 2; ++ni)
                    o_win[rowoff + ni * 16 + c] = f2bf(oacc[mi][ni][r] * iv);
            }
        }
    }
}

// ---------------------------------------------------------------------------
// mgemm_ln: out-proj + residual(x gathered f32) + LN2. 512 threads,
// 128 rows x full 256 cols. BK=64 single-buffer + swizzle.
// ---------------------------------------------------------------------------
#define XS 260

__global__ __launch_bounds__(512) void mgemm_ln(
    const unsigned short* __restrict__ A, const unsigned short* __restrict__ W,
    const float* __restrict__ bias, const float* __restrict__ x,
    const float* __restrict__ g2, const float* __restrict__ b2,
    unsigned short* __restrict__ x1_out, unsigned short* __restrict__ ln_out)
{
    __shared__ __align__(16) unsigned short pool[128 * XS];   // 65 KB
    unsigned short* As = pool;            // 8192 shorts (128x64)
    unsigned short* Bs = pool + 8192;     // 16384 shorts (256x64)

    int tid  = threadIdx.x;
    int w    = tid >> 6;          // 0..7
    int lane = tid & 63;
    int wr = w >> 2, wc = w & 3;  // 2 x 4 wave tiles of 64x64
    int bm = blockIdx.x * 128;
    int srow8 = lane >> 3;
    int scol  = ((lane & 7) ^ srow8) * 8;
    int c = lane & 15, hi = lane >> 4;

    f32x4 acc[4][4] = {};

    for (int k0 = 0; k0 < 256; k0 += GBK) {
        #pragma unroll
        for (int it = 0; it < 2; ++it) {
            int rb = it * 64 + w * 8;
            gload_lds16(A + (size_t)(bm + rb + srow8) * 256 + k0 + scol, As + rb * 64);
        }
        #pragma unroll
        for (int it = 0; it < 4; ++it) {
            int rb = it * 64 + w * 8;
            gload_lds16(W + (size_t)(rb + srow8) * 256 + k0 + scol, Bs + rb * 64);
        }
        __syncthreads();
        #pragma unroll
        for (int kk = 0; kk < 2; ++kk) {
            bf16x8 af[4], bf[4];
            int hs = ((kk * 4 + hi) ^ (c & 7)) * 8;
            #pragma unroll
            for (int mi = 0; mi < 4; ++mi)
                af[mi] = *(const bf16x8*)&As[(wr * 64 + mi * 16 + c) * 64 + hs];
            #pragma unroll
            for (int ni = 0; ni < 4; ++ni)
                bf[ni] = *(const bf16x8*)&Bs[(wc * 64 + ni * 16 + c) * 64 + hs];
            #pragma unroll
            for (int mi = 0; mi < 4; ++mi)
                #pragma unroll
                for (int ni = 0; ni < 4; ++ni)
                    acc[mi][ni] = __builtin_amdgcn_mfma_f32_16x16x32_bf16(
                        af[mi], bf[ni], acc[mi][ni], 0, 0, 0);
        }
        __syncthreads();
    }

    // stage o (+bias) to LDS bf16
    #pragma unroll
    for (int mi = 0; mi < 4; ++mi) {
        #pragma unroll
        for (int ni = 0; ni < 4; ++ni) {
            int colb = wc * 64 + ni * 16 + c;
            float bv = bias[colb];
            #pragma unroll
            for (int r = 0; r < 4; ++r)
                pool[(wr * 64 + mi * 16 + hi * 4 + r) * XS + colb] =
                    f2bf(acc[mi][ni][r] + bv);
        }
    }
    __syncthreads();

    float4 gv  = *(const float4*)(g2 + lane * 4);
    float4 bv2 = *(const float4*)(b2 + lane * 4);
    #pragma unroll 2
    for (int i = 0; i < 16; ++i) {
        int tl = w * 16 + i;
        int t = bm + tl;
        int rr = t2rr(t);
        float4 xv = *(const float4*)(x + (size_t)rr * C_ + lane * 4);
        uint2 ov = *(const uint2*)&pool[tl * XS + lane * 4];
        float x0 = xv.x + bf2f(ov.x & 0xffff);
        float x1 = xv.y + bf2f(ov.x >> 16);
        float x2 = xv.z + bf2f(ov.y & 0xffff);
        float x3 = xv.w + bf2f(ov.y >> 16);
        float s  = x0 + x1 + x2 + x3;
        float ss = x0 * x0 + x1 * x1 + x2 * x2 + x3 * x3;
        #pragma unroll
        for (int m = 1; m < 64; m <<= 1) {
            s  += __shfl_xor(s, m, 64);
            ss += __shfl_xor(ss, m, 64);
        }
        float mean = s * (1.0f / C_);
        float var  = ss * (1.0f / C_) - mean * mean;
        float inv  = rsqrtf(var + 1e-5f);
        uint2 xw, lw;
        xw.x = (unsigned)f2bf(x0) | ((unsigned)f2bf(x1) << 16);
        xw.y = (unsigned)f2bf(x2) | ((unsigned)f2bf(x3) << 16);
        float l0 = (x0 - mean) * inv * gv.x + bv2.x;
        float l1 = (x1 - mean) * inv * gv.y + bv2.y;
        float l2 = (x2 - mean) * inv * gv.z + bv2.z;
        float l3 = (x3 - mean) * inv * gv.w + bv2.w;
        lw.x = (unsigned)f2bf(l0) | ((unsigned)f2bf(l1) << 16);
        lw.y = (unsigned)f2bf(l2) | ((unsigned)f2bf(l3) << 16);
        *(uint2*)(x1_out + (size_t)t * C_ + lane * 4) = xw;
        *(uint2*)(ln_out + (size_t)t * C_ + lane * 4) = lw;
    }
}

// ---------------------------------------------------------------------------
// fc1: ln2 (M_ x 256) @ w1^T + b1 -> tanh-GELU -> natural [row][512] bf16.
// BK=64 single-buffer + swizzle; full-width single-phase Ts epilogue.
// ---------------------------------------------------------------------------
__global__ __launch_bounds__(256) void mgemm_g(
    const unsigned short* __restrict__ A, const unsigned short* __restrict__ W,
    const float* __restrict__ bias, unsigned short* __restrict__ outp)
{
    __shared__ __align__(16) unsigned short pool[128 * TSS];   // 34.8 KB
    unsigned short* As = pool;
    unsigned short* Bs = pool + 8192;
    unsigned short* Ts = pool;

    int tid  = threadIdx.x;
    int w    = tid >> 6;
    int lane = tid & 63;
    int wr = w >> 1, wc = w & 1;
    int bm, bn;
    xcd_decode<4>(gridDim.x, bm, bn);
    int srow8 = lane >> 3;
    int scol  = ((lane & 7) ^ srow8) * 8;
    int c = lane & 15, hi = lane >> 4;

    f32x4 acc[4][4] = {};

    for (int k0 = 0; k0 < 256; k0 += GBK) {
        #pragma unroll
        for (int it = 0; it < 4; ++it) {
            int rb = it * 32 + w * 8;
            gload_lds16(A + (size_t)(bm + rb + srow8) * 256 + k0 + scol, As + rb * 64);
            gload_lds16(W + (size_t)(bn + rb + srow8) * 256 + k0 + scol, Bs + rb * 64);
        }
        __syncthreads();
        #pragma unroll
        for (int kk = 0; kk < 2; ++kk) {
            bf16x8 af[4], bf[4];
            int hs = ((kk * 4 + hi) ^ (c & 7)) * 8;
            #pragma unroll
            for (int mi = 0; mi < 4; ++mi)
                af[mi] = *(const bf16x8*)&As[(wr * 64 + mi * 16 + c) * 64 + hs];
            #pragma unroll
            for (int ni = 0; ni < 4; ++ni)
                bf[ni] = *(const bf16x8*)&Bs[(wc * 64 + ni * 16 + c) * 64 + hs];
            #pragma unroll
            for (int mi = 0; mi < 4; ++mi)
                #pragma unroll
                for (int ni = 0; ni < 4; ++ni)
                    acc[mi][ni] = __builtin_amdgcn_mfma_f32_16x16x32_bf16(
                        af[mi], bf[ni], acc[mi][ni], 0, 0, 0);
        }
        __syncthreads();
    }

    #pragma unroll
    for (int mi = 0; mi < 4; ++mi) {
        #pragma unroll
        for (int ni = 0; ni < 4; ++ni) {
            int colb = wc * 64 + ni * 16 + c;
            float bv = bias[bn + colb];
            #pragma unroll
            for (int r = 0; r < 4; ++r) {
                float v = acc[mi][ni][r] + bv;
                float a = 1.5957691216f * (v + 0.044715f * v * v * v);
                float g = v / (1.0f + __expf(-a));
                Ts[(wr * 64 + mi * 16 + hi * 4 + r) * TSS + colb] = f2bf(g);
            }
        }
    }
    __syncthreads();

    #pragma unroll
    for (int it = 0; it < 8; ++it) {
        int id = it * 256 + tid;
        int row = id >> 4, cx = (id & 15) * 8;
        uint4 v = *(const uint4*)&Ts[row * TSS + cx];
        *(uint4*)&outp[(size_t)(bm + row) * MLPH + bn + cx] = v;
    }
}

// ---------------------------------------------------------------------------
// fc2: gelu (M_ x 512) @ w2^T + b2 + residual(x1 bf16 windowed) -> natural f32.
// BK=64 single-buffer + swizzle; 2-phase LDS-transposed epilogue.
// ---------------------------------------------------------------------------
__global__ __launch_bounds__(256) void mgemm_out(
    const unsigned short* __restrict__ A, const unsigned short* __restrict__ W,
    const float* __restrict__ bias, const unsigned short* __restrict__ x1,
    float* __restrict__ dout)
{
    __shared__ __align__(16) unsigned short pool[16896];   // 33.8 KB
    unsigned short* As = pool;
    unsigned short* Bs = pool + 8192;
    float* stg = (float*)pool;                             // 64 x 132 f32 alias

    int tid  = threadIdx.x;
    int w    = tid >> 6;
    int lane = tid & 63;
    int wr = w >> 1, wc = w & 1;
    int bm, bn;
    xcd_decode<2>(gridDim.x, bm, bn);
    int srow8 = lane >> 3;
    int scol  = ((lane & 7) ^ srow8) * 8;
    int c = lane & 15, hi = lane >> 4;

    f32x4 acc[4][4] = {};

    for (int k0 = 0; k0 < 512; k0 += GBK) {
        #pragma unroll
        for (int it = 0; it < 4; ++it) {
            int rb = it * 32 + w * 8;
            gload_lds16(A + (size_t)(bm + rb + srow8) * 512 + k0 + scol, As + rb * 64);
            gload_lds16(W + (size_t)(bn + rb + srow8) * 512 + k0 + scol, Bs + rb * 64);
        }
        __syncthreads();
        #pragma unroll
        for (int kk = 0; kk < 2; ++kk) {
            bf16x8 af[4], bf[4];
            int hs = ((kk * 4 + hi) ^ (c & 7)) * 8;
            #pragma unroll
            for (int mi = 0; mi < 4; ++mi)
                af[mi] = *(const bf16x8*)&As[(wr * 64 + mi * 16 + c) * 64 + hs];
            #pragma unroll
            for (int ni = 0; ni < 4; ++ni)
                bf[ni] = *(const bf16x8*)&Bs[(wc * 64 + ni * 16 + c) * 64 + hs];
            #pragma unroll
            for (int mi = 0; mi < 4; ++mi)
                #pragma unroll
                for (int ni = 0; ni < 4; ++ni)
                    acc[mi][ni] = __builtin_amdgcn_mfma_f32_16x16x32_bf16(
                        af[mi], bf[ni], acc[mi][ni], 0, 0, 0);
        }
        __syncthreads();
    }

    #pragma unroll
    for (int p = 0; p < 2; ++p) {
        if (wr == p) {
            #pragma unroll
            for (int mi = 0; mi < 4; ++mi)
                #pragma unroll
                for (int ni = 0; ni < 4; ++ni) {
                    int colb = wc * 64 + ni * 16 + c;
                    float bv = bias[bn + colb];
                    #pragma unroll
                    for (int r = 0; r < 4; ++r)
                        stg[(mi * 16 + hi * 4 + r) * 132 + colb] =
                            acc[mi][ni][r] + bv;
                }
        }
        __syncthreads();
        #pragma unroll
        for (int i = 0; i < 8; ++i) {
            int lr = i * 8 + (tid >> 5);         // 0..63
            int t = bm + p * 64 + lr;
            int rr = t2rr(t);
            int col4 = (tid & 31) * 4;
            float4 v = *(const float4*)&stg[lr * 132 + col4];
            uint2 rv = *(const uint2*)&x1[(size_t)t * C_ + bn + col4];
            v.x += bf2f(rv.x & 0xffff);
            v.y += bf2f(rv.x >> 16);
            v.z += bf2f(rv.y & 0xffff);
            v.w += bf2f(rv.y >> 16);
            *(float4*)&dout[(size_t)rr * C_ + bn + col4] = v;
        }
        __syncthreads();
    }
}

// ---------------------------------------------------------------------------
extern "C" void kernel_launch(void* const* d_in, const int* in_sizes, int n_in,
                              void* d_out, int out_size, void* d_ws, size_t ws_size,
                              hipStream_t stream)
{
    (void)in_sizes; (void)n_in; (void)out_size; (void)ws_size;
    const float* x    = (const float*)d_in[0];
    const float* n1g  = (const float*)d_in[3];
    const float* n1b  = (const float*)d_in[4];
    const float* wqkv = (const float*)d_in[5];
    const float* bqkv = (const float*)d_in[6];
    const float* wout = (const float*)d_in[7];
    const float* bout = (const float*)d_in[8];
    const float* n2g  = (const float*)d_in[9];
    const float* n2b  = (const float*)d_in[10];
    const float* w1   = (const float*)d_in[11];
    const float* b1   = (const float*)d_in[12];
    const float* w2   = (const float*)d_in[13];
    const float* b2   = (const float*)d_in[14];
    float* out = (float*)d_out;

    // workspace layout (bf16 shorts)
    unsigned short* bufA_bf = (unsigned short*)d_ws;                 // M*256 (LN1 out, then o_win)
    unsigned short* qkv_bf  = bufA_bf + (size_t)M_ * C_;             // 3*NWH*2048 (later gelu M*512)
    unsigned short* x1_bf   = qkv_bf + (size_t)3 * NWH * WHSZ;       // M*256
    unsigned short* ln2_bf  = x1_bf + (size_t)M_ * C_;               // M*256
    unsigned short* wqkv_bf = ln2_bf + (size_t)M_ * C_;              // contiguous weights
    unsigned short* wout_bf = wqkv_bf + 768 * 256;
    unsigned short* w1_bf   = wout_bf + 256 * 256;
    unsigned short* w2_bf   = w1_bf + 512 * 256;
    unsigned short* gelu    = qkv_bf;   // alias (qkv dead after mattn)

    // 0) weights -> bf16 (single merged launch; regions contiguous)
    cvt4_kernel<<<512, 256, 0, stream>>>(wqkv, wout, w1, w2, wqkv_bf);

    // 1) LN1 + window partition -> bufA_bf
    ln_kernel<<<M_ / 4, 256, 0, stream>>>(x, n1g, n1b, bufA_bf);

    // 2) QKV GEMM -> Q/K/V natural planes (XCD-chunked)
    mgemm_qkv<<<(M_ / 128) * 6, 256, 0, stream>>>(
        bufA_bf, wqkv_bf, bqkv, qkv_bf);

    // 3) MFMA window attention -> o_win (bufA_bf)
    mattn<<<NWH / 4, 256, 0, stream>>>(qkv_bf, bufA_bf);

    // 4) out-proj + residual + LN2 fused -> x1_bf, ln2_bf
    mgemm_ln<<<M_ / 128, 512, 0, stream>>>(
        bufA_bf, wout_bf, bout, x, n2g, n2b, x1_bf, ln2_bf);

    // 5) MLP fc1 + tanh-GELU -> gelu (M_ x 512, natural)
    mgemm_g<<<(M_ / 128) * 4, 256, 0, stream>>>(ln2_bf, w1_bf, b1, gelu);

    // 6) MLP fc2 + residual(x1) -> d_out natural f32
    mgemm_out<<<(M_ / 128) * 2, 256, 0, stream>>>(gelu, w2_bf, b2, x1_bf, out);
}

// Round 15
// 355.056 us; speedup vs baseline: 1.9246x; 1.0445x over previous
//
#include <hip/hip_runtime.h>
#include <hip/hip_bf16.h>
#include <math.h>

// Problem constants (B=32, H=W=56, C=256, heads=8, hd=32, ws=7)
#define NTOK 3136            // 56*56
#define C_ 256
#define HEADS_ 8
#define HD 32
#define WS_ 7
#define L_ 49
#define NWIN 2048            // 32 * 8 * 8
#define NWH 16384            // NWIN * HEADS_
#define M_ 100352            // NWIN * 49  == BATCH*NTOK
#define MLPH 512
#define WHSZ 2048            // per (win,head) plane stride (elems)

typedef __bf16 bf16x8 __attribute__((ext_vector_type(8)));
typedef float f32x4 __attribute__((ext_vector_type(4)));

// native cast -> compiler emits v_cvt_pk_bf16_f32 (RNE), pairs get packed
__device__ __forceinline__ unsigned short f2bf(float f) {
    __bf16 h = (__bf16)f;
    return __builtin_bit_cast(unsigned short, h);
}
__device__ __forceinline__ float bf2f(unsigned short s) {
    union { unsigned u; float f; } v; v.u = ((unsigned)s) << 16;
    return v.f;
}

// windowed token index (49-based) -> natural row index
__device__ __forceinline__ int t2rr(int t) {
    int win = t / L_;
    int l   = t - win * L_;
    int b_  = win >> 6, wh = (win >> 3) & 7, ww = win & 7;
    int ld7 = l / WS_;
    int y   = wh * WS_ + ld7;
    int xc  = ww * WS_ + (l - ld7 * WS_);
    return b_ * NTOK + y * 56 + xc;
}

// XCD-chunked bm-major remap (L2 reuse of the A stripe per XCD)
template <int NBN>
__device__ __forceinline__ void xcd_decode(int nb, int& bm, int& bn) {
    int h = blockIdx.x;
    int fid = (h & 7) * (nb >> 3) + (h >> 3);
    int bmi = fid / NBN;
    bm = bmi * 128;
    bn = (fid - bmi * NBN) * 128;
}

// ---------------------------------------------------------------------------
// merged weight conversion: the 4 bf16 weight regions are contiguous in ws.
// ---------------------------------------------------------------------------
__global__ __launch_bounds__(256) void cvt4_kernel(
    const float* __restrict__ a, const float* __restrict__ b,
    const float* __restrict__ c2, const float* __restrict__ d,
    unsigned short* __restrict__ out)
{
    int i = (blockIdx.x * 256 + threadIdx.x) * 4;
    const float* src; int off;
    if (i < 196608)      { src = a;  off = i; }
    else if (i < 262144) { src = b;  off = i - 196608; }
    else if (i < 393216) { src = c2; off = i - 262144; }
    else                 { src = d;  off = i - 393216; }
    float4 v = *(const float4*)(src + off);
    unsigned short o[4];
    o[0] = f2bf(v.x); o[1] = f2bf(v.y); o[2] = f2bf(v.z); o[3] = f2bf(v.w);
    *(uint2*)(out + i) = *(const uint2*)o;
}

// ---------------------------------------------------------------------------
// LN1: one wave per token; bf16 output in windowed row order (M_ rows).
// ---------------------------------------------------------------------------
__global__ __launch_bounds__(256) void ln_kernel(
    const float* __restrict__ x, const float* __restrict__ gamma,
    const float* __restrict__ beta, unsigned short* __restrict__ out)
{
    int wave = threadIdx.x >> 6;
    int lane = threadIdx.x & 63;
    int p = blockIdx.x * 4 + wave;
    const float* row = x + (size_t)p * C_;
    float4 v = *(const float4*)(row + lane * 4);
    float s  = v.x + v.y + v.z + v.w;
    float ss = v.x * v.x + v.y * v.y + v.z * v.z + v.w * v.w;
    #pragma unroll
    for (int m = 1; m < 64; m <<= 1) {
        s  += __shfl_xor(s, m, 64);
        ss += __shfl_xor(ss, m, 64);
    }
    float mean = s * (1.0f / C_);
    float var  = ss * (1.0f / C_) - mean * mean;
    float inv  = rsqrtf(var + 1e-5f);
    float4 gv = *(const float4*)(gamma + lane * 4);
    float4 bv = *(const float4*)(beta + lane * 4);
    int b_ = p / NTOK, n = p - b_ * NTOK;
    int y = n / 56, xc = n - y * 56;
    int win = (b_ * 8 + y / WS_) * 8 + xc / WS_;
    int l   = (y % WS_) * WS_ + (xc % WS_);
    size_t orow = (size_t)(win * L_ + l) * C_;
    unsigned short o[4];
    o[0] = f2bf((v.x - mean) * inv * gv.x + bv.x);
    o[1] = f2bf((v.y - mean) * inv * gv.y + bv.y);
    o[2] = f2bf((v.z - mean) * inv * gv.z + bv.z);
    o[3] = f2bf((v.w - mean) * inv * gv.w + bv.w);
    *(uint2*)(out + orow + lane * 4) = *(const uint2*)o;
}

// ---------------------------------------------------------------------------
#define GBK 64

__device__ __forceinline__ void gload_lds16(const void* g, void* l) {
    __builtin_amdgcn_global_load_lds(
        (const __attribute__((address_space(1))) unsigned*)g,
        (__attribute__((address_space(3))) unsigned*)l, 16, 0, 0);
}

// ---------------------------------------------------------------------------
// QKV GEMM: A (M_ x 256 windowed) @ wqkv^T -> Q,K,V natural per-(win,head)
// planes [wh][l*32+d]. BK=64 single-buffer + swizzle; full-width Ts epilogue.
// ---------------------------------------------------------------------------
#define TSS 136

__global__ __launch_bounds__(256) void mgemm_qkv(
    const unsigned short* __restrict__ A, const unsigned short* __restrict__ W,
    const float* __restrict__ bias, unsigned short* __restrict__ qkv)
{
    __shared__ __align__(16) unsigned short pool[128 * TSS];   // 34.8 KB
    unsigned short* As = pool;
    unsigned short* Bs = pool + 8192;
    unsigned short* Ts = pool;

    int tid  = threadIdx.x;
    int w    = tid >> 6;
    int lane = tid & 63;
    int wr = w >> 1, wc = w & 1;
    int bm, bn;
    xcd_decode<6>(gridDim.x, bm, bn);
    int srow8 = lane >> 3;
    int scol  = ((lane & 7) ^ srow8) * 8;
    int c = lane & 15, hi = lane >> 4;

    f32x4 acc[4][4] = {};

    for (int k0 = 0; k0 < 256; k0 += GBK) {
        #pragma unroll
        for (int it = 0; it < 4; ++it) {
            int rb = it * 32 + w * 8;
            gload_lds16(A + (size_t)(bm + rb + srow8) * 256 + k0 + scol, As + rb * 64);
            gload_lds16(W + (size_t)(bn + rb + srow8) * 256 + k0 + scol, Bs + rb * 64);
        }
        __syncthreads();
        #pragma unroll
        for (int kk = 0; kk < 2; ++kk) {
            bf16x8 af[4], bf[4];
            int hs = ((kk * 4 + hi) ^ (c & 7)) * 8;
            #pragma unroll
            for (int mi = 0; mi < 4; ++mi)
                af[mi] = *(const bf16x8*)&As[(wr * 64 + mi * 16 + c) * 64 + hs];
            #pragma unroll
            for (int ni = 0; ni < 4; ++ni)
                bf[ni] = *(const bf16x8*)&Bs[(wc * 64 + ni * 16 + c) * 64 + hs];
            #pragma unroll
            for (int mi = 0; mi < 4; ++mi)
                #pragma unroll
                for (int ni = 0; ni < 4; ++ni)
                    acc[mi][ni] = __builtin_amdgcn_mfma_f32_16x16x32_bf16(
                        af[mi], bf[ni], acc[mi][ni], 0, 0, 0);
        }
        __syncthreads();
    }

    #pragma unroll
    for (int mi = 0; mi < 4; ++mi) {
        #pragma unroll
        for (int ni = 0; ni < 4; ++ni) {
            int colb = wc * 64 + ni * 16 + c;
            float bv = bias[bn + colb];
            #pragma unroll
            for (int r = 0; r < 4; ++r)
                Ts[(wr * 64 + mi * 16 + hi * 4 + r) * TSS + colb] =
                    f2bf(acc[mi][ni][r] + bv);
        }
    }
    __syncthreads();

    int which  = bn >> 8;
    int bn_off = bn & 255;
    unsigned short* plane = qkv + (size_t)which * ((size_t)NWH * WHSZ);
    #pragma unroll
    for (int it = 0; it < 8; ++it) {
        int id = it * 256 + tid;
        int row = id >> 4, cx = (id & 15) * 8;
        int grow = bm + row;
        int win = grow / L_, l = grow - win * L_;
        int col = bn_off + cx;
        int head = col >> 5, d0 = col & 31;
        uint4 v = *(const uint4*)&Ts[row * TSS + cx];
        *(uint4*)&plane[(size_t)(win * HEADS_ + head) * WHSZ + l * HD + d0] = v;
    }
}

// ---------------------------------------------------------------------------
// MFMA window attention: 4 waves/block, wave = one (win,head).
// ---------------------------------------------------------------------------
__global__ __launch_bounds__(256) void mattn(
    const unsigned short* __restrict__ qkv, unsigned short* __restrict__ o_win)
{
    __shared__ __align__(16) unsigned short P_lds[4][64][72];
    int wave = threadIdx.x >> 6, lane = threadIdx.x & 63;
    int c = lane & 15, hi = lane >> 4;
    int wh = blockIdx.x * 4 + wave;
    int win = wh >> 3, head = wh & 7;
    const unsigned short* qb = qkv + (size_t)wh * WHSZ;
    const unsigned short* kb = qb + (size_t)NWH * WHSZ;
    const unsigned short* vb = kb + (size_t)NWH * WHSZ;

    unsigned short* Vs = &P_lds[wave][0][0];
    #pragma unroll
    for (int i = 0; i < 4; ++i) {
        int idx = i * 64 + lane;
        *(uint4*)&Vs[idx * 8] = *(const uint4*)(vb + idx * 8);
    }

    bf16x8 af[4], bk[4];
    #pragma unroll
    for (int mi = 0; mi < 4; ++mi)
        af[mi] = *(const bf16x8*)(qb + (mi * 16 + c) * HD + hi * 8);
    #pragma unroll
    for (int ni = 0; ni < 4; ++ni)
        bk[ni] = *(const bf16x8*)(kb + (ni * 16 + c) * HD + hi * 8);

    bf16x8 vf[2][2];
    #pragma unroll
    for (int ks = 0; ks < 2; ++ks)
        #pragma unroll
        for (int ni = 0; ni < 2; ++ni) {
            union { unsigned short s[8]; bf16x8 v; } uu;
            #pragma unroll
            for (int j = 0; j < 8; ++j)
                uu.s[j] = Vs[(ks * 32 + hi * 8 + j) * HD + ni * 16 + c];
            vf[ks][ni] = uu.v;
        }

    f32x4 sacc[4][4] = {};
    #pragma unroll
    for (int mi = 0; mi < 4; ++mi)
        #pragma unroll
        for (int ni = 0; ni < 4; ++ni)
            sacc[mi][ni] = __builtin_amdgcn_mfma_f32_16x16x32_bf16(
                af[mi], bk[ni], sacc[mi][ni], 0, 0, 0);

    const float scale = 0.17677669529663687f;
    float inv_[4][4];
    #pragma unroll
    for (int mi = 0; mi < 4; ++mi) {
        #pragma unroll
        for (int r = 0; r < 4; ++r) {
            float sv[4];
            float m = -1e30f;
            #pragma unroll
            for (int ni = 0; ni < 4; ++ni) {
                float v = sacc[mi][ni][r] * scale;
                v = (ni * 16 + c < L_) ? v : -1e30f;
                sv[ni] = v;
                m = fmaxf(m, v);
            }
            #pragma unroll
            for (int msk = 1; msk < 16; msk <<= 1)
                m = fmaxf(m, __shfl_xor(m, msk, 64));
            float sum = 0.f;
            unsigned short pb[4];
            #pragma unroll
            for (int ni = 0; ni < 4; ++ni) {
                float p = __expf(sv[ni] - m);
                sum += p;
                pb[ni] = f2bf(p);
            }
            #pragma unroll
            for (int msk = 1; msk < 16; msk <<= 1)
                sum += __shfl_xor(sum, msk, 64);
            inv_[mi][r] = __builtin_amdgcn_rcpf(sum);
            int q = mi * 16 + hi * 4 + r;
            #pragma unroll
            for (int ni = 0; ni < 4; ++ni)
                P_lds[wave][q][ni * 16 + c] = pb[ni];
        }
    }

    f32x4 oacc[4][2] = {};
    #pragma unroll
    for (int ks = 0; ks < 2; ++ks) {
        bf16x8 pa[4];
        #pragma unroll
        for (int mi = 0; mi < 4; ++mi)
            pa[mi] = *(const bf16x8*)&P_lds[wave][mi * 16 + c][ks * 32 + hi * 8];
        #pragma unroll
        for (int mi = 0; mi < 4; ++mi)
            #pragma unroll
            for (int ni = 0; ni < 2; ++ni)
                oacc[mi][ni] = __builtin_amdgcn_mfma_f32_16x16x32_bf16(
                    pa[mi], vf[ks][ni], oacc[mi][ni], 0, 0, 0);
    }

    #pragma unroll
    for (int mi = 0; mi < 4; ++mi) {
        #pragma unroll
        for (int r = 0; r < 4; ++r) {
            int q = mi * 16 + hi * 4 + r;
            if (q < L_) {
                size_t rowoff = ((size_t)(win * L_ + q)) * C_ + head * HD;
                float iv = inv_[mi][r];
                #pragma unroll
                for (int ni = 0; ni < 2; ++ni)
                    o_win[rowoff + ni * 16 + c] = f2bf(oacc[mi][ni][r] * iv);
            }
        }
    }
}

// ---------------------------------------------------------------------------
// mgemm_ln: out-proj + residual(x gathered f32) + LN2. 512 threads,
// 128 rows x full 256 cols. BK=64 single-buffer + swizzle.
// ---------------------------------------------------------------------------
#define XS 260

__global__ __launch_bounds__(512) void mgemm_ln(
    const unsigned short* __restrict__ A, const unsigned short* __restrict__ W,
    const float* __restrict__ bias, const float* __restrict__ x,
    const float* __restrict__ g2, const float* __restrict__ b2,
    unsigned short* __restrict__ x1_out, unsigned short* __restrict__ ln_out)
{
    __shared__ __align__(16) unsigned short pool[128 * XS];   // 65 KB
    unsigned short* As = pool;
    unsigned short* Bs = pool + 8192;

    int tid  = threadIdx.x;
    int w    = tid >> 6;
    int lane = tid & 63;
    int wr = w >> 2, wc = w & 3;
    int bm = blockIdx.x * 128;
    int srow8 = lane >> 3;
    int scol  = ((lane & 7) ^ srow8) * 8;
    int c = lane & 15, hi = lane >> 4;

    f32x4 acc[4][4] = {};

    for (int k0 = 0; k0 < 256; k0 += GBK) {
        #pragma unroll
        for (int it = 0; it < 2; ++it) {
            int rb = it * 64 + w * 8;
            gload_lds16(A + (size_t)(bm + rb + srow8) * 256 + k0 + scol, As + rb * 64);
        }
        #pragma unroll
        for (int it = 0; it < 4; ++it) {
            int rb = it * 64 + w * 8;
            gload_lds16(W + (size_t)(rb + srow8) * 256 + k0 + scol, Bs + rb * 64);
        }
        __syncthreads();
        #pragma unroll
        for (int kk = 0; kk < 2; ++kk) {
            bf16x8 af[4], bf[4];
            int hs = ((kk * 4 + hi) ^ (c & 7)) * 8;
            #pragma unroll
            for (int mi = 0; mi < 4; ++mi)
                af[mi] = *(const bf16x8*)&As[(wr * 64 + mi * 16 + c) * 64 + hs];
            #pragma unroll
            for (int ni = 0; ni < 4; ++ni)
                bf[ni] = *(const bf16x8*)&Bs[(wc * 64 + ni * 16 + c) * 64 + hs];
            #pragma unroll
            for (int mi = 0; mi < 4; ++mi)
                #pragma unroll
                for (int ni = 0; ni < 4; ++ni)
                    acc[mi][ni] = __builtin_amdgcn_mfma_f32_16x16x32_bf16(
                        af[mi], bf[ni], acc[mi][ni], 0, 0, 0);
        }
        __syncthreads();
    }

    #pragma unroll
    for (int mi = 0; mi < 4; ++mi) {
        #pragma unroll
        for (int ni = 0; ni < 4; ++ni) {
            int colb = wc * 64 + ni * 16 + c;
            float bv = bias[colb];
            #pragma unroll
            for (int r = 0; r < 4; ++r)
                pool[(wr * 64 + mi * 16 + hi * 4 + r) * XS + colb] =
                    f2bf(acc[mi][ni][r] + bv);
        }
    }
    __syncthreads();

    float4 gv  = *(const float4*)(g2 + lane * 4);
    float4 bv2 = *(const float4*)(b2 + lane * 4);
    #pragma unroll 2
    for (int i = 0; i < 16; ++i) {
        int tl = w * 16 + i;
        int t = bm + tl;
        int rr = t2rr(t);
        float4 xv = *(const float4*)(x + (size_t)rr * C_ + lane * 4);
        uint2 ov = *(const uint2*)&pool[tl * XS + lane * 4];
        float x0 = xv.x + bf2f(ov.x & 0xffff);
        float x1 = xv.y + bf2f(ov.x >> 16);
        float x2 = xv.z + bf2f(ov.y & 0xffff);
        float x3 = xv.w + bf2f(ov.y >> 16);
        float s  = x0 + x1 + x2 + x3;
        float ss = x0 * x0 + x1 * x1 + x2 * x2 + x3 * x3;
        #pragma unroll
        for (int m = 1; m < 64; m <<= 1) {
            s  += __shfl_xor(s, m, 64);
            ss += __shfl_xor(ss, m, 64);
        }
        float mean = s * (1.0f / C_);
        float var  = ss * (1.0f / C_) - mean * mean;
        float inv  = rsqrtf(var + 1e-5f);
        uint2 xw, lw;
        xw.x = (unsigned)f2bf(x0) | ((unsigned)f2bf(x1) << 16);
        xw.y = (unsigned)f2bf(x2) | ((unsigned)f2bf(x3) << 16);
        float l0 = (x0 - mean) * inv * gv.x + bv2.x;
        float l1 = (x1 - mean) * inv * gv.y + bv2.y;
        float l2 = (x2 - mean) * inv * gv.z + bv2.z;
        float l3 = (x3 - mean) * inv * gv.w + bv2.w;
        lw.x = (unsigned)f2bf(l0) | ((unsigned)f2bf(l1) << 16);
        lw.y = (unsigned)f2bf(l2) | ((unsigned)f2bf(l3) << 16);
        *(uint2*)(x1_out + (size_t)t * C_ + lane * 4) = xw;
        *(uint2*)(ln_out + (size_t)t * C_ + lane * 4) = lw;
    }
}

// ---------------------------------------------------------------------------
// fc1: ln2 (M_ x 256) @ w1^T + b1 -> tanh-GELU (rcpf) -> natural bf16.
// BK=64 single-buffer + swizzle; full-width single-phase Ts epilogue.
// ---------------------------------------------------------------------------
__global__ __launch_bounds__(256) void mgemm_g(
    const unsigned short* __restrict__ A, const unsigned short* __restrict__ W,
    const float* __restrict__ bias, unsigned short* __restrict__ outp)
{
    __shared__ __align__(16) unsigned short pool[128 * TSS];   // 34.8 KB
    unsigned short* As = pool;
    unsigned short* Bs = pool + 8192;
    unsigned short* Ts = pool;

    int tid  = threadIdx.x;
    int w    = tid >> 6;
    int lane = tid & 63;
    int wr = w >> 1, wc = w & 1;
    int bm, bn;
    xcd_decode<4>(gridDim.x, bm, bn);
    int srow8 = lane >> 3;
    int scol  = ((lane & 7) ^ srow8) * 8;
    int c = lane & 15, hi = lane >> 4;

    f32x4 acc[4][4] = {};

    for (int k0 = 0; k0 < 256; k0 += GBK) {
        #pragma unroll
        for (int it = 0; it < 4; ++it) {
            int rb = it * 32 + w * 8;
            gload_lds16(A + (size_t)(bm + rb + srow8) * 256 + k0 + scol, As + rb * 64);
            gload_lds16(W + (size_t)(bn + rb + srow8) * 256 + k0 + scol, Bs + rb * 64);
        }
        __syncthreads();
        #pragma unroll
        for (int kk = 0; kk < 2; ++kk) {
            bf16x8 af[4], bf[4];
            int hs = ((kk * 4 + hi) ^ (c & 7)) * 8;
            #pragma unroll
            for (int mi = 0; mi < 4; ++mi)
                af[mi] = *(const bf16x8*)&As[(wr * 64 + mi * 16 + c) * 64 + hs];
            #pragma unroll
            for (int ni = 0; ni < 4; ++ni)
                bf[ni] = *(const bf16x8*)&Bs[(wc * 64 + ni * 16 + c) * 64 + hs];
            #pragma unroll
            for (int mi = 0; mi < 4; ++mi)
                #pragma unroll
                for (int ni = 0; ni < 4; ++ni)
                    acc[mi][ni] = __builtin_amdgcn_mfma_f32_16x16x32_bf16(
                        af[mi], bf[ni], acc[mi][ni], 0, 0, 0);
        }
        __syncthreads();
    }

    #pragma unroll
    for (int mi = 0; mi < 4; ++mi) {
        #pragma unroll
        for (int ni = 0; ni < 4; ++ni) {
            int colb = wc * 64 + ni * 16 + c;
            float bv = bias[bn + colb];
            #pragma unroll
            for (int r = 0; r < 4; ++r) {
                float v = acc[mi][ni][r] + bv;
                float a = 1.5957691216f * (v + 0.044715f * v * v * v);
                float g = v * __builtin_amdgcn_rcpf(1.0f + __expf(-a));
                Ts[(wr * 64 + mi * 16 + hi * 4 + r) * TSS + colb] = f2bf(g);
            }
        }
    }
    __syncthreads();

    #pragma unroll
    for (int it = 0; it < 8; ++it) {
        int id = it * 256 + tid;
        int row = id >> 4, cx = (id & 15) * 8;
        uint4 v = *(const uint4*)&Ts[row * TSS + cx];
        *(uint4*)&outp[(size_t)(bm + row) * MLPH + bn + cx] = v;
    }
}

// ---------------------------------------------------------------------------
// fc2: gelu (M_ x 512) @ w2^T + b2 + residual(x1 bf16 windowed) -> natural f32.
// BK=64 single-buffer + swizzle; 2-phase LDS-transposed epilogue.
// ---------------------------------------------------------------------------
__global__ __launch_bounds__(256) void mgemm_out(
    const unsigned short* __restrict__ A, const unsigned short* __restrict__ W,
    const float* __restrict__ bias, const unsigned short* __restrict__ x1,
    float* __restrict__ dout)
{
    __shared__ __align__(16) unsigned short pool[16896];   // 33.8 KB
    unsigned short* As = pool;
    unsigned short* Bs = pool + 8192;
    float* stg = (float*)pool;

    int tid  = threadIdx.x;
    int w    = tid >> 6;
    int lane = tid & 63;
    int wr = w >> 1, wc = w & 1;
    int bm, bn;
    xcd_decode<2>(gridDim.x, bm, bn);
    int srow8 = lane >> 3;
    int scol  = ((lane & 7) ^ srow8) * 8;
    int c = lane & 15, hi = lane >> 4;

    f32x4 acc[4][4] = {};

    for (int k0 = 0; k0 < 512; k0 += GBK) {
        #pragma unroll
        for (int it = 0; it < 4; ++it) {
            int rb = it * 32 + w * 8;
            gload_lds16(A + (size_t)(bm + rb + srow8) * 512 + k0 + scol, As + rb * 64);
            gload_lds16(W + (size_t)(bn + rb + srow8) * 512 + k0 + scol, Bs + rb * 64);
        }
        __syncthreads();
        #pragma unroll
        for (int kk = 0; kk < 2; ++kk) {
            bf16x8 af[4], bf[4];
            int hs = ((kk * 4 + hi) ^ (c & 7)) * 8;
            #pragma unroll
            for (int mi = 0; mi < 4; ++mi)
                af[mi] = *(const bf16x8*)&As[(wr * 64 + mi * 16 + c) * 64 + hs];
            #pragma unroll
            for (int ni = 0; ni < 4; ++ni)
                bf[ni] = *(const bf16x8*)&Bs[(wc * 64 + ni * 16 + c) * 64 + hs];
            #pragma unroll
            for (int mi = 0; mi < 4; ++mi)
                #pragma unroll
                for (int ni = 0; ni < 4; ++ni)
                    acc[mi][ni] = __builtin_amdgcn_mfma_f32_16x16x32_bf16(
                        af[mi], bf[ni], acc[mi][ni], 0, 0, 0);
        }
        __syncthreads();
    }

    #pragma unroll
    for (int p = 0; p < 2; ++p) {
        if (wr == p) {
            #pragma unroll
            for (int mi = 0; mi < 4; ++mi)
                #pragma unroll
                for (int ni = 0; ni < 4; ++ni) {
                    int colb = wc * 64 + ni * 16 + c;
                    float bv = bias[bn + colb];
                    #pragma unroll
                    for (int r = 0; r < 4; ++r)
                        stg[(mi * 16 + hi * 4 + r) * 132 + colb] =
                            acc[mi][ni][r] + bv;
                }
        }
        __syncthreads();
        #pragma unroll
        for (int i = 0; i < 8; ++i) {
            int lr = i * 8 + (tid >> 5);
            int t = bm + p * 64 + lr;
            int rr = t2rr(t);
            int col4 = (tid & 31) * 4;
            float4 v = *(const float4*)&stg[lr * 132 + col4];
            uint2 rv = *(const uint2*)&x1[(size_t)t * C_ + bn + col4];
            v.x += bf2f(rv.x & 0xffff);
            v.y += bf2f(rv.x >> 16);
            v.z += bf2f(rv.y & 0xffff);
            v.w += bf2f(rv.y >> 16);
            *(float4*)&dout[(size_t)rr * C_ + bn + col4] = v;
        }
        __syncthreads();
    }
}

// ---------------------------------------------------------------------------
extern "C" void kernel_launch(void* const* d_in, const int* in_sizes, int n_in,
                              void* d_out, int out_size, void* d_ws, size_t ws_size,
                              hipStream_t stream)
{
    (void)in_sizes; (void)n_in; (void)out_size; (void)ws_size;
    const float* x    = (const float*)d_in[0];
    const float* n1g  = (const float*)d_in[3];
    const float* n1b  = (const float*)d_in[4];
    const float* wqkv = (const float*)d_in[5];
    const float* bqkv = (const float*)d_in[6];
    const float* wout = (const float*)d_in[7];
    const float* bout = (const float*)d_in[8];
    const float* n2g  = (const float*)d_in[9];
    const float* n2b  = (const float*)d_in[10];
    const float* w1   = (const float*)d_in[11];
    const float* b1   = (const float*)d_in[12];
    const float* w2   = (const float*)d_in[13];
    const float* b2   = (const float*)d_in[14];
    float* out = (float*)d_out;

    // workspace layout (bf16 shorts)
    unsigned short* bufA_bf = (unsigned short*)d_ws;                 // M*256 (LN1 out, then o_win)
    unsigned short* qkv_bf  = bufA_bf + (size_t)M_ * C_;             // 3*NWH*2048 (later gelu M*512)
    unsigned short* x1_bf   = qkv_bf + (size_t)3 * NWH * WHSZ;       // M*256
    unsigned short* ln2_bf  = x1_bf + (size_t)M_ * C_;               // M*256
    unsigned short* wqkv_bf = ln2_bf + (size_t)M_ * C_;              // contiguous weights
    unsigned short* wout_bf = wqkv_bf + 768 * 256;
    unsigned short* w1_bf   = wout_bf + 256 * 256;
    unsigned short* w2_bf   = w1_bf + 512 * 256;
    unsigned short* gelu    = qkv_bf;   // alias (qkv dead after mattn)

    // 0) weights -> bf16 (single merged launch; regions contiguous)
    cvt4_kernel<<<512, 256, 0, stream>>>(wqkv, wout, w1, w2, wqkv_bf);

    // 1) LN1 + window partition -> bufA_bf
    ln_kernel<<<M_ / 4, 256, 0, stream>>>(x, n1g, n1b, bufA_bf);

    // 2) QKV GEMM -> Q/K/V natural planes (XCD-chunked)
    mgemm_qkv<<<(M_ / 128) * 6, 256, 0, stream>>>(
        bufA_bf, wqkv_bf, bqkv, qkv_bf);

    // 3) MFMA window attention -> o_win (bufA_bf)
    mattn<<<NWH / 4, 256, 0, stream>>>(qkv_bf, bufA_bf);

    // 4) out-proj + residual + LN2 fused -> x1_bf, ln2_bf
    mgemm_ln<<<M_ / 128, 512, 0, stream>>>(
        bufA_bf, wout_bf, bout, x, n2g, n2b, x1_bf, ln2_bf);

    // 5) MLP fc1 + tanh-GELU -> gelu (M_ x 512, natural)
    mgemm_g<<<(M_ / 128) * 4, 256, 0, stream>>>(ln2_bf, w1_bf, b1, gelu);

    // 6) MLP fc2 + residual(x1) -> d_out natural f32
    mgemm_out<<<(M_ / 128) * 2, 256, 0, stream>>>(gelu, w2_bf, b2, x1_bf, out);
}

// Round 16
// 352.499 us; speedup vs baseline: 1.9386x; 1.0073x over previous
//
#include <hip/hip_runtime.h>
#include <hip/hip_bf16.h>
#include <math.h>

// Problem constants (B=32, H=W=56, C=256, heads=8, hd=32, ws=7)
#define NTOK 3136            // 56*56
#define C_ 256
#define HEADS_ 8
#define HD 32
#define WS_ 7
#define L_ 49
#define NWIN 2048            // 32 * 8 * 8
#define NWH 16384            // NWIN * HEADS_
#define M_ 100352            // NWIN * 49  == BATCH*NTOK
#define MLPH 512
#define WHSZ 2048            // per (win,head) plane stride (elems)

typedef __bf16 bf16x8 __attribute__((ext_vector_type(8)));
typedef float f32x4 __attribute__((ext_vector_type(4)));

// native cast -> compiler emits v_cvt_pk_bf16_f32 (RNE), pairs get packed
__device__ __forceinline__ unsigned short f2bf(float f) {
    __bf16 h = (__bf16)f;
    return __builtin_bit_cast(unsigned short, h);
}
__device__ __forceinline__ float bf2f(unsigned short s) {
    union { unsigned u; float f; } v; v.u = ((unsigned)s) << 16;
    return v.f;
}

// windowed token index (49-based) -> natural row index
__device__ __forceinline__ int t2rr(int t) {
    int win = t / L_;
    int l   = t - win * L_;
    int b_  = win >> 6, wh = (win >> 3) & 7, ww = win & 7;
    int ld7 = l / WS_;
    int y   = wh * WS_ + ld7;
    int xc  = ww * WS_ + (l - ld7 * WS_);
    return b_ * NTOK + y * 56 + xc;
}

// XCD-chunked bm-major remap (L2 reuse of the A stripe per XCD)
template <int NBN>
__device__ __forceinline__ void xcd_decode(int nb, int& bm, int& bn) {
    int h = blockIdx.x;
    int fid = (h & 7) * (nb >> 3) + (h >> 3);
    int bmi = fid / NBN;
    bm = bmi * 128;
    bn = (fid - bmi * NBN) * 128;
}

// ---------------------------------------------------------------------------
// LN1: one wave per token; bf16 output in windowed row order (M_ rows).
// Blocks 0..511 additionally convert the 4 weight matrices (524288 f32) to
// bf16 (1024 elems/block) -- replaces the separate cvt dispatch; weights are
// consumed only by LATER dispatches, so no intra-kernel ordering is needed.
// ---------------------------------------------------------------------------
__global__ __launch_bounds__(256) void ln_kernel(
    const float* __restrict__ x, const float* __restrict__ gamma,
    const float* __restrict__ beta, unsigned short* __restrict__ out,
    const float* __restrict__ wqkv, const float* __restrict__ wout,
    const float* __restrict__ w1, const float* __restrict__ w2,
    unsigned short* __restrict__ wout_bf16)
{
    if (blockIdx.x < 512) {
        int i = blockIdx.x * 1024 + threadIdx.x * 4;
        const float* src; int off;
        if (i < 196608)      { src = wqkv; off = i; }
        else if (i < 262144) { src = wout; off = i - 196608; }
        else if (i < 393216) { src = w1;   off = i - 262144; }
        else                 { src = w2;   off = i - 393216; }
        float4 v = *(const float4*)(src + off);
        unsigned short o[4];
        o[0] = f2bf(v.x); o[1] = f2bf(v.y); o[2] = f2bf(v.z); o[3] = f2bf(v.w);
        *(uint2*)(wout_bf16 + i) = *(const uint2*)o;
    }

    int wave = threadIdx.x >> 6;
    int lane = threadIdx.x & 63;
    int p = blockIdx.x * 4 + wave;
    const float* row = x + (size_t)p * C_;
    float4 v = *(const float4*)(row + lane * 4);
    float s  = v.x + v.y + v.z + v.w;
    float ss = v.x * v.x + v.y * v.y + v.z * v.z + v.w * v.w;
    #pragma unroll
    for (int m = 1; m < 64; m <<= 1) {
        s  += __shfl_xor(s, m, 64);
        ss += __shfl_xor(ss, m, 64);
    }
    float mean = s * (1.0f / C_);
    float var  = ss * (1.0f / C_) - mean * mean;
    float inv  = rsqrtf(var + 1e-5f);
    float4 gv = *(const float4*)(gamma + lane * 4);
    float4 bv = *(const float4*)(beta + lane * 4);
    int b_ = p / NTOK, n = p - b_ * NTOK;
    int y = n / 56, xc = n - y * 56;
    int win = (b_ * 8 + y / WS_) * 8 + xc / WS_;
    int l   = (y % WS_) * WS_ + (xc % WS_);
    size_t orow = (size_t)(win * L_ + l) * C_;
    unsigned short o[4];
    o[0] = f2bf((v.x - mean) * inv * gv.x + bv.x);
    o[1] = f2bf((v.y - mean) * inv * gv.y + bv.y);
    o[2] = f2bf((v.z - mean) * inv * gv.z + bv.z);
    o[3] = f2bf((v.w - mean) * inv * gv.w + bv.w);
    *(uint2*)(out + orow + lane * 4) = *(const uint2*)o;
}

// ---------------------------------------------------------------------------
#define GBK 64

__device__ __forceinline__ void gload_lds16(const void* g, void* l) {
    __builtin_amdgcn_global_load_lds(
        (const __attribute__((address_space(1))) unsigned*)g,
        (__attribute__((address_space(3))) unsigned*)l, 16, 0, 0);
}

// ---------------------------------------------------------------------------
// QKV GEMM: A (M_ x 256 windowed) @ wqkv^T -> Q,K,V natural per-(win,head)
// planes [wh][l*32+d]. BK=64 single-buffer + swizzle; full-width Ts epilogue.
// ---------------------------------------------------------------------------
#define TSS 136

__global__ __launch_bounds__(256) void mgemm_qkv(
    const unsigned short* __restrict__ A, const unsigned short* __restrict__ W,
    const float* __restrict__ bias, unsigned short* __restrict__ qkv)
{
    __shared__ __align__(16) unsigned short pool[128 * TSS];   // 34.8 KB
    unsigned short* As = pool;
    unsigned short* Bs = pool + 8192;
    unsigned short* Ts = pool;

    int tid  = threadIdx.x;
    int w    = tid >> 6;
    int lane = tid & 63;
    int wr = w >> 1, wc = w & 1;
    int bm, bn;
    xcd_decode<6>(gridDim.x, bm, bn);
    int srow8 = lane >> 3;
    int scol  = ((lane & 7) ^ srow8) * 8;
    int c = lane & 15, hi = lane >> 4;

    f32x4 acc[4][4] = {};

    for (int k0 = 0; k0 < 256; k0 += GBK) {
        #pragma unroll
        for (int it = 0; it < 4; ++it) {
            int rb = it * 32 + w * 8;
            gload_lds16(A + (size_t)(bm + rb + srow8) * 256 + k0 + scol, As + rb * 64);
            gload_lds16(W + (size_t)(bn + rb + srow8) * 256 + k0 + scol, Bs + rb * 64);
        }
        __syncthreads();
        #pragma unroll
        for (int kk = 0; kk < 2; ++kk) {
            bf16x8 af[4], bf[4];
            int hs = ((kk * 4 + hi) ^ (c & 7)) * 8;
            #pragma unroll
            for (int mi = 0; mi < 4; ++mi)
                af[mi] = *(const bf16x8*)&As[(wr * 64 + mi * 16 + c) * 64 + hs];
            #pragma unroll
            for (int ni = 0; ni < 4; ++ni)
                bf[ni] = *(const bf16x8*)&Bs[(wc * 64 + ni * 16 + c) * 64 + hs];
            #pragma unroll
            for (int mi = 0; mi < 4; ++mi)
                #pragma unroll
                for (int ni = 0; ni < 4; ++ni)
                    acc[mi][ni] = __builtin_amdgcn_mfma_f32_16x16x32_bf16(
                        af[mi], bf[ni], acc[mi][ni], 0, 0, 0);
        }
        __syncthreads();
    }

    #pragma unroll
    for (int mi = 0; mi < 4; ++mi) {
        #pragma unroll
        for (int ni = 0; ni < 4; ++ni) {
            int colb = wc * 64 + ni * 16 + c;
            float bv = bias[bn + colb];
            #pragma unroll
            for (int r = 0; r < 4; ++r)
                Ts[(wr * 64 + mi * 16 + hi * 4 + r) * TSS + colb] =
                    f2bf(acc[mi][ni][r] + bv);
        }
    }
    __syncthreads();

    int which  = bn >> 8;
    int bn_off = bn & 255;
    unsigned short* plane = qkv + (size_t)which * ((size_t)NWH * WHSZ);
    #pragma unroll
    for (int it = 0; it < 8; ++it) {
        int id = it * 256 + tid;
        int row = id >> 4, cx = (id & 15) * 8;
        int grow = bm + row;
        int win = grow / L_, l = grow - win * L_;
        int col = bn_off + cx;
        int head = col >> 5, d0 = col & 31;
        uint4 v = *(const uint4*)&Ts[row * TSS + cx];
        *(uint4*)&plane[(size_t)(win * HEADS_ + head) * WHSZ + l * HD + d0] = v;
    }
}

// ---------------------------------------------------------------------------
// MFMA window attention: 4 waves/block, wave = one (win,head).
// ---------------------------------------------------------------------------
__global__ __launch_bounds__(256) void mattn(
    const unsigned short* __restrict__ qkv, unsigned short* __restrict__ o_win)
{
    __shared__ __align__(16) unsigned short P_lds[4][64][72];
    int wave = threadIdx.x >> 6, lane = threadIdx.x & 63;
    int c = lane & 15, hi = lane >> 4;
    int wh = blockIdx.x * 4 + wave;
    int win = wh >> 3, head = wh & 7;
    const unsigned short* qb = qkv + (size_t)wh * WHSZ;
    const unsigned short* kb = qb + (size_t)NWH * WHSZ;
    const unsigned short* vb = kb + (size_t)NWH * WHSZ;

    unsigned short* Vs = &P_lds[wave][0][0];
    #pragma unroll
    for (int i = 0; i < 4; ++i) {
        int idx = i * 64 + lane;
        *(uint4*)&Vs[idx * 8] = *(const uint4*)(vb + idx * 8);
    }

    bf16x8 af[4], bk[4];
    #pragma unroll
    for (int mi = 0; mi < 4; ++mi)
        af[mi] = *(const bf16x8*)(qb + (mi * 16 + c) * HD + hi * 8);
    #pragma unroll
    for (int ni = 0; ni < 4; ++ni)
        bk[ni] = *(const bf16x8*)(kb + (ni * 16 + c) * HD + hi * 8);

    bf16x8 vf[2][2];
    #pragma unroll
    for (int ks = 0; ks < 2; ++ks)
        #pragma unroll
        for (int ni = 0; ni < 2; ++ni) {
            union { unsigned short s[8]; bf16x8 v; } uu;
            #pragma unroll
            for (int j = 0; j < 8; ++j)
                uu.s[j] = Vs[(ks * 32 + hi * 8 + j) * HD + ni * 16 + c];
            vf[ks][ni] = uu.v;
        }

    f32x4 sacc[4][4] = {};
    #pragma unroll
    for (int mi = 0; mi < 4; ++mi)
        #pragma unroll
        for (int ni = 0; ni < 4; ++ni)
            sacc[mi][ni] = __builtin_amdgcn_mfma_f32_16x16x32_bf16(
                af[mi], bk[ni], sacc[mi][ni], 0, 0, 0);

    const float scale = 0.17677669529663687f;
    float inv_[4][4];
    #pragma unroll
    for (int mi = 0; mi < 4; ++mi) {
        #pragma unroll
        for (int r = 0; r < 4; ++r) {
            float sv[4];
            float m = -1e30f;
            #pragma unroll
            for (int ni = 0; ni < 4; ++ni) {
                float v = sacc[mi][ni][r] * scale;
                v = (ni * 16 + c < L_) ? v : -1e30f;
                sv[ni] = v;
                m = fmaxf(m, v);
            }
            #pragma unroll
            for (int msk = 1; msk < 16; msk <<= 1)
                m = fmaxf(m, __shfl_xor(m, msk, 64));
            float sum = 0.f;
            unsigned short pb[4];
            #pragma unroll
            for (int ni = 0; ni < 4; ++ni) {
                float p = __expf(sv[ni] - m);
                sum += p;
                pb[ni] = f2bf(p);
            }
            #pragma unroll
            for (int msk = 1; msk < 16; msk <<= 1)
                sum += __shfl_xor(sum, msk, 64);
            inv_[mi][r] = __builtin_amdgcn_rcpf(sum);
            int q = mi * 16 + hi * 4 + r;
            #pragma unroll
            for (int ni = 0; ni < 4; ++ni)
                P_lds[wave][q][ni * 16 + c] = pb[ni];
        }
    }

    f32x4 oacc[4][2] = {};
    #pragma unroll
    for (int ks = 0; ks < 2; ++ks) {
        bf16x8 pa[4];
        #pragma unroll
        for (int mi = 0; mi < 4; ++mi)
            pa[mi] = *(const bf16x8*)&P_lds[wave][mi * 16 + c][ks * 32 + hi * 8];
        #pragma unroll
        for (int mi = 0; mi < 4; ++mi)
            #pragma unroll
            for (int ni = 0; ni < 2; ++ni)
                oacc[mi][ni] = __builtin_amdgcn_mfma_f32_16x16x32_bf16(
                    pa[mi], vf[ks][ni], oacc[mi][ni], 0, 0, 0);
    }

    #pragma unroll
    for (int mi = 0; mi < 4; ++mi) {
        #pragma unroll
        for (int r = 0; r < 4; ++r) {
            int q = mi * 16 + hi * 4 + r;
            if (q < L_) {
                size_t rowoff = ((size_t)(win * L_ + q)) * C_ + head * HD;
                float iv = inv_[mi][r];
                #pragma unroll
                for (int ni = 0; ni < 2; ++ni)
                    o_win[rowoff + ni * 16 + c] = f2bf(oacc[mi][ni][r] * iv);
            }
        }
    }
}

// ---------------------------------------------------------------------------
// mgemm_ln: out-proj + residual(x gathered f32) + LN2. 512 threads,
// 128 rows x full 256 cols. BK=64 single-buffer + swizzle.
// ---------------------------------------------------------------------------
#define XS 260

__global__ __launch_bounds__(512) void mgemm_ln(
    const unsigned short* __restrict__ A, const unsigned short* __restrict__ W,
    const float* __restrict__ bias, const float* __restrict__ x,
    const float* __restrict__ g2, const float* __restrict__ b2,
    unsigned short* __restrict__ x1_out, unsigned short* __restrict__ ln_out)
{
    __shared__ __align__(16) unsigned short pool[128 * XS];   // 65 KB
    unsigned short* As = pool;
    unsigned short* Bs = pool + 8192;

    int tid  = threadIdx.x;
    int w    = tid >> 6;
    int lane = tid & 63;
    int wr = w >> 2, wc = w & 3;
    int bm = blockIdx.x * 128;
    int srow8 = lane >> 3;
    int scol  = ((lane & 7) ^ srow8) * 8;
    int c = lane & 15, hi = lane >> 4;

    f32x4 acc[4][4] = {};

    for (int k0 = 0; k0 < 256; k0 += GBK) {
        #pragma unroll
        for (int it = 0; it < 2; ++it) {
            int rb = it * 64 + w * 8;
            gload_lds16(A + (size_t)(bm + rb + srow8) * 256 + k0 + scol, As + rb * 64);
        }
        #pragma unroll
        for (int it = 0; it < 4; ++it) {
            int rb = it * 64 + w * 8;
            gload_lds16(W + (size_t)(rb + srow8) * 256 + k0 + scol, Bs + rb * 64);
        }
        __syncthreads();
        #pragma unroll
        for (int kk = 0; kk < 2; ++kk) {
            bf16x8 af[4], bf[4];
            int hs = ((kk * 4 + hi) ^ (c & 7)) * 8;
            #pragma unroll
            for (int mi = 0; mi < 4; ++mi)
                af[mi] = *(const bf16x8*)&As[(wr * 64 + mi * 16 + c) * 64 + hs];
            #pragma unroll
            for (int ni = 0; ni < 4; ++ni)
                bf[ni] = *(const bf16x8*)&Bs[(wc * 64 + ni * 16 + c) * 64 + hs];
            #pragma unroll
            for (int mi = 0; mi < 4; ++mi)
                #pragma unroll
                for (int ni = 0; ni < 4; ++ni)
                    acc[mi][ni] = __builtin_amdgcn_mfma_f32_16x16x32_bf16(
                        af[mi], bf[ni], acc[mi][ni], 0, 0, 0);
        }
        __syncthreads();
    }

    #pragma unroll
    for (int mi = 0; mi < 4; ++mi) {
        #pragma unroll
        for (int ni = 0; ni < 4; ++ni) {
            int colb = wc * 64 + ni * 16 + c;
            float bv = bias[colb];
            #pragma unroll
            for (int r = 0; r < 4; ++r)
                pool[(wr * 64 + mi * 16 + hi * 4 + r) * XS + colb] =
                    f2bf(acc[mi][ni][r] + bv);
        }
    }
    __syncthreads();

    float4 gv  = *(const float4*)(g2 + lane * 4);
    float4 bv2 = *(const float4*)(b2 + lane * 4);
    #pragma unroll 2
    for (int i = 0; i < 16; ++i) {
        int tl = w * 16 + i;
        int t = bm + tl;
        int rr = t2rr(t);
        float4 xv = *(const float4*)(x + (size_t)rr * C_ + lane * 4);
        uint2 ov = *(const uint2*)&pool[tl * XS + lane * 4];
        float x0 = xv.x + bf2f(ov.x & 0xffff);
        float x1 = xv.y + bf2f(ov.x >> 16);
        float x2 = xv.z + bf2f(ov.y & 0xffff);
        float x3 = xv.w + bf2f(ov.y >> 16);
        float s  = x0 + x1 + x2 + x3;
        float ss = x0 * x0 + x1 * x1 + x2 * x2 + x3 * x3;
        #pragma unroll
        for (int m = 1; m < 64; m <<= 1) {
            s  += __shfl_xor(s, m, 64);
            ss += __shfl_xor(ss, m, 64);
        }
        float mean = s * (1.0f / C_);
        float var  = ss * (1.0f / C_) - mean * mean;
        float inv  = rsqrtf(var + 1e-5f);
        uint2 xw, lw;
        xw.x = (unsigned)f2bf(x0) | ((unsigned)f2bf(x1) << 16);
        xw.y = (unsigned)f2bf(x2) | ((unsigned)f2bf(x3) << 16);
        float l0 = (x0 - mean) * inv * gv.x + bv2.x;
        float l1 = (x1 - mean) * inv * gv.y + bv2.y;
        float l2 = (x2 - mean) * inv * gv.z + bv2.z;
        float l3 = (x3 - mean) * inv * gv.w + bv2.w;
        lw.x = (unsigned)f2bf(l0) | ((unsigned)f2bf(l1) << 16);
        lw.y = (unsigned)f2bf(l2) | ((unsigned)f2bf(l3) << 16);
        *(uint2*)(x1_out + (size_t)t * C_ + lane * 4) = xw;
        *(uint2*)(ln_out + (size_t)t * C_ + lane * 4) = lw;
    }
}

// ---------------------------------------------------------------------------
// fc1: ln2 (M_ x 256) @ w1^T + b1 -> tanh-GELU (rcpf) -> natural bf16.
// BK=64 single-buffer + swizzle; full-width single-phase Ts epilogue.
// ---------------------------------------------------------------------------
__global__ __launch_bounds__(256) void mgemm_g(
    const unsigned short* __restrict__ A, const unsigned short* __restrict__ W,
    const float* __restrict__ bias, unsigned short* __restrict__ outp)
{
    __shared__ __align__(16) unsigned short pool[128 * TSS];   // 34.8 KB
    unsigned short* As = pool;
    unsigned short* Bs = pool + 8192;
    unsigned short* Ts = pool;

    int tid  = threadIdx.x;
    int w    = tid >> 6;
    int lane = tid & 63;
    int wr = w >> 1, wc = w & 1;
    int bm, bn;
    xcd_decode<4>(gridDim.x, bm, bn);
    int srow8 = lane >> 3;
    int scol  = ((lane & 7) ^ srow8) * 8;
    int c = lane & 15, hi = lane >> 4;

    f32x4 acc[4][4] = {};

    for (int k0 = 0; k0 < 256; k0 += GBK) {
        #pragma unroll
        for (int it = 0; it < 4; ++it) {
            int rb = it * 32 + w * 8;
            gload_lds16(A + (size_t)(bm + rb + srow8) * 256 + k0 + scol, As + rb * 64);
            gload_lds16(W + (size_t)(bn + rb + srow8) * 256 + k0 + scol, Bs + rb * 64);
        }
        __syncthreads();
        #pragma unroll
        for (int kk = 0; kk < 2; ++kk) {
            bf16x8 af[4], bf[4];
            int hs = ((kk * 4 + hi) ^ (c & 7)) * 8;
            #pragma unroll
            for (int mi = 0; mi < 4; ++mi)
                af[mi] = *(const bf16x8*)&As[(wr * 64 + mi * 16 + c) * 64 + hs];
            #pragma unroll
            for (int ni = 0; ni < 4; ++ni)
                bf[ni] = *(const bf16x8*)&Bs[(wc * 64 + ni * 16 + c) * 64 + hs];
            #pragma unroll
            for (int mi = 0; mi < 4; ++mi)
                #pragma unroll
                for (int ni = 0; ni < 4; ++ni)
                    acc[mi][ni] = __builtin_amdgcn_mfma_f32_16x16x32_bf16(
                        af[mi], bf[ni], acc[mi][ni], 0, 0, 0);
        }
        __syncthreads();
    }

    #pragma unroll
    for (int mi = 0; mi < 4; ++mi) {
        #pragma unroll
        for (int ni = 0; ni < 4; ++ni) {
            int colb = wc * 64 + ni * 16 + c;
            float bv = bias[bn + colb];
            #pragma unroll
            for (int r = 0; r < 4; ++r) {
                float v = acc[mi][ni][r] + bv;
                float a = 1.5957691216f * (v + 0.044715f * v * v * v);
                float g = v * __builtin_amdgcn_rcpf(1.0f + __expf(-a));
                Ts[(wr * 64 + mi * 16 + hi * 4 + r) * TSS + colb] = f2bf(g);
            }
        }
    }
    __syncthreads();

    #pragma unroll
    for (int it = 0; it < 8; ++it) {
        int id = it * 256 + tid;
        int row = id >> 4, cx = (id & 15) * 8;
        uint4 v = *(const uint4*)&Ts[row * TSS + cx];
        *(uint4*)&outp[(size_t)(bm + row) * MLPH + bn + cx] = v;
    }
}

// ---------------------------------------------------------------------------
// fc2: gelu (M_ x 512) @ w2^T + b2 + residual(x1 bf16 windowed) -> natural f32.
// BK=64 single-buffer + swizzle; 2-phase LDS-transposed epilogue.
// ---------------------------------------------------------------------------
__global__ __launch_bounds__(256) void mgemm_out(
    const unsigned short* __restrict__ A, const unsigned short* __restrict__ W,
    const float* __restrict__ bias, const unsigned short* __restrict__ x1,
    float* __restrict__ dout)
{
    __shared__ __align__(16) unsigned short pool[16896];   // 33.8 KB
    unsigned short* As = pool;
    unsigned short* Bs = pool + 8192;
    float* stg = (float*)pool;

    int tid  = threadIdx.x;
    int w    = tid >> 6;
    int lane = tid & 63;
    int wr = w >> 1, wc = w & 1;
    int bm, bn;
    xcd_decode<2>(gridDim.x, bm, bn);
    int srow8 = lane >> 3;
    int scol  = ((lane & 7) ^ srow8) * 8;
    int c = lane & 15, hi = lane >> 4;

    f32x4 acc[4][4] = {};

    for (int k0 = 0; k0 < 512; k0 += GBK) {
        #pragma unroll
        for (int it = 0; it < 4; ++it) {
            int rb = it * 32 + w * 8;
            gload_lds16(A + (size_t)(bm + rb + srow8) * 512 + k0 + scol, As + rb * 64);
            gload_lds16(W + (size_t)(bn + rb + srow8) * 512 + k0 + scol, Bs + rb * 64);
        }
        __syncthreads();
        #pragma unroll
        for (int kk = 0; kk < 2; ++kk) {
            bf16x8 af[4], bf[4];
            int hs = ((kk * 4 + hi) ^ (c & 7)) * 8;
            #pragma unroll
            for (int mi = 0; mi < 4; ++mi)
                af[mi] = *(const bf16x8*)&As[(wr * 64 + mi * 16 + c) * 64 + hs];
            #pragma unroll
            for (int ni = 0; ni < 4; ++ni)
                bf[ni] = *(const bf16x8*)&Bs[(wc * 64 + ni * 16 + c) * 64 + hs];
            #pragma unroll
            for (int mi = 0; mi < 4; ++mi)
                #pragma unroll
                for (int ni = 0; ni < 4; ++ni)
                    acc[mi][ni] = __builtin_amdgcn_mfma_f32_16x16x32_bf16(
                        af[mi], bf[ni], acc[mi][ni], 0, 0, 0);
        }
        __syncthreads();
    }

    #pragma unroll
    for (int p = 0; p < 2; ++p) {
        if (wr == p) {
            #pragma unroll
            for (int mi = 0; mi < 4; ++mi)
                #pragma unroll
                for (int ni = 0; ni < 4; ++ni) {
                    int colb = wc * 64 + ni * 16 + c;
                    float bv = bias[bn + colb];
                    #pragma unroll
                    for (int r = 0; r < 4; ++r)
                        stg[(mi * 16 + hi * 4 + r) * 132 + colb] =
                            acc[mi][ni][r] + bv;
                }
        }
        __syncthreads();
        #pragma unroll
        for (int i = 0; i < 8; ++i) {
            int lr = i * 8 + (tid >> 5);
            int t = bm + p * 64 + lr;
            int rr = t2rr(t);
            int col4 = (tid & 31) * 4;
            float4 v = *(const float4*)&stg[lr * 132 + col4];
            uint2 rv = *(const uint2*)&x1[(size_t)t * C_ + bn + col4];
            v.x += bf2f(rv.x & 0xffff);
            v.y += bf2f(rv.x >> 16);
            v.z += bf2f(rv.y & 0xffff);
            v.w += bf2f(rv.y >> 16);
            *(float4*)&dout[(size_t)rr * C_ + bn + col4] = v;
        }
        if (p == 0) __syncthreads();
    }
}

// ---------------------------------------------------------------------------
extern "C" void kernel_launch(void* const* d_in, const int* in_sizes, int n_in,
                              void* d_out, int out_size, void* d_ws, size_t ws_size,
                              hipStream_t stream)
{
    (void)in_sizes; (void)n_in; (void)out_size; (void)ws_size;
    const float* x    = (const float*)d_in[0];
    const float* n1g  = (const float*)d_in[3];
    const float* n1b  = (const float*)d_in[4];
    const float* wqkv = (const float*)d_in[5];
    const float* bqkv = (const float*)d_in[6];
    const float* wout = (const float*)d_in[7];
    const float* bout = (const float*)d_in[8];
    const float* n2g  = (const float*)d_in[9];
    const float* n2b  = (const float*)d_in[10];
    const float* w1   = (const float*)d_in[11];
    const float* b1   = (const float*)d_in[12];
    const float* w2   = (const float*)d_in[13];
    const float* b2   = (const float*)d_in[14];
    float* out = (float*)d_out;

    // workspace layout (bf16 shorts)
    unsigned short* bufA_bf = (unsigned short*)d_ws;                 // M*256 (LN1 out, then o_win)
    unsigned short* qkv_bf  = bufA_bf + (size_t)M_ * C_;             // 3*NWH*2048 (later gelu M*512)
    unsigned short* x1_bf   = qkv_bf + (size_t)3 * NWH * WHSZ;       // M*256
    unsigned short* ln2_bf  = x1_bf + (size_t)M_ * C_;               // M*256
    unsigned short* wqkv_bf = ln2_bf + (size_t)M_ * C_;              // contiguous weights
    unsigned short* wout_bf = wqkv_bf + 768 * 256;
    unsigned short* w1_bf   = wout_bf + 256 * 256;
    unsigned short* w2_bf   = w1_bf + 512 * 256;
    unsigned short* gelu    = qkv_bf;   // alias (qkv dead after mattn)

    // 1) LN1 + window partition -> bufA_bf  (also converts weights -> bf16)
    ln_kernel<<<M_ / 4, 256, 0, stream>>>(x, n1g, n1b, bufA_bf,
                                          wqkv, wout, w1, w2, wqkv_bf);

    // 2) QKV GEMM -> Q/K/V natural planes (XCD-chunked)
    mgemm_qkv<<<(M_ / 128) * 6, 256, 0, stream>>>(
        bufA_bf, wqkv_bf, bqkv, qkv_bf);

    // 3) MFMA window attention -> o_win (bufA_bf)
    mattn<<<NWH / 4, 256, 0, stream>>>(qkv_bf, bufA_bf);

    // 4) out-proj + residual + LN2 fused -> x1_bf, ln2_bf
    mgemm_ln<<<M_ / 128, 512, 0, stream>>>(
        bufA_bf, wout_bf, bout, x, n2g, n2b, x1_bf, ln2_bf);

    // 5) MLP fc1 + tanh-GELU -> gelu (M_ x 512, natural)
    mgemm_g<<<(M_ / 128) * 4, 256, 0, stream>>>(ln2_bf, w1_bf, b1, gelu);

    // 6) MLP fc2 + residual(x1) -> d_out natural f32
    mgemm_out<<<(M_ / 128) * 2, 256, 0, stream>>>(gelu, w2_bf, b2, x1_bf, out);
}